// Round 4
// baseline (995.179 us; speedup 1.0000x reference)
//
#include <hip/hip_runtime.h>
#include <cstdint>
#include <cstddef>

// ---- problem constants (from reference) ----
#define F_INP 78
#define F_MID 156
#define C2    312   // HEADS*F_MID
#define GDIM  128
#define F1D   1024
#define F2D   512

#define NEG_SENTINEL -1e30f

__device__ __forceinline__ float leaky(float v, float s) { return v > 0.f ? v : s * v; }
__device__ __forceinline__ int rfl(int v) { return __builtin_amdgcn_readfirstlane(v); }

// ---------------- CSR construction ----------------

__global__ void deg_count_kernel(const int* __restrict__ ei, int* __restrict__ deg, int E) {
    int e = blockIdx.x * blockDim.x + threadIdx.x;
    if (e >= E) return;
    atomicAdd(&deg[ei[E + e]], 1);
}

// single-block scan: deg[N] -> row_ptr[N+1]; also emits cursor copy and dinv
__global__ void scan_kernel(const int* __restrict__ deg, int* __restrict__ row_ptr,
                            int* __restrict__ cursor, float* __restrict__ dinv, int N) {
    __shared__ int sums[1024];
    int tid = threadIdx.x;
    int chunk = (N + 1023) / 1024;
    int start = tid * chunk;
    int end = start + chunk;
    if (start > N) start = N;
    if (end > N) end = N;
    int s = 0;
    for (int i = start; i < end; i++) s += deg[i];
    sums[tid] = s;
    __syncthreads();
    for (int off = 1; off < 1024; off <<= 1) {
        int v = (tid >= off) ? sums[tid - off] : 0;
        __syncthreads();
        sums[tid] += v;
        __syncthreads();
    }
    int run = (tid == 0) ? 0 : sums[tid - 1];
    for (int i = start; i < end; i++) {
        int dg = deg[i];
        row_ptr[i] = run;
        cursor[i] = run;
        dinv[i] = rsqrtf((float)dg + 1.0f);
        run += dg;
    }
    if (tid == 1023) row_ptr[N] = run;
}

// fill col[] (src per CSR slot) and dstpos[] (dst per CSR slot)
__global__ void fill_csr_kernel(const int* __restrict__ ei, int* __restrict__ cursor,
                                int* __restrict__ col, int* __restrict__ dstpos, int E) {
    int e = blockIdx.x * blockDim.x + threadIdx.x;
    if (e >= E) return;
    int s = ei[e], d = ei[E + e];
    int pos = atomicAdd(&cursor[d], 1);
    col[pos] = s;
    dstpos[pos] = d;
}

// ---------------- dense layers (uniform scalar x-loads, no LDS) ----------------

// h_lin = x @ W1   [N,78]@[78,156]; 8 rows per block, x via wave-uniform float2 loads
__global__ void lin1_kernel(const float* __restrict__ x, const float* __restrict__ W1,
                            float* __restrict__ h_lin, int N) {
    int tid = threadIdx.x;           // block 192
    int n0 = blockIdx.x * 8;
    if (tid >= F_MID) return;
    const float2* x2 = (const float2*)x;   // row stride 39 float2
    size_t rb[8];
    #pragma unroll
    for (int r = 0; r < 8; r++) {
        int n = n0 + r; if (n >= N) n = N - 1;
        rb[r] = (size_t)n * 39;
    }
    float acc[8] = {0,0,0,0,0,0,0,0};
    for (int k2 = 0; k2 < 39; k2++) {
        float w0 = W1[(2 * k2) * F_MID + tid];
        float w1 = W1[(2 * k2 + 1) * F_MID + tid];
        #pragma unroll
        for (int r = 0; r < 8; r++) {
            float2 xv = x2[rb[r] + k2];    // uniform -> s_load
            acc[r] += xv.x * w0 + xv.y * w1;
        }
    }
    #pragma unroll
    for (int r = 0; r < 8; r++) {
        int n = n0 + r;
        if (n < N) h_lin[(size_t)n * F_MID + tid] = acc[r];
    }
}

// g = h_act @ W2   [N,156]@[156,312]; h_act already has b1+leaky applied
__global__ void lin2_kernel(const float* __restrict__ h_act, const float* __restrict__ W2,
                            float* __restrict__ g, int N) {
    int tid = threadIdx.x;           // block 320
    int n0 = blockIdx.x * 8;
    if (tid >= C2) return;
    const float4* h4 = (const float4*)h_act;  // row stride 39 float4
    size_t rb[8];
    #pragma unroll
    for (int r = 0; r < 8; r++) {
        int n = n0 + r; if (n >= N) n = N - 1;
        rb[r] = (size_t)n * 39;
    }
    float acc[8] = {0,0,0,0,0,0,0,0};
    for (int k4 = 0; k4 < 39; k4++) {
        float w0 = W2[(4 * k4 + 0) * C2 + tid];
        float w1 = W2[(4 * k4 + 1) * C2 + tid];
        float w2 = W2[(4 * k4 + 2) * C2 + tid];
        float w3 = W2[(4 * k4 + 3) * C2 + tid];
        #pragma unroll
        for (int r = 0; r < 8; r++) {
            float4 xv = h4[rb[r] + k4];    // uniform -> s_load_dwordx4
            acc[r] += xv.x * w0 + xv.y * w1 + xv.z * w2 + xv.w * w3;
        }
    }
    #pragma unroll
    for (int r = 0; r < 8; r++) {
        int n = n0 + r;
        if (n < N) g[(size_t)n * C2 + tid] = acc[r];
    }
}

// ---------------- GCN gather (float4, fused b1 + leaky) ----------------
// h_act[d,:] = leaky( sum_in h_lin[s,:]*dinv[s]*dinv[d] + h_lin[d,:]*dinv[d]^2 + b1, 0.01 )
__global__ void gcn_gather_kernel(const float* __restrict__ h_lin, const int* __restrict__ row_ptr,
                                  const int* __restrict__ col, const float* __restrict__ dinv,
                                  const float* __restrict__ b1, float* __restrict__ h_act, int N) {
    int wid  = (blockIdx.x * blockDim.x + threadIdx.x) >> 6;
    int lane = threadIdx.x & 63;
    if (wid >= N) return;
    int d  = wid;
    int jb = row_ptr[d], je = row_ptr[d + 1];
    float dd = dinv[d];
    const float4* h4 = (const float4*)h_lin;  // row stride 39
    bool act = lane < 39;
    float ax = 0.f, ay = 0.f, az = 0.f, aw = 0.f;
    int j = jb;
    for (; j + 3 < je; j += 4) {
        int s0 = rfl(col[j]);
        int s1 = rfl(col[j + 1]);
        int s2 = rfl(col[j + 2]);
        int s3 = rfl(col[j + 3]);
        float w0 = dinv[s0] * dd, w1 = dinv[s1] * dd, w2 = dinv[s2] * dd, w3 = dinv[s3] * dd;
        if (act) {
            float4 v0 = h4[(size_t)s0 * 39 + lane];
            float4 v1 = h4[(size_t)s1 * 39 + lane];
            float4 v2 = h4[(size_t)s2 * 39 + lane];
            float4 v3 = h4[(size_t)s3 * 39 + lane];
            ax += v0.x * w0 + v1.x * w1 + v2.x * w2 + v3.x * w3;
            ay += v0.y * w0 + v1.y * w1 + v2.y * w2 + v3.y * w3;
            az += v0.z * w0 + v1.z * w1 + v2.z * w2 + v3.z * w3;
            aw += v0.w * w0 + v1.w * w1 + v2.w * w2 + v3.w * w3;
        }
    }
    for (; j < je; j++) {
        int s = rfl(col[j]);
        float w = dinv[s] * dd;
        if (act) {
            float4 v = h4[(size_t)s * 39 + lane];
            ax += v.x * w; ay += v.y * w; az += v.z * w; aw += v.w * w;
        }
    }
    if (act) {
        float sn = dd * dd;
        float4 v = h4[(size_t)d * 39 + lane];
        float4 bb = ((const float4*)b1)[lane];
        float4 o;
        o.x = leaky(ax + v.x * sn + bb.x, 0.01f);
        o.y = leaky(ay + v.y * sn + bb.y, 0.01f);
        o.z = leaky(az + v.z * sn + bb.z, 0.01f);
        o.w = leaky(aw + v.w * sn + bb.w, 0.01f);
        ((float4*)h_act)[(size_t)d * 39 + lane] = o;
    }
}

// ---------------- GAT attention coefficients (one wave per node, both heads) ----------------
__global__ void att_kernel(const float* __restrict__ g, const float* __restrict__ att_src,
                           const float* __restrict__ att_dst, float2* __restrict__ a_src,
                           float2* __restrict__ a_dst, int N) {
    int wid  = (blockIdx.x * blockDim.x + threadIdx.x) >> 6;
    int lane = threadIdx.x & 63;
    if (wid >= N) return;
    const float* grow = g + (size_t)wid * C2;
    float vs0 = 0.f, vs1 = 0.f, vd0 = 0.f, vd1 = 0.f;
    #pragma unroll
    for (int k = 0; k < 5; k++) {
        int c = lane + 64 * k;
        if (c < C2) {
            float gv = grow[c];
            float sw = att_src[c];
            float dw = att_dst[c];
            if (c < F_MID) { vs0 += gv * sw; vd0 += gv * dw; }
            else           { vs1 += gv * sw; vd1 += gv * dw; }
        }
    }
    #pragma unroll
    for (int off = 32; off; off >>= 1) {
        vs0 += __shfl_xor(vs0, off);
        vs1 += __shfl_xor(vs1, off);
        vd0 += __shfl_xor(vd0, off);
        vd1 += __shfl_xor(vd1, off);
    }
    if (lane == 0) {
        float2 s; s.x = vs0; s.y = vs1;
        float2 t; t.x = vd0; t.y = vd1;
        a_src[wid] = s;
        a_dst[wid] = t;
    }
}

// ---------------- GAT K1: per-dst online max+sum -> minv[d]=(m0,inv0,m1,inv1) ----------------
__global__ void gat_ms_kernel(const float2* __restrict__ a_src, const float2* __restrict__ a_dst,
                              const int* __restrict__ row_ptr, const int* __restrict__ col,
                              float4* __restrict__ minv, int N) {
    int wid  = (blockIdx.x * blockDim.x + threadIdx.x) >> 6;
    int lane = threadIdx.x & 63;
    if (wid >= N) return;
    int d  = wid;
    int jb = row_ptr[d], je = row_ptr[d + 1];
    float2 ad = a_dst[d];
    float2 asd = a_src[d];
    float es0 = leaky(asd.x + ad.x, 0.2f);   // self-loop logits
    float es1 = leaky(asd.y + ad.y, 0.2f);

    float m0 = NEG_SENTINEL, s0 = 0.f, m1 = NEG_SENTINEL, s1 = 0.f;
    for (int j = jb + lane; j < je; j += 64) {
        float2 as = a_src[col[j]];
        float e0 = leaky(as.x + ad.x, 0.2f);
        float e1 = leaky(as.y + ad.y, 0.2f);
        float nm0 = fmaxf(m0, e0); s0 = s0 * __expf(m0 - nm0) + __expf(e0 - nm0); m0 = nm0;
        float nm1 = fmaxf(m1, e1); s1 = s1 * __expf(m1 - nm1) + __expf(e1 - nm1); m1 = nm1;
    }
    #pragma unroll
    for (int off = 32; off; off >>= 1) {
        float om0 = __shfl_xor(m0, off), os0 = __shfl_xor(s0, off);
        float om1 = __shfl_xor(m1, off), os1 = __shfl_xor(s1, off);
        float nm0 = fmaxf(m0, om0);
        s0 = s0 * __expf(m0 - nm0) + os0 * __expf(om0 - nm0); m0 = nm0;
        float nm1 = fmaxf(m1, om1);
        s1 = s1 * __expf(m1 - nm1) + os1 * __expf(om1 - nm1); m1 = nm1;
    }
    { // fold self-loop
        float nm0 = fmaxf(m0, es0);
        s0 = s0 * __expf(m0 - nm0) + __expf(es0 - nm0); m0 = nm0;
        float nm1 = fmaxf(m1, es1);
        s1 = s1 * __expf(m1 - nm1) + __expf(es1 - nm1); m1 = nm1;
    }
    if (lane == 0) {
        float4 r; r.x = m0; r.y = 1.0f / s0; r.z = m1; r.w = 1.0f / s1;
        minv[d] = r;
    }
}

// ---------------- GAT K2: per-CSR-slot normalized weights ----------------
__global__ void gat_w_kernel(const float2* __restrict__ a_src, const float2* __restrict__ a_dst,
                             const int* __restrict__ col, const int* __restrict__ dstpos,
                             const float4* __restrict__ minv, float2* __restrict__ wbuf, int E) {
    int j = blockIdx.x * blockDim.x + threadIdx.x;
    if (j >= E) return;
    int s = col[j], d = dstpos[j];
    float2 as = a_src[s];
    float2 ad = a_dst[d];
    float4 mv = minv[d];
    float2 w;
    w.x = __expf(leaky(as.x + ad.x, 0.2f) - mv.x) * mv.y;
    w.y = __expf(leaky(as.y + ad.y, 0.2f) - mv.z) * mv.w;
    wbuf[j] = w;
}

// ---------------- GAT K3: weighted gather (float4 rows) ----------------
// chunk0: float4 idx lane   (floats 4*lane..4*lane+3)  -> head0 iff lane<39
// chunk1: float4 idx 64+lane (lane<14)                 -> always head1
__global__ void gat_gather_kernel(const float* __restrict__ g, const float2* __restrict__ a_src,
                                  const float2* __restrict__ a_dst, const int* __restrict__ row_ptr,
                                  const int* __restrict__ col, const float2* __restrict__ wbuf,
                                  const float4* __restrict__ minv, float* __restrict__ gout, int N) {
    int wid  = (blockIdx.x * blockDim.x + threadIdx.x) >> 6;
    int lane = threadIdx.x & 63;
    if (wid >= N) return;
    int d  = wid;
    int jb = row_ptr[d], je = row_ptr[d + 1];
    const float4* g4 = (const float4*)g;   // row stride 78
    bool h0   = lane < 39;
    bool act1 = lane < 14;
    float Ax, Ay, Az, Aw;                  // chunk0 acc
    float Bx = 0.f, By = 0.f, Bz = 0.f, Bw = 0.f;  // chunk1 acc
    { // self contribution
        float2 ad = a_dst[d];
        float2 asd = a_src[d];
        float4 mv = minv[d];
        float w0 = __expf(leaky(asd.x + ad.x, 0.2f) - mv.x) * mv.y;
        float w1 = __expf(leaky(asd.y + ad.y, 0.2f) - mv.z) * mv.w;
        size_t rb = (size_t)d * 78;
        float4 v = g4[rb + lane];
        float w = h0 ? w0 : w1;
        Ax = v.x * w; Ay = v.y * w; Az = v.z * w; Aw = v.w * w;
        if (act1) {
            float4 u = g4[rb + 64 + lane];
            Bx = u.x * w1; By = u.y * w1; Bz = u.z * w1; Bw = u.w * w1;
        }
    }
    int j = jb;
    for (; j + 1 < je; j += 2) {
        int sA = rfl(col[j]);
        int sB = rfl(col[j + 1]);
        float2 wA = wbuf[j], wB = wbuf[j + 1];
        size_t ra = (size_t)sA * 78, rb = (size_t)sB * 78;
        float4 vA = g4[ra + lane];
        float4 vB = g4[rb + lane];
        float wa = h0 ? wA.x : wA.y;
        float wb = h0 ? wB.x : wB.y;
        Ax += vA.x * wa + vB.x * wb;
        Ay += vA.y * wa + vB.y * wb;
        Az += vA.z * wa + vB.z * wb;
        Aw += vA.w * wa + vB.w * wb;
        if (act1) {
            float4 uA = g4[ra + 64 + lane];
            float4 uB = g4[rb + 64 + lane];
            Bx += uA.x * wA.y + uB.x * wB.y;
            By += uA.y * wA.y + uB.y * wB.y;
            Bz += uA.z * wA.y + uB.z * wB.y;
            Bw += uA.w * wA.y + uB.w * wB.y;
        }
    }
    if (j < je) {
        int s = rfl(col[j]);
        float2 w2 = wbuf[j];
        size_t rs = (size_t)s * 78;
        float4 v = g4[rs + lane];
        float w = h0 ? w2.x : w2.y;
        Ax += v.x * w; Ay += v.y * w; Az += v.z * w; Aw += v.w * w;
        if (act1) {
            float4 u = g4[rs + 64 + lane];
            Bx += u.x * w2.y; By += u.y * w2.y; Bz += u.z * w2.y; Bw += u.w * w2.y;
        }
    }
    float4* o4 = (float4*)gout;
    float4 oa; oa.x = Ax; oa.y = Ay; oa.z = Az; oa.w = Aw;
    o4[(size_t)d * 78 + lane] = oa;
    if (act1) {
        float4 ob; ob.x = Bx; ob.y = By; ob.z = Bz; ob.w = Bw;
        o4[(size_t)d * 78 + 64 + lane] = ob;
    }
}

// ---------------- pooling + MLP ----------------

__global__ void starts_kernel(const int* __restrict__ batch, int* __restrict__ starts, int N, int B) {
    int b = blockIdx.x * blockDim.x + threadIdx.x;
    if (b > B) return;
    if (b == B) { starts[B] = N; return; }
    int lo = 0, hi = N;
    while (lo < hi) {
        int mid = (lo + hi) >> 1;
        if (batch[mid] < b) lo = mid + 1; else hi = mid;
    }
    starts[b] = lo;
}

// p0[b,:] = leaky(max_n gout[n,:] + b2, 0.01); float4 columns, 4-deep unroll
__global__ void pool_kernel(const float* __restrict__ gout, const float* __restrict__ b2,
                            const int* __restrict__ starts, float* __restrict__ p0) {
    int b = blockIdx.x;
    int t = threadIdx.x;   // block 128; t<78 active
    if (t >= 78) return;
    int s = starts[b], e = starts[b + 1];
    const float4* g4 = (const float4*)gout;
    float4 m0, m1, m2, m3;
    m0.x = m0.y = m0.z = m0.w = -INFINITY;
    m1 = m0; m2 = m0; m3 = m0;
    int n = s;
    for (; n + 3 < e; n += 4) {
        float4 v0 = g4[(size_t)(n + 0) * 78 + t];
        float4 v1 = g4[(size_t)(n + 1) * 78 + t];
        float4 v2 = g4[(size_t)(n + 2) * 78 + t];
        float4 v3 = g4[(size_t)(n + 3) * 78 + t];
        m0.x = fmaxf(m0.x, v0.x); m0.y = fmaxf(m0.y, v0.y); m0.z = fmaxf(m0.z, v0.z); m0.w = fmaxf(m0.w, v0.w);
        m1.x = fmaxf(m1.x, v1.x); m1.y = fmaxf(m1.y, v1.y); m1.z = fmaxf(m1.z, v1.z); m1.w = fmaxf(m1.w, v1.w);
        m2.x = fmaxf(m2.x, v2.x); m2.y = fmaxf(m2.y, v2.y); m2.z = fmaxf(m2.z, v2.z); m2.w = fmaxf(m2.w, v2.w);
        m3.x = fmaxf(m3.x, v3.x); m3.y = fmaxf(m3.y, v3.y); m3.z = fmaxf(m3.z, v3.z); m3.w = fmaxf(m3.w, v3.w);
    }
    for (; n < e; n++) {
        float4 v = g4[(size_t)n * 78 + t];
        m0.x = fmaxf(m0.x, v.x); m0.y = fmaxf(m0.y, v.y); m0.z = fmaxf(m0.z, v.z); m0.w = fmaxf(m0.w, v.w);
    }
    m0.x = fmaxf(fmaxf(m0.x, m1.x), fmaxf(m2.x, m3.x));
    m0.y = fmaxf(fmaxf(m0.y, m1.y), fmaxf(m2.y, m3.y));
    m0.z = fmaxf(fmaxf(m0.z, m1.z), fmaxf(m2.z, m3.z));
    m0.w = fmaxf(fmaxf(m0.w, m1.w), fmaxf(m2.w, m3.w));
    float4 bb = ((const float4*)b2)[t];
    float4 o;
    o.x = leaky(m0.x + bb.x, 0.01f);
    o.y = leaky(m0.y + bb.y, 0.01f);
    o.z = leaky(m0.z + bb.z, 0.01f);
    o.w = leaky(m0.w + bb.w, 0.01f);
    ((float4*)p0)[(size_t)b * 78 + t] = o;
}

// generic dense layer: out[b,c] = act(in[b,:KDIM] . W[:,c] + bias[c])
// ACT: 0 none, 1 leaky 0.01, 2 relu
template <int KDIM, int ACT>
__global__ void fc_kernel(const float* __restrict__ in, const float* __restrict__ W,
                          const float* __restrict__ bias, float* __restrict__ out,
                          int Bn, int OUT) {
    int idx = blockIdx.x * blockDim.x + threadIdx.x;
    if (idx >= Bn * OUT) return;
    int b = idx / OUT, c = idx % OUT;
    const float* irow = in + (size_t)b * KDIM;
    float acc = bias[c];
    #pragma unroll 4
    for (int k = 0; k < KDIM; k++) acc += irow[k] * W[(size_t)k * OUT + c];
    if (ACT == 1) acc = leaky(acc, 0.01f);
    if (ACT == 2) acc = fmaxf(acc, 0.f);
    out[idx] = acc;
}

extern "C" void kernel_launch(void* const* d_in, const int* in_sizes, int n_in,
                              void* d_out, int out_size, void* d_ws, size_t ws_size,
                              hipStream_t stream) {
    const float* x       = (const float*)d_in[0];
    const int*   ei      = (const int*)d_in[1];
    const int*   batch   = (const int*)d_in[2];
    const float* W1      = (const float*)d_in[3];
    const float* b1      = (const float*)d_in[4];
    const float* W2      = (const float*)d_in[5];
    const float* att_src = (const float*)d_in[6];
    const float* att_dst = (const float*)d_in[7];
    const float* b2      = (const float*)d_in[8];
    const float* Wg      = (const float*)d_in[9];
    const float* bg      = (const float*)d_in[10];
    const float* Wf1     = (const float*)d_in[11];
    const float* bf1     = (const float*)d_in[12];
    const float* Wf2     = (const float*)d_in[13];
    const float* bf2     = (const float*)d_in[14];
    const float* Wo      = (const float*)d_in[15];
    const float* bo      = (const float*)d_in[16];
    float* out = (float*)d_out;

    const int N  = in_sizes[0] / F_INP;
    const int E  = in_sizes[1] / 2;
    const int Bn = out_size;          // 128 graphs

    // ---- workspace carving (16B-aligned slices) ----
    char* base = (char*)d_ws;
    size_t off = 0;
    auto take = [&](size_t bytes) -> void* {
        off = (off + 15) & ~(size_t)15;
        void* p = base + off;
        off += bytes;
        return p;
    };
    float*  g       = (float*)take((size_t)C2 * N * 4);      // lives whole pipeline
    float*  AA      = (float*)take((size_t)C2 * N * 4);      // h_lin|h_act early, gout late
    float*  h_lin   = AA;
    float*  h_act   = AA + (size_t)F_MID * N;
    float*  gout    = AA;                                    // alias after lin2
    float4* minv    = (float4*)take((size_t)N * 16);
    float2* a_src   = (float2*)take((size_t)N * 8);
    float2* a_dst   = (float2*)take((size_t)N * 8);
    float2* wbuf    = (float2*)take((size_t)E * 8);
    float*  dinv    = (float*)take((size_t)N * 4);
    int*    deg_i   = (int*)take((size_t)N * 4);
    int*    row_ptr = (int*)take((size_t)(N + 1) * 4);
    int*    cursor  = (int*)take((size_t)N * 4);
    int*    col     = (int*)take((size_t)E * 4);
    int*    dstpos  = (int*)take((size_t)E * 4);
    int*    starts  = (int*)take((size_t)(Bn + 1) * 4);
    float*  p0      = (float*)take((size_t)Bn * C2 * 4);
    float*  p1      = (float*)take((size_t)Bn * GDIM * 4);
    float*  p2      = (float*)take((size_t)Bn * F1D * 4);
    float*  p3      = (float*)take((size_t)Bn * F2D * 4);

    hipMemsetAsync(deg_i, 0, (size_t)N * sizeof(int), stream);

    // segment starts (only depends on batch)
    starts_kernel<<<1, 256, 0, stream>>>(batch, starts, N, Bn);

    // CSR build
    deg_count_kernel<<<(E + 255) / 256, 256, 0, stream>>>(ei, deg_i, E);
    scan_kernel<<<1, 1024, 0, stream>>>(deg_i, row_ptr, cursor, dinv, N);
    fill_csr_kernel<<<(E + 255) / 256, 256, 0, stream>>>(ei, cursor, col, dstpos, E);

    // GCN
    lin1_kernel<<<(N + 7) / 8, 192, 0, stream>>>(x, W1, h_lin, N);
    gcn_gather_kernel<<<(N + 3) / 4, 256, 0, stream>>>(h_lin, row_ptr, col, dinv, b1, h_act, N);

    // GAT
    lin2_kernel<<<(N + 7) / 8, 320, 0, stream>>>(h_act, W2, g, N);
    att_kernel<<<(N + 3) / 4, 256, 0, stream>>>(g, att_src, att_dst, a_src, a_dst, N);
    gat_ms_kernel<<<(N + 3) / 4, 256, 0, stream>>>(a_src, a_dst, row_ptr, col, minv, N);
    gat_w_kernel<<<(E + 255) / 256, 256, 0, stream>>>(a_src, a_dst, col, dstpos, minv, wbuf, E);
    gat_gather_kernel<<<(N + 3) / 4, 256, 0, stream>>>(g, a_src, a_dst, row_ptr, col, wbuf, minv, gout, N);

    // pool + MLP
    pool_kernel<<<Bn, 128, 0, stream>>>(gout, b2, starts, p0);
    fc_kernel<C2, 1><<<(Bn * GDIM + 255) / 256, 256, 0, stream>>>(p0, Wg, bg, p1, Bn, GDIM);
    fc_kernel<GDIM, 2><<<(Bn * F1D + 255) / 256, 256, 0, stream>>>(p1, Wf1, bf1, p2, Bn, F1D);
    fc_kernel<F1D, 2><<<(Bn * F2D + 255) / 256, 256, 0, stream>>>(p2, Wf2, bf2, p3, Bn, F2D);
    fc_kernel<F2D, 0><<<1, 128, 0, stream>>>(p3, Wo, bo, out, Bn, 1);
}

// Round 5
// 963.746 us; speedup vs baseline: 1.0326x; 1.0326x over previous
//
#include <hip/hip_runtime.h>
#include <cstdint>
#include <cstddef>

// ---- problem constants (from reference) ----
#define F_INP 78
#define F_MID 156
#define C2    312   // HEADS*F_MID
#define GDIM  128
#define F1D   1024
#define F2D   512

#define NEG_SENTINEL -1e30f

__device__ __forceinline__ float leaky(float v, float s) { return v > 0.f ? v : s * v; }
__device__ __forceinline__ int rfl(int v) { return __builtin_amdgcn_readfirstlane(v); }

// ---------------- CSR construction ----------------

__global__ void deg_count_kernel(const int* __restrict__ ei, int* __restrict__ deg, int E) {
    int e = blockIdx.x * blockDim.x + threadIdx.x;
    if (e >= E) return;
    atomicAdd(&deg[ei[E + e]], 1);
}

// single-block scan: deg[N] -> row_ptr[N+1]; also emits cursor copy and dinv
__global__ void scan_kernel(const int* __restrict__ deg, int* __restrict__ row_ptr,
                            int* __restrict__ cursor, float* __restrict__ dinv, int N) {
    __shared__ int sums[1024];
    int tid = threadIdx.x;
    int chunk = (N + 1023) / 1024;
    int start = tid * chunk;
    int end = start + chunk;
    if (start > N) start = N;
    if (end > N) end = N;
    int s = 0;
    for (int i = start; i < end; i++) s += deg[i];
    sums[tid] = s;
    __syncthreads();
    for (int off = 1; off < 1024; off <<= 1) {
        int v = (tid >= off) ? sums[tid - off] : 0;
        __syncthreads();
        sums[tid] += v;
        __syncthreads();
    }
    int run = (tid == 0) ? 0 : sums[tid - 1];
    for (int i = start; i < end; i++) {
        int dg = deg[i];
        row_ptr[i] = run;
        cursor[i] = run;
        dinv[i] = rsqrtf((float)dg + 1.0f);
        run += dg;
    }
    if (tid == 1023) row_ptr[N] = run;
}

// fill col[] (src per CSR slot)
__global__ void fill_csr_kernel(const int* __restrict__ ei, int* __restrict__ cursor,
                                int* __restrict__ col, int E) {
    int e = blockIdx.x * blockDim.x + threadIdx.x;
    if (e >= E) return;
    int s = ei[e], d = ei[E + e];
    int pos = atomicAdd(&cursor[d], 1);
    col[pos] = s;
}

// ---------------- dense layers (LDS-staged float4 inner loops) ----------------

// h_lin = x @ W1   [N,78]@[78,156]; 16 rows per block, block 192
__global__ void lin1_kernel(const float* __restrict__ x, const float* __restrict__ W1,
                            float* __restrict__ h_lin, int N) {
    __shared__ float2 xs[16][39];
    int tid = threadIdx.x;           // 192
    int n0 = blockIdx.x * 16;
    const float2* x2 = (const float2*)x;   // row stride 39 float2
    for (int i = tid; i < 16 * 39; i += 192) {
        int r = i / 39, c = i % 39;
        int n = n0 + r;
        float2 z; z.x = 0.f; z.y = 0.f;
        xs[r][c] = (n < N) ? x2[(size_t)n * 39 + c] : z;
    }
    __syncthreads();
    if (tid >= F_MID) return;
    float acc[16] = {};
    for (int k2 = 0; k2 < 39; k2++) {
        float w0 = W1[(2 * k2) * F_MID + tid];
        float w1 = W1[(2 * k2 + 1) * F_MID + tid];
        #pragma unroll
        for (int r = 0; r < 16; r++) {
            float2 xv = xs[r][k2];
            acc[r] += xv.x * w0 + xv.y * w1;
        }
    }
    #pragma unroll
    for (int r = 0; r < 16; r++) {
        int n = n0 + r;
        if (n < N) h_lin[(size_t)n * F_MID + tid] = acc[r];
    }
}

// g = h_act @ W2   [N,156]@[156,312]; 16 rows per block, block 320
__global__ void lin2_kernel(const float* __restrict__ h_act, const float* __restrict__ W2,
                            float* __restrict__ g, int N) {
    __shared__ float4 hs[16][39];
    int tid = threadIdx.x;           // 320
    int n0 = blockIdx.x * 16;
    const float4* h4 = (const float4*)h_act;  // row stride 39 float4
    for (int i = tid; i < 16 * 39; i += 320) {
        int r = i / 39, c = i % 39;
        int n = n0 + r;
        float4 z; z.x = z.y = z.z = z.w = 0.f;
        hs[r][c] = (n < N) ? h4[(size_t)n * 39 + c] : z;
    }
    __syncthreads();
    if (tid >= C2) return;
    float acc[16] = {};
    for (int k4 = 0; k4 < 39; k4++) {
        float w0 = W2[(4 * k4 + 0) * C2 + tid];
        float w1 = W2[(4 * k4 + 1) * C2 + tid];
        float w2 = W2[(4 * k4 + 2) * C2 + tid];
        float w3 = W2[(4 * k4 + 3) * C2 + tid];
        #pragma unroll
        for (int r = 0; r < 16; r++) {
            float4 xv = hs[r][k4];
            acc[r] += xv.x * w0 + xv.y * w1 + xv.z * w2 + xv.w * w3;
        }
    }
    #pragma unroll
    for (int r = 0; r < 16; r++) {
        int n = n0 + r;
        if (n < N) g[(size_t)n * C2 + tid] = acc[r];
    }
}

// ---------------- GCN gather (float4, fused b1 + leaky) ----------------
// h_act[d,:] = leaky( sum_in h_lin[s,:]*dinv[s]*dinv[d] + h_lin[d,:]*dinv[d]^2 + b1, 0.01 )
__global__ void gcn_gather_kernel(const float* __restrict__ h_lin, const int* __restrict__ row_ptr,
                                  const int* __restrict__ col, const float* __restrict__ dinv,
                                  const float* __restrict__ b1, float* __restrict__ h_act, int N) {
    int wid  = (blockIdx.x * blockDim.x + threadIdx.x) >> 6;
    int lane = threadIdx.x & 63;
    if (wid >= N) return;
    int d  = wid;
    int jb = row_ptr[d], je = row_ptr[d + 1];
    float dd = dinv[d];
    const float4* h4 = (const float4*)h_lin;  // row stride 39
    bool act = lane < 39;
    float ax = 0.f, ay = 0.f, az = 0.f, aw = 0.f;
    int j = jb;
    for (; j + 3 < je; j += 4) {
        int s0 = rfl(col[j]);
        int s1 = rfl(col[j + 1]);
        int s2 = rfl(col[j + 2]);
        int s3 = rfl(col[j + 3]);
        float w0 = dinv[s0] * dd, w1 = dinv[s1] * dd, w2 = dinv[s2] * dd, w3 = dinv[s3] * dd;
        if (act) {
            float4 v0 = h4[(size_t)s0 * 39 + lane];
            float4 v1 = h4[(size_t)s1 * 39 + lane];
            float4 v2 = h4[(size_t)s2 * 39 + lane];
            float4 v3 = h4[(size_t)s3 * 39 + lane];
            ax += v0.x * w0 + v1.x * w1 + v2.x * w2 + v3.x * w3;
            ay += v0.y * w0 + v1.y * w1 + v2.y * w2 + v3.y * w3;
            az += v0.z * w0 + v1.z * w1 + v2.z * w2 + v3.z * w3;
            aw += v0.w * w0 + v1.w * w1 + v2.w * w2 + v3.w * w3;
        }
    }
    for (; j < je; j++) {
        int s = rfl(col[j]);
        float w = dinv[s] * dd;
        if (act) {
            float4 v = h4[(size_t)s * 39 + lane];
            ax += v.x * w; ay += v.y * w; az += v.z * w; aw += v.w * w;
        }
    }
    if (act) {
        float sn = dd * dd;
        float4 v = h4[(size_t)d * 39 + lane];
        float4 bb = ((const float4*)b1)[lane];
        float4 o;
        o.x = leaky(ax + v.x * sn + bb.x, 0.01f);
        o.y = leaky(ay + v.y * sn + bb.y, 0.01f);
        o.z = leaky(az + v.z * sn + bb.z, 0.01f);
        o.w = leaky(aw + v.w * sn + bb.w, 0.01f);
        ((float4*)h_act)[(size_t)d * 39 + lane] = o;
    }
}

// ---------------- GAT attention coefficients (one wave per node, both heads) ----------------
__global__ void att_kernel(const float* __restrict__ g, const float* __restrict__ att_src,
                           const float* __restrict__ att_dst, float2* __restrict__ a_src,
                           float2* __restrict__ a_dst, int N) {
    int wid  = (blockIdx.x * blockDim.x + threadIdx.x) >> 6;
    int lane = threadIdx.x & 63;
    if (wid >= N) return;
    const float* grow = g + (size_t)wid * C2;
    float vs0 = 0.f, vs1 = 0.f, vd0 = 0.f, vd1 = 0.f;
    #pragma unroll
    for (int k = 0; k < 5; k++) {
        int c = lane + 64 * k;
        if (c < C2) {
            float gv = grow[c];
            float sw = att_src[c];
            float dw = att_dst[c];
            if (c < F_MID) { vs0 += gv * sw; vd0 += gv * dw; }
            else           { vs1 += gv * sw; vd1 += gv * dw; }
        }
    }
    #pragma unroll
    for (int off = 32; off; off >>= 1) {
        vs0 += __shfl_xor(vs0, off);
        vs1 += __shfl_xor(vs1, off);
        vd0 += __shfl_xor(vd0, off);
        vd1 += __shfl_xor(vd1, off);
    }
    if (lane == 0) {
        float2 s; s.x = vs0; s.y = vs1;
        float2 t; t.x = vd0; t.y = vd1;
        a_src[wid] = s;
        a_dst[wid] = t;
    }
}

// ---------------- GAT: per-dst online max+sum, then per-slot weights ----------------
// minv[d] = (m0, 1/s0, m1, 1/s1); wbuf[j] = normalized alpha for CSR slot j
__global__ void gat_msw_kernel(const float2* __restrict__ a_src, const float2* __restrict__ a_dst,
                               const int* __restrict__ row_ptr, const int* __restrict__ col,
                               float4* __restrict__ minv, float2* __restrict__ wbuf, int N) {
    int wid  = (blockIdx.x * blockDim.x + threadIdx.x) >> 6;
    int lane = threadIdx.x & 63;
    if (wid >= N) return;
    int d  = wid;
    int jb = row_ptr[d], je = row_ptr[d + 1];
    float2 ad = a_dst[d];
    float2 asd = a_src[d];
    float es0 = leaky(asd.x + ad.x, 0.2f);   // self-loop logits
    float es1 = leaky(asd.y + ad.y, 0.2f);

    float m0 = NEG_SENTINEL, s0 = 0.f, m1 = NEG_SENTINEL, s1 = 0.f;
    for (int j = jb + lane; j < je; j += 64) {
        float2 as = a_src[col[j]];
        float e0 = leaky(as.x + ad.x, 0.2f);
        float e1 = leaky(as.y + ad.y, 0.2f);
        float nm0 = fmaxf(m0, e0); s0 = s0 * __expf(m0 - nm0) + __expf(e0 - nm0); m0 = nm0;
        float nm1 = fmaxf(m1, e1); s1 = s1 * __expf(m1 - nm1) + __expf(e1 - nm1); m1 = nm1;
    }
    #pragma unroll
    for (int off = 32; off; off >>= 1) {
        float om0 = __shfl_xor(m0, off), os0 = __shfl_xor(s0, off);
        float om1 = __shfl_xor(m1, off), os1 = __shfl_xor(s1, off);
        float nm0 = fmaxf(m0, om0);
        s0 = s0 * __expf(m0 - nm0) + os0 * __expf(om0 - nm0); m0 = nm0;
        float nm1 = fmaxf(m1, om1);
        s1 = s1 * __expf(m1 - nm1) + os1 * __expf(om1 - nm1); m1 = nm1;
    }
    { // fold self-loop
        float nm0 = fmaxf(m0, es0);
        s0 = s0 * __expf(m0 - nm0) + __expf(es0 - nm0); m0 = nm0;
        float nm1 = fmaxf(m1, es1);
        s1 = s1 * __expf(m1 - nm1) + __expf(es1 - nm1); m1 = nm1;
    }
    float i0 = 1.0f / s0, i1 = 1.0f / s1;   // all lanes hold result after butterfly
    if (lane == 0) {
        float4 r; r.x = m0; r.y = i0; r.z = m1; r.w = i1;
        minv[d] = r;
    }
    // second pass: write normalized weights for this row's slots (coalesced-ish)
    for (int j = jb + lane; j < je; j += 64) {
        float2 as = a_src[col[j]];      // L1-hot from first pass
        float2 w;
        w.x = __expf(leaky(as.x + ad.x, 0.2f) - m0) * i0;
        w.y = __expf(leaky(as.y + ad.y, 0.2f) - m1) * i1;
        wbuf[j] = w;
    }
}

// ---------------- GAT gather (float4 rows, x4 edge unroll) ----------------
// chunk0: float4 idx lane (all 64 lanes; head0 iff lane<39)
// chunk1: float4 idx 64+lane (lane<14; always head1)
__global__ void gat_gather_kernel(const float* __restrict__ g, const float2* __restrict__ a_src,
                                  const float2* __restrict__ a_dst, const int* __restrict__ row_ptr,
                                  const int* __restrict__ col, const float2* __restrict__ wbuf,
                                  const float4* __restrict__ minv, float* __restrict__ gout, int N) {
    int wid  = (blockIdx.x * blockDim.x + threadIdx.x) >> 6;
    int lane = threadIdx.x & 63;
    if (wid >= N) return;
    int d  = wid;
    int jb = row_ptr[d], je = row_ptr[d + 1];
    const float4* g4 = (const float4*)g;   // row stride 78
    bool h0   = lane < 39;
    bool act1 = lane < 14;
    float Ax, Ay, Az, Aw;
    float Bx = 0.f, By = 0.f, Bz = 0.f, Bw = 0.f;
    { // self contribution
        float2 ad = a_dst[d];
        float2 asd = a_src[d];
        float4 mv = minv[d];
        float w0 = __expf(leaky(asd.x + ad.x, 0.2f) - mv.x) * mv.y;
        float w1 = __expf(leaky(asd.y + ad.y, 0.2f) - mv.z) * mv.w;
        size_t rb = (size_t)d * 78;
        float4 v = g4[rb + lane];
        float w = h0 ? w0 : w1;
        Ax = v.x * w; Ay = v.y * w; Az = v.z * w; Aw = v.w * w;
        if (act1) {
            float4 u = g4[rb + 64 + lane];
            Bx = u.x * w1; By = u.y * w1; Bz = u.z * w1; Bw = u.w * w1;
        }
    }
    int j = jb;
    for (; j + 3 < je; j += 4) {
        int s0 = rfl(col[j]);
        int s1 = rfl(col[j + 1]);
        int s2 = rfl(col[j + 2]);
        int s3 = rfl(col[j + 3]);
        float2 W0 = wbuf[j], W1v = wbuf[j + 1], W2v = wbuf[j + 2], W3v = wbuf[j + 3];
        size_t r0 = (size_t)s0 * 78, r1 = (size_t)s1 * 78, r2 = (size_t)s2 * 78, r3 = (size_t)s3 * 78;
        float4 v0 = g4[r0 + lane];
        float4 v1 = g4[r1 + lane];
        float4 v2 = g4[r2 + lane];
        float4 v3 = g4[r3 + lane];
        float wa = h0 ? W0.x : W0.y;
        float wb = h0 ? W1v.x : W1v.y;
        float wc = h0 ? W2v.x : W2v.y;
        float wd = h0 ? W3v.x : W3v.y;
        Ax += v0.x * wa + v1.x * wb + v2.x * wc + v3.x * wd;
        Ay += v0.y * wa + v1.y * wb + v2.y * wc + v3.y * wd;
        Az += v0.z * wa + v1.z * wb + v2.z * wc + v3.z * wd;
        Aw += v0.w * wa + v1.w * wb + v2.w * wc + v3.w * wd;
        if (act1) {
            float4 u0 = g4[r0 + 64 + lane];
            float4 u1 = g4[r1 + 64 + lane];
            float4 u2 = g4[r2 + 64 + lane];
            float4 u3 = g4[r3 + 64 + lane];
            Bx += u0.x * W0.y + u1.x * W1v.y + u2.x * W2v.y + u3.x * W3v.y;
            By += u0.y * W0.y + u1.y * W1v.y + u2.y * W2v.y + u3.y * W3v.y;
            Bz += u0.z * W0.y + u1.z * W1v.y + u2.z * W2v.y + u3.z * W3v.y;
            Bw += u0.w * W0.y + u1.w * W1v.y + u2.w * W2v.y + u3.w * W3v.y;
        }
    }
    for (; j < je; j++) {
        int s = rfl(col[j]);
        float2 w2 = wbuf[j];
        size_t rs = (size_t)s * 78;
        float4 v = g4[rs + lane];
        float w = h0 ? w2.x : w2.y;
        Ax += v.x * w; Ay += v.y * w; Az += v.z * w; Aw += v.w * w;
        if (act1) {
            float4 u = g4[rs + 64 + lane];
            Bx += u.x * w2.y; By += u.y * w2.y; Bz += u.z * w2.y; Bw += u.w * w2.y;
        }
    }
    float4* o4 = (float4*)gout;
    float4 oa; oa.x = Ax; oa.y = Ay; oa.z = Az; oa.w = Aw;
    o4[(size_t)d * 78 + lane] = oa;
    if (act1) {
        float4 ob; ob.x = Bx; ob.y = By; ob.z = Bz; ob.w = Bw;
        o4[(size_t)d * 78 + 64 + lane] = ob;
    }
}

// ---------------- pooling + MLP ----------------

__global__ void starts_kernel(const int* __restrict__ batch, int* __restrict__ starts, int N, int B) {
    int b = blockIdx.x * blockDim.x + threadIdx.x;
    if (b > B) return;
    if (b == B) { starts[B] = N; return; }
    int lo = 0, hi = N;
    while (lo < hi) {
        int mid = (lo + hi) >> 1;
        if (batch[mid] < b) lo = mid + 1; else hi = mid;
    }
    starts[b] = lo;
}

// p0[b,:] = leaky(max_n gout[n,:] + b2, 0.01); float4 columns, 4-deep unroll
__global__ void pool_kernel(const float* __restrict__ gout, const float* __restrict__ b2,
                            const int* __restrict__ starts, float* __restrict__ p0) {
    int b = blockIdx.x;
    int t = threadIdx.x;   // block 128; t<78 active
    if (t >= 78) return;
    int s = starts[b], e = starts[b + 1];
    const float4* g4 = (const float4*)gout;
    float4 m0, m1, m2, m3;
    m0.x = m0.y = m0.z = m0.w = -INFINITY;
    m1 = m0; m2 = m0; m3 = m0;
    int n = s;
    for (; n + 3 < e; n += 4) {
        float4 v0 = g4[(size_t)(n + 0) * 78 + t];
        float4 v1 = g4[(size_t)(n + 1) * 78 + t];
        float4 v2 = g4[(size_t)(n + 2) * 78 + t];
        float4 v3 = g4[(size_t)(n + 3) * 78 + t];
        m0.x = fmaxf(m0.x, v0.x); m0.y = fmaxf(m0.y, v0.y); m0.z = fmaxf(m0.z, v0.z); m0.w = fmaxf(m0.w, v0.w);
        m1.x = fmaxf(m1.x, v1.x); m1.y = fmaxf(m1.y, v1.y); m1.z = fmaxf(m1.z, v1.z); m1.w = fmaxf(m1.w, v1.w);
        m2.x = fmaxf(m2.x, v2.x); m2.y = fmaxf(m2.y, v2.y); m2.z = fmaxf(m2.z, v2.z); m2.w = fmaxf(m2.w, v2.w);
        m3.x = fmaxf(m3.x, v3.x); m3.y = fmaxf(m3.y, v3.y); m3.z = fmaxf(m3.z, v3.z); m3.w = fmaxf(m3.w, v3.w);
    }
    for (; n < e; n++) {
        float4 v = g4[(size_t)n * 78 + t];
        m0.x = fmaxf(m0.x, v.x); m0.y = fmaxf(m0.y, v.y); m0.z = fmaxf(m0.z, v.z); m0.w = fmaxf(m0.w, v.w);
    }
    m0.x = fmaxf(fmaxf(m0.x, m1.x), fmaxf(m2.x, m3.x));
    m0.y = fmaxf(fmaxf(m0.y, m1.y), fmaxf(m2.y, m3.y));
    m0.z = fmaxf(fmaxf(m0.z, m1.z), fmaxf(m2.z, m3.z));
    m0.w = fmaxf(fmaxf(m0.w, m1.w), fmaxf(m2.w, m3.w));
    float4 bb = ((const float4*)b2)[t];
    float4 o;
    o.x = leaky(m0.x + bb.x, 0.01f);
    o.y = leaky(m0.y + bb.y, 0.01f);
    o.z = leaky(m0.z + bb.z, 0.01f);
    o.w = leaky(m0.w + bb.w, 0.01f);
    ((float4*)p0)[(size_t)b * 78 + t] = o;
}

// generic dense layer: out[b,c] = act(in[b,:KDIM] . W[:,c] + bias[c])
// ACT: 0 none, 1 leaky 0.01, 2 relu
template <int KDIM, int ACT>
__global__ void fc_kernel(const float* __restrict__ in, const float* __restrict__ W,
                          const float* __restrict__ bias, float* __restrict__ out,
                          int Bn, int OUT) {
    int idx = blockIdx.x * blockDim.x + threadIdx.x;
    if (idx >= Bn * OUT) return;
    int b = idx / OUT, c = idx % OUT;
    const float* irow = in + (size_t)b * KDIM;
    float acc = bias[c];
    #pragma unroll 4
    for (int k = 0; k < KDIM; k++) acc += irow[k] * W[(size_t)k * OUT + c];
    if (ACT == 1) acc = leaky(acc, 0.01f);
    if (ACT == 2) acc = fmaxf(acc, 0.f);
    out[idx] = acc;
}

extern "C" void kernel_launch(void* const* d_in, const int* in_sizes, int n_in,
                              void* d_out, int out_size, void* d_ws, size_t ws_size,
                              hipStream_t stream) {
    const float* x       = (const float*)d_in[0];
    const int*   ei      = (const int*)d_in[1];
    const int*   batch   = (const int*)d_in[2];
    const float* W1      = (const float*)d_in[3];
    const float* b1      = (const float*)d_in[4];
    const float* W2      = (const float*)d_in[5];
    const float* att_src = (const float*)d_in[6];
    const float* att_dst = (const float*)d_in[7];
    const float* b2      = (const float*)d_in[8];
    const float* Wg      = (const float*)d_in[9];
    const float* bg      = (const float*)d_in[10];
    const float* Wf1     = (const float*)d_in[11];
    const float* bf1     = (const float*)d_in[12];
    const float* Wf2     = (const float*)d_in[13];
    const float* bf2     = (const float*)d_in[14];
    const float* Wo      = (const float*)d_in[15];
    const float* bo      = (const float*)d_in[16];
    float* out = (float*)d_out;

    const int N  = in_sizes[0] / F_INP;
    const int E  = in_sizes[1] / 2;
    const int Bn = out_size;          // 128 graphs

    // ---- workspace carving (16B-aligned slices) ----
    char* base = (char*)d_ws;
    size_t off = 0;
    auto take = [&](size_t bytes) -> void* {
        off = (off + 15) & ~(size_t)15;
        void* p = base + off;
        off += bytes;
        return p;
    };
    float*  g       = (float*)take((size_t)C2 * N * 4);      // lives whole pipeline
    float*  AA      = (float*)take((size_t)C2 * N * 4);      // h_lin|h_act early, gout late
    float*  h_lin   = AA;
    float*  h_act   = AA + (size_t)F_MID * N;
    float*  gout    = AA;                                    // alias after lin2
    float4* minv    = (float4*)take((size_t)N * 16);
    float2* a_src   = (float2*)take((size_t)N * 8);
    float2* a_dst   = (float2*)take((size_t)N * 8);
    float2* wbuf    = (float2*)take((size_t)E * 8);
    float*  dinv    = (float*)take((size_t)N * 4);
    int*    deg_i   = (int*)take((size_t)N * 4);
    int*    row_ptr = (int*)take((size_t)(N + 1) * 4);
    int*    cursor  = (int*)take((size_t)N * 4);
    int*    col     = (int*)take((size_t)E * 4);
    int*    starts  = (int*)take((size_t)(Bn + 1) * 4);
    float*  p0      = (float*)take((size_t)Bn * C2 * 4);
    float*  p1      = (float*)take((size_t)Bn * GDIM * 4);
    float*  p2      = (float*)take((size_t)Bn * F1D * 4);
    float*  p3      = (float*)take((size_t)Bn * F2D * 4);

    hipMemsetAsync(deg_i, 0, (size_t)N * sizeof(int), stream);

    // segment starts (only depends on batch)
    starts_kernel<<<1, 256, 0, stream>>>(batch, starts, N, Bn);

    // CSR build
    deg_count_kernel<<<(E + 255) / 256, 256, 0, stream>>>(ei, deg_i, E);
    scan_kernel<<<1, 1024, 0, stream>>>(deg_i, row_ptr, cursor, dinv, N);
    fill_csr_kernel<<<(E + 255) / 256, 256, 0, stream>>>(ei, cursor, col, E);

    // GCN
    lin1_kernel<<<(N + 15) / 16, 192, 0, stream>>>(x, W1, h_lin, N);
    gcn_gather_kernel<<<(N + 3) / 4, 256, 0, stream>>>(h_lin, row_ptr, col, dinv, b1, h_act, N);

    // GAT
    lin2_kernel<<<(N + 15) / 16, 320, 0, stream>>>(h_act, W2, g, N);
    att_kernel<<<(N + 3) / 4, 256, 0, stream>>>(g, att_src, att_dst, a_src, a_dst, N);
    gat_msw_kernel<<<(N + 3) / 4, 256, 0, stream>>>(a_src, a_dst, row_ptr, col, minv, wbuf, N);
    gat_gather_kernel<<<(N + 3) / 4, 256, 0, stream>>>(g, a_src, a_dst, row_ptr, col, wbuf, minv, gout, N);

    // pool + MLP
    pool_kernel<<<Bn, 128, 0, stream>>>(gout, b2, starts, p0);
    fc_kernel<C2, 1><<<(Bn * GDIM + 255) / 256, 256, 0, stream>>>(p0, Wg, bg, p1, Bn, GDIM);
    fc_kernel<GDIM, 2><<<(Bn * F1D + 255) / 256, 256, 0, stream>>>(p1, Wf1, bf1, p2, Bn, F1D);
    fc_kernel<F1D, 2><<<(Bn * F2D + 255) / 256, 256, 0, stream>>>(p2, Wf2, bf2, p3, Bn, F2D);
    fc_kernel<F2D, 0><<<1, 128, 0, stream>>>(p3, Wo, bo, out, Bn, 1);
}

// Round 8
// 853.693 us; speedup vs baseline: 1.1657x; 1.1289x over previous
//
#include <hip/hip_runtime.h>
#include <cstdint>
#include <cstddef>

// ---- problem constants (from reference) ----
#define F_INP 78
#define F_MID 156
#define C2    312   // HEADS*F_MID
#define GDIM  128
#define F1D   1024
#define F2D   512

#define NEG_SENTINEL -1e30f

typedef _Float16 half_t;
typedef _Float16 half8 __attribute__((ext_vector_type(8)));

__device__ __forceinline__ float leaky(float v, float s) { return v > 0.f ? v : s * v; }
__device__ __forceinline__ int rfl(int v) { return __builtin_amdgcn_readfirstlane(v); }

// ---------------- CSR construction ----------------

__global__ void deg_count_kernel(const int* __restrict__ ei, int* __restrict__ deg, int E) {
    int e = blockIdx.x * blockDim.x + threadIdx.x;
    if (e >= E) return;
    atomicAdd(&deg[ei[E + e]], 1);
}

// single-block scan: deg[N] -> row_ptr[N+1]; also emits cursor copy and dinv
__global__ void scan_kernel(const int* __restrict__ deg, int* __restrict__ row_ptr,
                            int* __restrict__ cursor, float* __restrict__ dinv, int N) {
    __shared__ int sums[1024];
    int tid = threadIdx.x;
    int chunk = (N + 1023) / 1024;
    int start = tid * chunk;
    int end = start + chunk;
    if (start > N) start = N;
    if (end > N) end = N;
    int s = 0;
    for (int i = start; i < end; i++) s += deg[i];
    sums[tid] = s;
    __syncthreads();
    for (int off = 1; off < 1024; off <<= 1) {
        int v = (tid >= off) ? sums[tid - off] : 0;
        __syncthreads();
        sums[tid] += v;
        __syncthreads();
    }
    int run = (tid == 0) ? 0 : sums[tid - 1];
    for (int i = start; i < end; i++) {
        int dg = deg[i];
        row_ptr[i] = run;
        cursor[i] = run;
        dinv[i] = rsqrtf((float)dg + 1.0f);
        run += dg;
    }
    if (tid == 1023) row_ptr[N] = run;
}

// fill col[] (src per CSR slot)
__global__ void fill_csr_kernel(const int* __restrict__ ei, int* __restrict__ cursor,
                                int* __restrict__ col, int E) {
    int e = blockIdx.x * blockDim.x + threadIdx.x;
    if (e >= E) return;
    int s = ei[e], d = ei[E + e];
    int pos = atomicAdd(&cursor[d], 1);
    col[pos] = s;
}

// ---------------- dense layers ----------------

// h_lin = dinv[n] * (x @ W1)  -> fp16, row stride 160 (pad 156..159 = 0)
// 16 rows/block, block 192
__global__ void lin1_kernel(const float* __restrict__ x, const float* __restrict__ W1,
                            const float* __restrict__ dinv, half_t* __restrict__ h_lin, int N) {
    __shared__ float2 xs[16][39];
    int tid = threadIdx.x;           // 192
    int n0 = blockIdx.x * 16;
    const float2* x2 = (const float2*)x;   // row stride 39 float2
    for (int i = tid; i < 16 * 39; i += 192) {
        int r = i / 39, c = i % 39;
        int n = n0 + r;
        float2 z; z.x = 0.f; z.y = 0.f;
        if (n < N) {
            float dn = dinv[n];
            float2 v = x2[(size_t)n * 39 + c];
            z.x = v.x * dn; z.y = v.y * dn;   // pre-scale by dinv[src]
        }
        xs[r][c] = z;
    }
    __syncthreads();
    if (tid >= 160) return;
    if (tid >= F_MID) {   // zero the pad columns
        for (int r = 0; r < 16; r++) {
            int n = n0 + r;
            if (n < N) h_lin[(size_t)n * 160 + tid] = (half_t)0.f;
        }
        return;
    }
    float acc[16] = {};
    for (int k2 = 0; k2 < 39; k2++) {
        float w0 = W1[(2 * k2) * F_MID + tid];
        float w1 = W1[(2 * k2 + 1) * F_MID + tid];
        #pragma unroll
        for (int r = 0; r < 16; r++) {
            float2 xv = xs[r][k2];
            acc[r] += xv.x * w0 + xv.y * w1;
        }
    }
    #pragma unroll
    for (int r = 0; r < 16; r++) {
        int n = n0 + r;
        if (n < N) h_lin[(size_t)n * 160 + tid] = (half_t)acc[r];
    }
}

// g = h_act @ W2 -> fp16, row stride 312; 16 rows/block, block 320
__global__ void lin2_kernel(const float* __restrict__ h_act, const float* __restrict__ W2,
                            half_t* __restrict__ g, int N) {
    __shared__ float4 hs[16][39];
    int tid = threadIdx.x;           // 320
    int n0 = blockIdx.x * 16;
    const float4* h4 = (const float4*)h_act;  // row stride 39 float4
    for (int i = tid; i < 16 * 39; i += 320) {
        int r = i / 39, c = i % 39;
        int n = n0 + r;
        float4 z; z.x = z.y = z.z = z.w = 0.f;
        hs[r][c] = (n < N) ? h4[(size_t)n * 39 + c] : z;
    }
    __syncthreads();
    if (tid >= C2) return;
    float acc[16] = {};
    for (int k4 = 0; k4 < 39; k4++) {
        float w0 = W2[(4 * k4 + 0) * C2 + tid];
        float w1 = W2[(4 * k4 + 1) * C2 + tid];
        float w2 = W2[(4 * k4 + 2) * C2 + tid];
        float w3 = W2[(4 * k4 + 3) * C2 + tid];
        #pragma unroll
        for (int r = 0; r < 16; r++) {
            float4 xv = hs[r][k4];
            acc[r] += xv.x * w0 + xv.y * w1 + xv.z * w2 + xv.w * w3;
        }
    }
    #pragma unroll
    for (int r = 0; r < 16; r++) {
        int n = n0 + r;
        if (n < N) g[(size_t)n * C2 + tid] = (half_t)acc[r];
    }
}

// ---------------- GCN gather (fp16 rows, pure sum; dinv pre-applied) ----------------
// h_act[d,f] = leaky( dd*( sum_in h_lin[s,f] + h_lin[d,f] ) + b1[f], 0.01 ), dd=dinv[d]
__global__ void gcn_gather_kernel(const half_t* __restrict__ h_lin, const int* __restrict__ row_ptr,
                                  const int* __restrict__ col, const float* __restrict__ dinv,
                                  const float* __restrict__ b1, float* __restrict__ h_act, int N) {
    int wid  = (blockIdx.x * blockDim.x + threadIdx.x) >> 6;
    int lane = threadIdx.x & 63;
    if (wid >= N) return;
    int d  = wid;
    int jb = row_ptr[d], je = row_ptr[d + 1];
    float dd = dinv[d];
    const half8* h8 = (const half8*)h_lin;  // row stride 20 half8
    bool actv = lane < 20;
    int f0 = lane * 8;
    float acc[8] = {};
    if (actv) {   // self contribution
        half8 v = h8[(size_t)d * 20 + lane];
        #pragma unroll
        for (int e = 0; e < 8; e++) acc[e] = (float)v[e];
    }
    int j = jb;
    for (; j + 3 < je; j += 4) {
        int s0 = rfl(col[j]);
        int s1 = rfl(col[j + 1]);
        int s2 = rfl(col[j + 2]);
        int s3 = rfl(col[j + 3]);
        if (actv) {
            half8 v0 = h8[(size_t)s0 * 20 + lane];
            half8 v1 = h8[(size_t)s1 * 20 + lane];
            half8 v2 = h8[(size_t)s2 * 20 + lane];
            half8 v3 = h8[(size_t)s3 * 20 + lane];
            #pragma unroll
            for (int e = 0; e < 8; e++)
                acc[e] += (float)v0[e] + (float)v1[e] + (float)v2[e] + (float)v3[e];
        }
    }
    for (; j < je; j++) {
        int s = rfl(col[j]);
        if (actv) {
            half8 v = h8[(size_t)s * 20 + lane];
            #pragma unroll
            for (int e = 0; e < 8; e++) acc[e] += (float)v[e];
        }
    }
    if (actv) {
        float4 b0 = *(const float4*)(b1 + f0);
        float4 o0;
        o0.x = leaky(dd * acc[0] + b0.x, 0.01f);
        o0.y = leaky(dd * acc[1] + b0.y, 0.01f);
        o0.z = leaky(dd * acc[2] + b0.z, 0.01f);
        o0.w = leaky(dd * acc[3] + b0.w, 0.01f);
        *(float4*)(h_act + (size_t)d * F_MID + f0) = o0;
        if (lane < 19) {   // f0+4..f0+7 < 156
            float4 b1v = *(const float4*)(b1 + f0 + 4);
            float4 o1;
            o1.x = leaky(dd * acc[4] + b1v.x, 0.01f);
            o1.y = leaky(dd * acc[5] + b1v.y, 0.01f);
            o1.z = leaky(dd * acc[6] + b1v.z, 0.01f);
            o1.w = leaky(dd * acc[7] + b1v.w, 0.01f);
            *(float4*)(h_act + (size_t)d * F_MID + f0 + 4) = o1;
        }
    }
}

// ---------------- GAT attention coefficients (fp16 g) ----------------
__global__ void att_kernel(const half_t* __restrict__ g, const float* __restrict__ att_src,
                           const float* __restrict__ att_dst, float2* __restrict__ a_src,
                           float2* __restrict__ a_dst, int N) {
    int wid  = (blockIdx.x * blockDim.x + threadIdx.x) >> 6;
    int lane = threadIdx.x & 63;
    if (wid >= N) return;
    const half8* g8 = (const half8*)g;   // row stride 39
    float vs0 = 0.f, vs1 = 0.f, vd0 = 0.f, vd1 = 0.f;
    if (lane < 39) {
        half8 v = g8[(size_t)wid * 39 + lane];
        int f0 = lane * 8;
        #pragma unroll
        for (int e = 0; e < 8; e++) {
            int f = f0 + e;
            float gv = (float)v[e];
            float sw = att_src[f];
            float dw = att_dst[f];
            if (f < F_MID) { vs0 += gv * sw; vd0 += gv * dw; }
            else           { vs1 += gv * sw; vd1 += gv * dw; }
        }
    }
    #pragma unroll
    for (int off = 32; off; off >>= 1) {
        vs0 += __shfl_xor(vs0, off);
        vs1 += __shfl_xor(vs1, off);
        vd0 += __shfl_xor(vd0, off);
        vd1 += __shfl_xor(vd1, off);
    }
    if (lane == 0) {
        float2 s; s.x = vs0; s.y = vs1;
        float2 t; t.x = vd0; t.y = vd1;
        a_src[wid] = s;
        a_dst[wid] = t;
    }
}

// ---------------- GAT: per-dst online max+sum, then per-slot weights ----------------
__global__ void gat_msw_kernel(const float2* __restrict__ a_src, const float2* __restrict__ a_dst,
                               const int* __restrict__ row_ptr, const int* __restrict__ col,
                               float4* __restrict__ minv, float2* __restrict__ wbuf, int N) {
    int wid  = (blockIdx.x * blockDim.x + threadIdx.x) >> 6;
    int lane = threadIdx.x & 63;
    if (wid >= N) return;
    int d  = wid;
    int jb = row_ptr[d], je = row_ptr[d + 1];
    float2 ad = a_dst[d];
    float2 asd = a_src[d];
    float es0 = leaky(asd.x + ad.x, 0.2f);   // self-loop logits
    float es1 = leaky(asd.y + ad.y, 0.2f);

    float m0 = NEG_SENTINEL, s0 = 0.f, m1 = NEG_SENTINEL, s1 = 0.f;
    for (int j = jb + lane; j < je; j += 64) {
        float2 as = a_src[col[j]];
        float e0 = leaky(as.x + ad.x, 0.2f);
        float e1 = leaky(as.y + ad.y, 0.2f);
        float nm0 = fmaxf(m0, e0); s0 = s0 * __expf(m0 - nm0) + __expf(e0 - nm0); m0 = nm0;
        float nm1 = fmaxf(m1, e1); s1 = s1 * __expf(m1 - nm1) + __expf(e1 - nm1); m1 = nm1;
    }
    #pragma unroll
    for (int off = 32; off; off >>= 1) {
        float om0 = __shfl_xor(m0, off), os0 = __shfl_xor(s0, off);
        float om1 = __shfl_xor(m1, off), os1 = __shfl_xor(s1, off);
        float nm0 = fmaxf(m0, om0);
        s0 = s0 * __expf(m0 - nm0) + os0 * __expf(om0 - nm0); m0 = nm0;
        float nm1 = fmaxf(m1, om1);
        s1 = s1 * __expf(m1 - nm1) + os1 * __expf(om1 - nm1); m1 = nm1;
    }
    { // fold self-loop
        float nm0 = fmaxf(m0, es0);
        s0 = s0 * __expf(m0 - nm0) + __expf(es0 - nm0); m0 = nm0;
        float nm1 = fmaxf(m1, es1);
        s1 = s1 * __expf(m1 - nm1) + __expf(es1 - nm1); m1 = nm1;
    }
    float i0 = 1.0f / s0, i1 = 1.0f / s1;
    if (lane == 0) {
        float4 r; r.x = m0; r.y = i0; r.z = m1; r.w = i1;
        minv[d] = r;
    }
    for (int j = jb + lane; j < je; j += 64) {
        float2 as = a_src[col[j]];      // L1-hot from first pass
        float2 w;
        w.x = __expf(leaky(as.x + ad.x, 0.2f) - m0) * i0;
        w.y = __expf(leaky(as.y + ad.y, 0.2f) - m1) * i1;
        wbuf[j] = w;
    }
}

// ---------------- GAT gather (fp16 rows, one load/edge, x4 unroll) ----------------
// lane<39: half8 covering feats f0=8*lane .. f0+7; head select per 4-group
__global__ void gat_gather_kernel(const half_t* __restrict__ g, const float2* __restrict__ a_src,
                                  const float2* __restrict__ a_dst, const int* __restrict__ row_ptr,
                                  const int* __restrict__ col, const float2* __restrict__ wbuf,
                                  const float4* __restrict__ minv, float* __restrict__ gout, int N) {
    int wid  = (blockIdx.x * blockDim.x + threadIdx.x) >> 6;
    int lane = threadIdx.x & 63;
    if (wid >= N) return;
    int d  = wid;
    int jb = row_ptr[d], je = row_ptr[d + 1];
    const half8* g8 = (const half8*)g;   // row stride 39
    bool actv = lane < 39;
    int f0 = lane * 8;
    bool lo0 = f0 < F_MID;        // head of first 4 feats
    bool hi0 = (f0 + 4) < F_MID;  // head of last 4 feats
    float acc[8] = {};
    { // self contribution
        float2 ad = a_dst[d];
        float2 asd = a_src[d];
        float4 mv = minv[d];
        float w0 = __expf(leaky(asd.x + ad.x, 0.2f) - mv.x) * mv.y;
        float w1 = __expf(leaky(asd.y + ad.y, 0.2f) - mv.z) * mv.w;
        if (actv) {
            half8 v = g8[(size_t)d * 39 + lane];
            float wlo = lo0 ? w0 : w1;
            float whi = hi0 ? w0 : w1;
            #pragma unroll
            for (int e = 0; e < 4; e++) acc[e] = (float)v[e] * wlo;
            #pragma unroll
            for (int e = 4; e < 8; e++) acc[e] = (float)v[e] * whi;
        }
    }
    int j = jb;
    for (; j + 3 < je; j += 4) {
        int s0 = rfl(col[j]);
        int s1 = rfl(col[j + 1]);
        int s2 = rfl(col[j + 2]);
        int s3 = rfl(col[j + 3]);
        float2 W0 = wbuf[j], W1v = wbuf[j + 1], W2v = wbuf[j + 2], W3v = wbuf[j + 3];
        if (actv) {
            half8 v0 = g8[(size_t)s0 * 39 + lane];
            half8 v1 = g8[(size_t)s1 * 39 + lane];
            half8 v2 = g8[(size_t)s2 * 39 + lane];
            half8 v3 = g8[(size_t)s3 * 39 + lane];
            float a0 = lo0 ? W0.x : W0.y,  b0 = hi0 ? W0.x : W0.y;
            float a1 = lo0 ? W1v.x : W1v.y, b1 = hi0 ? W1v.x : W1v.y;
            float a2 = lo0 ? W2v.x : W2v.y, b2 = hi0 ? W2v.x : W2v.y;
            float a3 = lo0 ? W3v.x : W3v.y, b3 = hi0 ? W3v.x : W3v.y;
            #pragma unroll
            for (int e = 0; e < 4; e++)
                acc[e] += (float)v0[e] * a0 + (float)v1[e] * a1 + (float)v2[e] * a2 + (float)v3[e] * a3;
            #pragma unroll
            for (int e = 4; e < 8; e++)
                acc[e] += (float)v0[e] * b0 + (float)v1[e] * b1 + (float)v2[e] * b2 + (float)v3[e] * b3;
        }
    }
    for (; j < je; j++) {
        int s = rfl(col[j]);
        float2 w2 = wbuf[j];
        if (actv) {
            half8 v = g8[(size_t)s * 39 + lane];
            float wlo = lo0 ? w2.x : w2.y;
            float whi = hi0 ? w2.x : w2.y;
            #pragma unroll
            for (int e = 0; e < 4; e++) acc[e] += (float)v[e] * wlo;
            #pragma unroll
            for (int e = 4; e < 8; e++) acc[e] += (float)v[e] * whi;
        }
    }
    if (actv) {
        float* orow = gout + (size_t)d * C2 + f0;
        float4 o0; o0.x = acc[0]; o0.y = acc[1]; o0.z = acc[2]; o0.w = acc[3];
        float4 o1; o1.x = acc[4]; o1.y = acc[5]; o1.z = acc[6]; o1.w = acc[7];
        *(float4*)orow = o0;
        *(float4*)(orow + 4) = o1;
    }
}

// ---------------- pooling + MLP ----------------

__global__ void starts_kernel(const int* __restrict__ batch, int* __restrict__ starts, int N, int B) {
    int b = blockIdx.x * blockDim.x + threadIdx.x;
    if (b > B) return;
    if (b == B) { starts[B] = N; return; }
    int lo = 0, hi = N;
    while (lo < hi) {
        int mid = (lo + hi) >> 1;
        if (batch[mid] < b) lo = mid + 1; else hi = mid;
    }
    starts[b] = lo;
}

// p0[b,:] = leaky(max_n gout[n,:] + b2, 0.01); float4 columns, 4-deep unroll
__global__ void pool_kernel(const float* __restrict__ gout, const float* __restrict__ b2,
                            const int* __restrict__ starts, float* __restrict__ p0) {
    int b = blockIdx.x;
    int t = threadIdx.x;   // block 128; t<78 active
    if (t >= 78) return;
    int s = starts[b], e = starts[b + 1];
    const float4* g4 = (const float4*)gout;
    float4 m0, m1, m2, m3;
    m0.x = m0.y = m0.z = m0.w = -INFINITY;
    m1 = m0; m2 = m0; m3 = m0;
    int n = s;
    for (; n + 3 < e; n += 4) {
        float4 v0 = g4[(size_t)(n + 0) * 78 + t];
        float4 v1 = g4[(size_t)(n + 1) * 78 + t];
        float4 v2 = g4[(size_t)(n + 2) * 78 + t];
        float4 v3 = g4[(size_t)(n + 3) * 78 + t];
        m0.x = fmaxf(m0.x, v0.x); m0.y = fmaxf(m0.y, v0.y); m0.z = fmaxf(m0.z, v0.z); m0.w = fmaxf(m0.w, v0.w);
        m1.x = fmaxf(m1.x, v1.x); m1.y = fmaxf(m1.y, v1.y); m1.z = fmaxf(m1.z, v1.z); m1.w = fmaxf(m1.w, v1.w);
        m2.x = fmaxf(m2.x, v2.x); m2.y = fmaxf(m2.y, v2.y); m2.z = fmaxf(m2.z, v2.z); m2.w = fmaxf(m2.w, v2.w);
        m3.x = fmaxf(m3.x, v3.x); m3.y = fmaxf(m3.y, v3.y); m3.z = fmaxf(m3.z, v3.z); m3.w = fmaxf(m3.w, v3.w);
    }
    for (; n < e; n++) {
        float4 v = g4[(size_t)n * 78 + t];
        m0.x = fmaxf(m0.x, v.x); m0.y = fmaxf(m0.y, v.y); m0.z = fmaxf(m0.z, v.z); m0.w = fmaxf(m0.w, v.w);
    }
    m0.x = fmaxf(fmaxf(m0.x, m1.x), fmaxf(m2.x, m3.x));
    m0.y = fmaxf(fmaxf(m0.y, m1.y), fmaxf(m2.y, m3.y));
    m0.z = fmaxf(fmaxf(m0.z, m1.z), fmaxf(m2.z, m3.z));
    m0.w = fmaxf(fmaxf(m0.w, m1.w), fmaxf(m2.w, m3.w));
    float4 bb = ((const float4*)b2)[t];
    float4 o;
    o.x = leaky(m0.x + bb.x, 0.01f);
    o.y = leaky(m0.y + bb.y, 0.01f);
    o.z = leaky(m0.z + bb.z, 0.01f);
    o.w = leaky(m0.w + bb.w, 0.01f);
    ((float4*)p0)[(size_t)b * 78 + t] = o;
}

// generic dense layer: out[b,c] = act(in[b,:KDIM] . W[:,c] + bias[c])
// ACT: 0 none, 1 leaky 0.01, 2 relu
template <int KDIM, int ACT>
__global__ void fc_kernel(const float* __restrict__ in, const float* __restrict__ W,
                          const float* __restrict__ bias, float* __restrict__ out,
                          int Bn, int OUT) {
    int idx = blockIdx.x * blockDim.x + threadIdx.x;
    if (idx >= Bn * OUT) return;
    int b = idx / OUT, c = idx % OUT;
    const float* irow = in + (size_t)b * KDIM;
    float acc = bias[c];
    #pragma unroll 4
    for (int k = 0; k < KDIM; k++) acc += irow[k] * W[(size_t)k * OUT + c];
    if (ACT == 1) acc = leaky(acc, 0.01f);
    if (ACT == 2) acc = fmaxf(acc, 0.f);
    out[idx] = acc;
}

extern "C" void kernel_launch(void* const* d_in, const int* in_sizes, int n_in,
                              void* d_out, int out_size, void* d_ws, size_t ws_size,
                              hipStream_t stream) {
    const float* x       = (const float*)d_in[0];
    const int*   ei      = (const int*)d_in[1];
    const int*   batch   = (const int*)d_in[2];
    const float* W1      = (const float*)d_in[3];
    const float* b1      = (const float*)d_in[4];
    const float* W2      = (const float*)d_in[5];
    const float* att_src = (const float*)d_in[6];
    const float* att_dst = (const float*)d_in[7];
    const float* b2      = (const float*)d_in[8];
    const float* Wg      = (const float*)d_in[9];
    const float* bg      = (const float*)d_in[10];
    const float* Wf1     = (const float*)d_in[11];
    const float* bf1     = (const float*)d_in[12];
    const float* Wf2     = (const float*)d_in[13];
    const float* bf2     = (const float*)d_in[14];
    const float* Wo      = (const float*)d_in[15];
    const float* bo      = (const float*)d_in[16];
    float* out = (float*)d_out;

    const int N  = in_sizes[0] / F_INP;
    const int E  = in_sizes[1] / 2;
    const int Bn = out_size;          // 128 graphs

    // ---- workspace carving (16B-aligned slices) ----
    char* base = (char*)d_ws;
    size_t off = 0;
    auto take = [&](size_t bytes) -> void* {
        off = (off + 15) & ~(size_t)15;
        void* p = base + off;
        off += bytes;
        return p;
    };
    half_t* g      = (half_t*)take((size_t)C2 * N * 2);      // fp16, stride 312
    char*   AA     = (char*)take((size_t)C2 * N * 4);        // h_lin|h_act early, gout late
    half_t* h_lin  = (half_t*)AA;                            //   N*160 fp16 (16 MB)
    float*  h_act  = (float*)(AA + (size_t)160 * N * 2);     //   N*156 fp32 (31 MB)
    float*  gout   = (float*)AA;                             //   N*312 fp32 (62 MB, alias)
    float4* minv   = (float4*)take((size_t)N * 16);
    float2* a_src  = (float2*)take((size_t)N * 8);
    float2* a_dst  = (float2*)take((size_t)N * 8);
    float2* wbuf   = (float2*)take((size_t)E * 8);
    float*  dinv   = (float*)take((size_t)N * 4);
    int*    deg_i  = (int*)take((size_t)N * 4);
    int*    row_ptr= (int*)take((size_t)(N + 1) * 4);
    int*    cursor = (int*)take((size_t)N * 4);
    int*    col    = (int*)take((size_t)E * 4);
    int*    starts = (int*)take((size_t)(Bn + 1) * 4);
    float*  p0     = (float*)take((size_t)Bn * C2 * 4);
    float*  p1     = (float*)take((size_t)Bn * GDIM * 4);
    float*  p2     = (float*)take((size_t)Bn * F1D * 4);
    float*  p3     = (float*)take((size_t)Bn * F2D * 4);

    hipMemsetAsync(deg_i, 0, (size_t)N * sizeof(int), stream);

    // segment starts (only depends on batch)
    starts_kernel<<<1, 256, 0, stream>>>(batch, starts, N, Bn);

    // CSR build (produces dinv needed by lin1)
    deg_count_kernel<<<(E + 255) / 256, 256, 0, stream>>>(ei, deg_i, E);
    scan_kernel<<<1, 1024, 0, stream>>>(deg_i, row_ptr, cursor, dinv, N);
    fill_csr_kernel<<<(E + 255) / 256, 256, 0, stream>>>(ei, cursor, col, E);

    // GCN
    lin1_kernel<<<(N + 15) / 16, 192, 0, stream>>>(x, W1, dinv, h_lin, N);
    gcn_gather_kernel<<<(N + 3) / 4, 256, 0, stream>>>(h_lin, row_ptr, col, dinv, b1, h_act, N);

    // GAT
    lin2_kernel<<<(N + 15) / 16, 320, 0, stream>>>(h_act, W2, g, N);
    att_kernel<<<(N + 3) / 4, 256, 0, stream>>>(g, att_src, att_dst, a_src, a_dst, N);
    gat_msw_kernel<<<(N + 3) / 4, 256, 0, stream>>>(a_src, a_dst, row_ptr, col, minv, wbuf, N);
    gat_gather_kernel<<<(N + 3) / 4, 256, 0, stream>>>(g, a_src, a_dst, row_ptr, col, wbuf, minv, gout, N);

    // pool + MLP
    pool_kernel<<<Bn, 128, 0, stream>>>(gout, b2, starts, p0);
    fc_kernel<C2, 1><<<(Bn * GDIM + 255) / 256, 256, 0, stream>>>(p0, Wg, bg, p1, Bn, GDIM);
    fc_kernel<GDIM, 2><<<(Bn * F1D + 255) / 256, 256, 0, stream>>>(p1, Wf1, bf1, p2, Bn, F1D);
    fc_kernel<F1D, 2><<<(Bn * F2D + 255) / 256, 256, 0, stream>>>(p2, Wf2, bf2, p3, Bn, F2D);
    fc_kernel<F2D, 0><<<1, 128, 0, stream>>>(p3, Wo, bo, out, Bn, 1);
}

// Round 10
// 753.295 us; speedup vs baseline: 1.3211x; 1.1333x over previous
//
#include <hip/hip_runtime.h>
#include <cstdint>
#include <cstddef>

// ---- problem constants (from reference) ----
#define F_INP 78
#define F_MID 156
#define C2    312   // HEADS*F_MID
#define GDIM  128
#define F1D   1024
#define F2D   512

#define NEG_SENTINEL -1e30f

typedef _Float16 half_t;
typedef _Float16 half8 __attribute__((ext_vector_type(8)));
typedef float f32x4 __attribute__((ext_vector_type(4)));

__device__ __forceinline__ float leaky(float v, float s) { return v > 0.f ? v : s * v; }
__device__ __forceinline__ int rfl(int v) { return __builtin_amdgcn_readfirstlane(v); }

// ---------------- CSR construction ----------------

__global__ void deg_count_kernel(const int* __restrict__ ei, int* __restrict__ deg, int E) {
    int e = blockIdx.x * blockDim.x + threadIdx.x;
    if (e >= E) return;
    atomicAdd(&deg[ei[E + e]], 1);
}

// single-block scan: deg[N] -> row_ptr[N+1]; also emits cursor copy and dinv
__global__ void scan_kernel(const int* __restrict__ deg, int* __restrict__ row_ptr,
                            int* __restrict__ cursor, float* __restrict__ dinv, int N) {
    __shared__ int sums[1024];
    int tid = threadIdx.x;
    int chunk = (N + 1023) / 1024;
    int start = tid * chunk;
    int end = start + chunk;
    if (start > N) start = N;
    if (end > N) end = N;
    int s = 0;
    for (int i = start; i < end; i++) s += deg[i];
    sums[tid] = s;
    __syncthreads();
    for (int off = 1; off < 1024; off <<= 1) {
        int v = (tid >= off) ? sums[tid - off] : 0;
        __syncthreads();
        sums[tid] += v;
        __syncthreads();
    }
    int run = (tid == 0) ? 0 : sums[tid - 1];
    for (int i = start; i < end; i++) {
        int dg = deg[i];
        row_ptr[i] = run;
        cursor[i] = run;
        dinv[i] = rsqrtf((float)dg + 1.0f);
        run += dg;
    }
    if (tid == 1023) row_ptr[N] = run;
}

// fill col[] (src per CSR slot)
__global__ void fill_csr_kernel(const int* __restrict__ ei, int* __restrict__ cursor,
                                int* __restrict__ col, int E) {
    int e = blockIdx.x * blockDim.x + threadIdx.x;
    if (e >= E) return;
    int s = ei[e], d = ei[E + e];
    int pos = atomicAdd(&cursor[d], 1);
    col[pos] = s;
}

// ---------------- dense layers ----------------

// h_lin = dinv[n] * (x @ W1)  -> fp16, row stride 160 (pad 156..159 = 0)
// 16 rows/block, block 192
__global__ void lin1_kernel(const float* __restrict__ x, const float* __restrict__ W1,
                            const float* __restrict__ dinv, half_t* __restrict__ h_lin, int N) {
    __shared__ float2 xs[16][39];
    int tid = threadIdx.x;           // 192
    int n0 = blockIdx.x * 16;
    const float2* x2 = (const float2*)x;   // row stride 39 float2
    for (int i = tid; i < 16 * 39; i += 192) {
        int r = i / 39, c = i % 39;
        int n = n0 + r;
        float2 z; z.x = 0.f; z.y = 0.f;
        if (n < N) {
            float dn = dinv[n];
            float2 v = x2[(size_t)n * 39 + c];
            z.x = v.x * dn; z.y = v.y * dn;   // pre-scale by dinv[src]
        }
        xs[r][c] = z;
    }
    __syncthreads();
    if (tid >= 160) return;
    if (tid >= F_MID) {   // zero the pad columns
        for (int r = 0; r < 16; r++) {
            int n = n0 + r;
            if (n < N) h_lin[(size_t)n * 160 + tid] = (half_t)0.f;
        }
        return;
    }
    float acc[16] = {};
    for (int k2 = 0; k2 < 39; k2++) {
        float w0 = W1[(2 * k2) * F_MID + tid];
        float w1 = W1[(2 * k2 + 1) * F_MID + tid];
        #pragma unroll
        for (int r = 0; r < 16; r++) {
            float2 xv = xs[r][k2];
            acc[r] += xv.x * w0 + xv.y * w1;
        }
    }
    #pragma unroll
    for (int r = 0; r < 16; r++) {
        int n = n0 + r;
        if (n < N) h_lin[(size_t)n * 160 + tid] = (half_t)acc[r];
    }
}

// W2 [156][312] fp32 -> w2t [320][160] fp16 transposed, zero-padded
__global__ void w2t_kernel(const float* __restrict__ W2, half_t* __restrict__ w2t) {
    int idx = blockIdx.x * blockDim.x + threadIdx.x;
    if (idx >= 320 * 160) return;
    int coln = idx / 160, k = idx % 160;
    float v = (coln < C2 && k < F_MID) ? W2[k * C2 + coln] : 0.f;
    w2t[idx] = (half_t)v;
}

// g = h16 @ W2 via MFMA f16: [N x 160(pad)] @ [160 x 320(pad)] -> fp16 g stride 312
// one wave handles 2 M-tiles (32 rows) x 20 N-tiles, K = 5 steps of 32
// frag maps (cdna4_isa §10 / m89): A row=lane&15, k=(lane>>4)*8+e; B col=lane&15 same k;
//                                   C col=lane&15, row=(lane>>4)*4+j
__global__ void lin2_mfma_kernel(const half_t* __restrict__ h16, const half_t* __restrict__ w2t,
                                 half_t* __restrict__ g, int N) {
    int wid  = (blockIdx.x * blockDim.x + threadIdx.x) >> 6;
    int lane = threadIdx.x & 63;
    int m0 = wid * 32;
    if (m0 >= N) return;
    int rl = lane & 15;          // A row within tile / B col within tile
    int kg = lane >> 4;          // k-group (8 elements each)
    bool has2 = (m0 + 16) < N;

    const half8* hv = (const half8*)h16;   // row stride 20 half8
    const half8* wv = (const half8*)w2t;   // row stride 20 half8 (N-major)
    half8 zz = {(half_t)0.f,(half_t)0.f,(half_t)0.f,(half_t)0.f,
                (half_t)0.f,(half_t)0.f,(half_t)0.f,(half_t)0.f};

    half8 a0[5], a1[5];
    size_t rA = (size_t)(m0 + rl) * 20;
    size_t rB = (size_t)(m0 + 16 + rl) * 20;
    #pragma unroll
    for (int ks = 0; ks < 5; ks++) {
        a0[ks] = hv[rA + ks * 4 + kg];
        a1[ks] = has2 ? hv[rB + ks * 4 + kg] : zz;
    }

    for (int n0 = 0; n0 < 20; n0++) {
        f32x4 c0 = {0.f, 0.f, 0.f, 0.f};
        f32x4 c1 = {0.f, 0.f, 0.f, 0.f};
        size_t wb = (size_t)(n0 * 16 + rl) * 20 + kg;
        #pragma unroll
        for (int ks = 0; ks < 5; ks++) {
            half8 b = wv[wb + ks * 4];
            c0 = __builtin_amdgcn_mfma_f32_16x16x32_f16(a0[ks], b, c0, 0, 0, 0);
            c1 = __builtin_amdgcn_mfma_f32_16x16x32_f16(a1[ks], b, c1, 0, 0, 0);
        }
        int col = n0 * 16 + rl;
        if (col < C2) {
            int r0 = kg * 4;
            #pragma unroll
            for (int j = 0; j < 4; j++) {
                g[(size_t)(m0 + r0 + j) * C2 + col] = (half_t)c0[j];
            }
            if (has2) {
                #pragma unroll
                for (int j = 0; j < 4; j++) {
                    g[(size_t)(m0 + 16 + r0 + j) * C2 + col] = (half_t)c1[j];
                }
            }
        }
    }
}

// ---------------- GCN gather (fp16 rows, pure sum; dinv pre-applied) ----------------
// h16[d,f] = (half) leaky( dd*( sum_in h_lin[s,f] + h_lin[d,f] ) + b1[f], 0.01 ), pad f>=156 = 0
__global__ void gcn_gather_kernel(const half_t* __restrict__ h_lin, const int* __restrict__ row_ptr,
                                  const int* __restrict__ col, const float* __restrict__ dinv,
                                  const float* __restrict__ b1, half_t* __restrict__ h16, int N) {
    int wid  = (blockIdx.x * blockDim.x + threadIdx.x) >> 6;
    int lane = threadIdx.x & 63;
    if (wid >= N) return;
    int d  = wid;
    int jb = row_ptr[d], je = row_ptr[d + 1];
    float dd = dinv[d];
    const half8* h8v = (const half8*)h_lin;  // row stride 20 half8
    bool actv = lane < 20;
    int f0 = lane * 8;
    float acc[8] = {};
    if (actv) {   // self contribution
        half8 v = h8v[(size_t)d * 20 + lane];
        #pragma unroll
        for (int e = 0; e < 8; e++) acc[e] = (float)v[e];
    }
    int j = jb;
    for (; j + 3 < je; j += 4) {
        int s0 = rfl(col[j]);
        int s1 = rfl(col[j + 1]);
        int s2 = rfl(col[j + 2]);
        int s3 = rfl(col[j + 3]);
        if (actv) {
            half8 v0 = h8v[(size_t)s0 * 20 + lane];
            half8 v1 = h8v[(size_t)s1 * 20 + lane];
            half8 v2 = h8v[(size_t)s2 * 20 + lane];
            half8 v3 = h8v[(size_t)s3 * 20 + lane];
            #pragma unroll
            for (int e = 0; e < 8; e++)
                acc[e] += (float)v0[e] + (float)v1[e] + (float)v2[e] + (float)v3[e];
        }
    }
    for (; j < je; j++) {
        int s = rfl(col[j]);
        if (actv) {
            half8 v = h8v[(size_t)s * 20 + lane];
            #pragma unroll
            for (int e = 0; e < 8; e++) acc[e] += (float)v[e];
        }
    }
    if (actv) {
        half8 o;
        #pragma unroll
        for (int e = 0; e < 8; e++) {
            int f = f0 + e;
            float val = 0.f;
            if (f < F_MID) val = leaky(dd * acc[e] + b1[f], 0.01f);
            o[e] = (half_t)val;
        }
        ((half8*)h16)[(size_t)d * 20 + lane] = o;
    }
}

// ---------------- GAT attention coefficients (fp16 g) ----------------
__global__ void att_kernel(const half_t* __restrict__ g, const float* __restrict__ att_src,
                           const float* __restrict__ att_dst, float2* __restrict__ a_src,
                           float2* __restrict__ a_dst, int N) {
    int wid  = (blockIdx.x * blockDim.x + threadIdx.x) >> 6;
    int lane = threadIdx.x & 63;
    if (wid >= N) return;
    const half8* g8 = (const half8*)g;   // row stride 39
    float vs0 = 0.f, vs1 = 0.f, vd0 = 0.f, vd1 = 0.f;
    if (lane < 39) {
        half8 v = g8[(size_t)wid * 39 + lane];
        int f0 = lane * 8;
        #pragma unroll
        for (int e = 0; e < 8; e++) {
            int f = f0 + e;
            float gv = (float)v[e];
            float sw = att_src[f];
            float dw = att_dst[f];
            if (f < F_MID) { vs0 += gv * sw; vd0 += gv * dw; }
            else           { vs1 += gv * sw; vd1 += gv * dw; }
        }
    }
    #pragma unroll
    for (int off = 32; off; off >>= 1) {
        vs0 += __shfl_xor(vs0, off);
        vs1 += __shfl_xor(vs1, off);
        vd0 += __shfl_xor(vd0, off);
        vd1 += __shfl_xor(vd1, off);
    }
    if (lane == 0) {
        float2 s; s.x = vs0; s.y = vs1;
        float2 t; t.x = vd0; t.y = vd1;
        a_src[wid] = s;
        a_dst[wid] = t;
    }
}

// ---------------- GAT: per-dst online max+sum, then per-slot weights ----------------
__global__ void gat_msw_kernel(const float2* __restrict__ a_src, const float2* __restrict__ a_dst,
                               const int* __restrict__ row_ptr, const int* __restrict__ col,
                               float4* __restrict__ minv, float2* __restrict__ wbuf, int N) {
    int wid  = (blockIdx.x * blockDim.x + threadIdx.x) >> 6;
    int lane = threadIdx.x & 63;
    if (wid >= N) return;
    int d  = wid;
    int jb = row_ptr[d], je = row_ptr[d + 1];
    float2 ad = a_dst[d];
    float2 asd = a_src[d];
    float es0 = leaky(asd.x + ad.x, 0.2f);   // self-loop logits
    float es1 = leaky(asd.y + ad.y, 0.2f);

    float m0 = NEG_SENTINEL, s0 = 0.f, m1 = NEG_SENTINEL, s1 = 0.f;
    for (int j = jb + lane; j < je; j += 64) {
        float2 as = a_src[col[j]];
        float e0 = leaky(as.x + ad.x, 0.2f);
        float e1 = leaky(as.y + ad.y, 0.2f);
        float nm0 = fmaxf(m0, e0); s0 = s0 * __expf(m0 - nm0) + __expf(e0 - nm0); m0 = nm0;
        float nm1 = fmaxf(m1, e1); s1 = s1 * __expf(m1 - nm1) + __expf(e1 - nm1); m1 = nm1;
    }
    #pragma unroll
    for (int off = 32; off; off >>= 1) {
        float om0 = __shfl_xor(m0, off), os0 = __shfl_xor(s0, off);
        float om1 = __shfl_xor(m1, off), os1 = __shfl_xor(s1, off);
        float nm0 = fmaxf(m0, om0);
        s0 = s0 * __expf(m0 - nm0) + os0 * __expf(om0 - nm0); m0 = nm0;
        float nm1 = fmaxf(m1, om1);
        s1 = s1 * __expf(m1 - nm1) + os1 * __expf(om1 - nm1); m1 = nm1;
    }
    { // fold self-loop
        float nm0 = fmaxf(m0, es0);
        s0 = s0 * __expf(m0 - nm0) + __expf(es0 - nm0); m0 = nm0;
        float nm1 = fmaxf(m1, es1);
        s1 = s1 * __expf(m1 - nm1) + __expf(es1 - nm1); m1 = nm1;
    }
    float i0 = 1.0f / s0, i1 = 1.0f / s1;
    if (lane == 0) {
        float4 r; r.x = m0; r.y = i0; r.z = m1; r.w = i1;
        minv[d] = r;
    }
    for (int j = jb + lane; j < je; j += 64) {
        float2 as = a_src[col[j]];      // L1-hot from first pass
        float2 w;
        w.x = __expf(leaky(as.x + ad.x, 0.2f) - m0) * i0;
        w.y = __expf(leaky(as.y + ad.y, 0.2f) - m1) * i1;
        wbuf[j] = w;
    }
}

// ---------------- GAT gather (fp16 rows, one load/edge, x4 unroll) ----------------
// lane<39: half8 covering feats f0=8*lane .. f0+7; head select per 4-group
__global__ void gat_gather_kernel(const half_t* __restrict__ g, const float2* __restrict__ a_src,
                                  const float2* __restrict__ a_dst, const int* __restrict__ row_ptr,
                                  const int* __restrict__ col, const float2* __restrict__ wbuf,
                                  const float4* __restrict__ minv, float* __restrict__ gout, int N) {
    int wid  = (blockIdx.x * blockDim.x + threadIdx.x) >> 6;
    int lane = threadIdx.x & 63;
    if (wid >= N) return;
    int d  = wid;
    int jb = row_ptr[d], je = row_ptr[d + 1];
    const half8* g8 = (const half8*)g;   // row stride 39
    bool actv = lane < 39;
    int f0 = lane * 8;
    bool lo0 = f0 < F_MID;        // head of first 4 feats
    bool hi0 = (f0 + 4) < F_MID;  // head of last 4 feats
    float acc[8] = {};
    { // self contribution
        float2 ad = a_dst[d];
        float2 asd = a_src[d];
        float4 mv = minv[d];
        float w0 = __expf(leaky(asd.x + ad.x, 0.2f) - mv.x) * mv.y;
        float w1 = __expf(leaky(asd.y + ad.y, 0.2f) - mv.z) * mv.w;
        if (actv) {
            half8 v = g8[(size_t)d * 39 + lane];
            float wlo = lo0 ? w0 : w1;
            float whi = hi0 ? w0 : w1;
            #pragma unroll
            for (int e = 0; e < 4; e++) acc[e] = (float)v[e] * wlo;
            #pragma unroll
            for (int e = 4; e < 8; e++) acc[e] = (float)v[e] * whi;
        }
    }
    int j = jb;
    for (; j + 3 < je; j += 4) {
        int s0 = rfl(col[j]);
        int s1 = rfl(col[j + 1]);
        int s2 = rfl(col[j + 2]);
        int s3 = rfl(col[j + 3]);
        float2 W0 = wbuf[j], W1v = wbuf[j + 1], W2v = wbuf[j + 2], W3v = wbuf[j + 3];
        if (actv) {
            half8 v0 = g8[(size_t)s0 * 39 + lane];
            half8 v1 = g8[(size_t)s1 * 39 + lane];
            half8 v2 = g8[(size_t)s2 * 39 + lane];
            half8 v3 = g8[(size_t)s3 * 39 + lane];
            float a0 = lo0 ? W0.x : W0.y,  b0 = hi0 ? W0.x : W0.y;
            float a1 = lo0 ? W1v.x : W1v.y, b1 = hi0 ? W1v.x : W1v.y;
            float a2 = lo0 ? W2v.x : W2v.y, b2 = hi0 ? W2v.x : W2v.y;
            float a3 = lo0 ? W3v.x : W3v.y, b3 = hi0 ? W3v.x : W3v.y;
            #pragma unroll
            for (int e = 0; e < 4; e++)
                acc[e] += (float)v0[e] * a0 + (float)v1[e] * a1 + (float)v2[e] * a2 + (float)v3[e] * a3;
            #pragma unroll
            for (int e = 4; e < 8; e++)
                acc[e] += (float)v0[e] * b0 + (float)v1[e] * b1 + (float)v2[e] * b2 + (float)v3[e] * b3;
        }
    }
    for (; j < je; j++) {
        int s = rfl(col[j]);
        float2 w2 = wbuf[j];
        if (actv) {
            half8 v = g8[(size_t)s * 39 + lane];
            float wlo = lo0 ? w2.x : w2.y;
            float whi = hi0 ? w2.x : w2.y;
            #pragma unroll
            for (int e = 0; e < 4; e++) acc[e] += (float)v[e] * wlo;
            #pragma unroll
            for (int e = 4; e < 8; e++) acc[e] += (float)v[e] * whi;
        }
    }
    if (actv) {
        float* orow = gout + (size_t)d * C2 + f0;
        float4 o0; o0.x = acc[0]; o0.y = acc[1]; o0.z = acc[2]; o0.w = acc[3];
        float4 o1; o1.x = acc[4]; o1.y = acc[5]; o1.z = acc[6]; o1.w = acc[7];
        *(float4*)orow = o0;
        *(float4*)(orow + 4) = o1;
    }
}

// ---------------- pooling + MLP ----------------

__global__ void starts_kernel(const int* __restrict__ batch, int* __restrict__ starts, int N, int B) {
    int b = blockIdx.x * blockDim.x + threadIdx.x;
    if (b > B) return;
    if (b == B) { starts[B] = N; return; }
    int lo = 0, hi = N;
    while (lo < hi) {
        int mid = (lo + hi) >> 1;
        if (batch[mid] < b) lo = mid + 1; else hi = mid;
    }
    starts[b] = lo;
}

// p0[b,:] = leaky(max_n gout[n,:] + b2, 0.01); float4 columns, 4-deep unroll
__global__ void pool_kernel(const float* __restrict__ gout, const float* __restrict__ b2,
                            const int* __restrict__ starts, float* __restrict__ p0) {
    int b = blockIdx.x;
    int t = threadIdx.x;   // block 128; t<78 active
    if (t >= 78) return;
    int s = starts[b], e = starts[b + 1];
    const float4* g4 = (const float4*)gout;
    float4 m0, m1, m2, m3;
    m0.x = m0.y = m0.z = m0.w = -INFINITY;
    m1 = m0; m2 = m0; m3 = m0;
    int n = s;
    for (; n + 3 < e; n += 4) {
        float4 v0 = g4[(size_t)(n + 0) * 78 + t];
        float4 v1 = g4[(size_t)(n + 1) * 78 + t];
        float4 v2 = g4[(size_t)(n + 2) * 78 + t];
        float4 v3 = g4[(size_t)(n + 3) * 78 + t];
        m0.x = fmaxf(m0.x, v0.x); m0.y = fmaxf(m0.y, v0.y); m0.z = fmaxf(m0.z, v0.z); m0.w = fmaxf(m0.w, v0.w);
        m1.x = fmaxf(m1.x, v1.x); m1.y = fmaxf(m1.y, v1.y); m1.z = fmaxf(m1.z, v1.z); m1.w = fmaxf(m1.w, v1.w);
        m2.x = fmaxf(m2.x, v2.x); m2.y = fmaxf(m2.y, v2.y); m2.z = fmaxf(m2.z, v2.z); m2.w = fmaxf(m2.w, v2.w);
        m3.x = fmaxf(m3.x, v3.x); m3.y = fmaxf(m3.y, v3.y); m3.z = fmaxf(m3.z, v3.z); m3.w = fmaxf(m3.w, v3.w);
    }
    for (; n < e; n++) {
        float4 v = g4[(size_t)n * 78 + t];
        m0.x = fmaxf(m0.x, v.x); m0.y = fmaxf(m0.y, v.y); m0.z = fmaxf(m0.z, v.z); m0.w = fmaxf(m0.w, v.w);
    }
    m0.x = fmaxf(fmaxf(m0.x, m1.x), fmaxf(m2.x, m3.x));
    m0.y = fmaxf(fmaxf(m0.y, m1.y), fmaxf(m2.y, m3.y));
    m0.z = fmaxf(fmaxf(m0.z, m1.z), fmaxf(m2.z, m3.z));
    m0.w = fmaxf(fmaxf(m0.w, m1.w), fmaxf(m2.w, m3.w));
    float4 bb = ((const float4*)b2)[t];
    float4 o;
    o.x = leaky(m0.x + bb.x, 0.01f);
    o.y = leaky(m0.y + bb.y, 0.01f);
    o.z = leaky(m0.z + bb.z, 0.01f);
    o.w = leaky(m0.w + bb.w, 0.01f);
    ((float4*)p0)[(size_t)b * 78 + t] = o;
}

// generic dense layer: out[b,c] = act(in[b,:KDIM] . W[:,c] + bias[c])
// ACT: 0 none, 1 leaky 0.01, 2 relu
template <int KDIM, int ACT>
__global__ void fc_kernel(const float* __restrict__ in, const float* __restrict__ W,
                          const float* __restrict__ bias, float* __restrict__ out,
                          int Bn, int OUT) {
    int idx = blockIdx.x * blockDim.x + threadIdx.x;
    if (idx >= Bn * OUT) return;
    int b = idx / OUT, c = idx % OUT;
    const float* irow = in + (size_t)b * KDIM;
    float acc = bias[c];
    #pragma unroll 4
    for (int k = 0; k < KDIM; k++) acc += irow[k] * W[(size_t)k * OUT + c];
    if (ACT == 1) acc = leaky(acc, 0.01f);
    if (ACT == 2) acc = fmaxf(acc, 0.f);
    out[idx] = acc;
}

extern "C" void kernel_launch(void* const* d_in, const int* in_sizes, int n_in,
                              void* d_out, int out_size, void* d_ws, size_t ws_size,
                              hipStream_t stream) {
    const float* x       = (const float*)d_in[0];
    const int*   ei      = (const int*)d_in[1];
    const int*   batch   = (const int*)d_in[2];
    const float* W1      = (const float*)d_in[3];
    const float* b1      = (const float*)d_in[4];
    const float* W2      = (const float*)d_in[5];
    const float* att_src = (const float*)d_in[6];
    const float* att_dst = (const float*)d_in[7];
    const float* b2      = (const float*)d_in[8];
    const float* Wg      = (const float*)d_in[9];
    const float* bg      = (const float*)d_in[10];
    const float* Wf1     = (const float*)d_in[11];
    const float* bf1     = (const float*)d_in[12];
    const float* Wf2     = (const float*)d_in[13];
    const float* bf2     = (const float*)d_in[14];
    const float* Wo      = (const float*)d_in[15];
    const float* bo      = (const float*)d_in[16];
    float* out = (float*)d_out;

    const int N  = in_sizes[0] / F_INP;
    const int E  = in_sizes[1] / 2;
    const int Bn = out_size;          // 128 graphs

    // ---- workspace carving (16B-aligned slices) ----
    char* base = (char*)d_ws;
    size_t off = 0;
    auto take = [&](size_t bytes) -> void* {
        off = (off + 15) & ~(size_t)15;
        void* p = base + off;
        off += bytes;
        return p;
    };
    half_t* g      = (half_t*)take((size_t)C2 * N * 2);      // fp16, stride 312
    char*   AA     = (char*)take((size_t)C2 * N * 4);        // h_lin|h16 early, gout late
    half_t* h_lin  = (half_t*)AA;                            //   N*160 fp16 (16 MB)
    half_t* h16    = (half_t*)(AA + (size_t)160 * N * 2);    //   N*160 fp16 (16 MB)
    float*  gout   = (float*)AA;                             //   N*312 fp32 (62 MB, alias)
    half_t* w2t    = (half_t*)take((size_t)320 * 160 * 2);   // W2^T fp16 padded
    float4* minv   = (float4*)take((size_t)N * 16);
    float2* a_src  = (float2*)take((size_t)N * 8);
    float2* a_dst  = (float2*)take((size_t)N * 8);
    float2* wbuf   = (float2*)take((size_t)E * 8);
    float*  dinv   = (float*)take((size_t)N * 4);
    int*    deg_i  = (int*)take((size_t)N * 4);
    int*    row_ptr= (int*)take((size_t)(N + 1) * 4);
    int*    cursor = (int*)take((size_t)N * 4);
    int*    col    = (int*)take((size_t)E * 4);
    int*    starts = (int*)take((size_t)(Bn + 1) * 4);
    float*  p0     = (float*)take((size_t)Bn * C2 * 4);
    float*  p1     = (float*)take((size_t)Bn * GDIM * 4);
    float*  p2     = (float*)take((size_t)Bn * F1D * 4);
    float*  p3     = (float*)take((size_t)Bn * F2D * 4);

    hipMemsetAsync(deg_i, 0, (size_t)N * sizeof(int), stream);

    // independent prep
    starts_kernel<<<1, 256, 0, stream>>>(batch, starts, N, Bn);
    w2t_kernel<<<(320 * 160 + 255) / 256, 256, 0, stream>>>(W2, w2t);

    // CSR build (produces dinv needed by lin1)
    deg_count_kernel<<<(E + 255) / 256, 256, 0, stream>>>(ei, deg_i, E);
    scan_kernel<<<1, 1024, 0, stream>>>(deg_i, row_ptr, cursor, dinv, N);
    fill_csr_kernel<<<(E + 255) / 256, 256, 0, stream>>>(ei, cursor, col, E);

    // GCN
    lin1_kernel<<<(N + 15) / 16, 192, 0, stream>>>(x, W1, dinv, h_lin, N);
    gcn_gather_kernel<<<(N + 3) / 4, 256, 0, stream>>>(h_lin, row_ptr, col, dinv, b1, h16, N);

    // GAT
    {
        int mwaves = (N + 31) / 32;            // one wave per 32 rows
        int blocks = (mwaves + 3) / 4;         // 4 waves per block
        lin2_mfma_kernel<<<blocks, 256, 0, stream>>>(h16, w2t, g, N);
    }
    att_kernel<<<(N + 3) / 4, 256, 0, stream>>>(g, att_src, att_dst, a_src, a_dst, N);
    gat_msw_kernel<<<(N + 3) / 4, 256, 0, stream>>>(a_src, a_dst, row_ptr, col, minv, wbuf, N);
    gat_gather_kernel<<<(N + 3) / 4, 256, 0, stream>>>(g, a_src, a_dst, row_ptr, col, wbuf, minv, gout, N);

    // pool + MLP
    pool_kernel<<<Bn, 128, 0, stream>>>(gout, b2, starts, p0);
    fc_kernel<C2, 1><<<(Bn * GDIM + 255) / 256, 256, 0, stream>>>(p0, Wg, bg, p1, Bn, GDIM);
    fc_kernel<GDIM, 2><<<(Bn * F1D + 255) / 256, 256, 0, stream>>>(p1, Wf1, bf1, p2, Bn, F1D);
    fc_kernel<F1D, 2><<<(Bn * F2D + 255) / 256, 256, 0, stream>>>(p2, Wf2, bf2, p3, Bn, F2D);
    fc_kernel<F2D, 0><<<1, 128, 0, stream>>>(p3, Wo, bo, out, Bn, 1);
}

// Round 11
// 619.324 us; speedup vs baseline: 1.6069x; 1.2163x over previous
//
#include <hip/hip_runtime.h>
#include <cstdint>
#include <cstddef>

// ---- problem constants (from reference) ----
#define F_INP 78
#define F_MID 156
#define C2    312   // HEADS*F_MID
#define GDIM  128
#define F1D   1024
#define F2D   512

#define NEG_SENTINEL -1e30f
#define SCAN_BLOCKS 256

typedef _Float16 half_t;
typedef _Float16 half8 __attribute__((ext_vector_type(8)));
typedef float f32x4 __attribute__((ext_vector_type(4)));

__device__ __forceinline__ float leaky(float v, float s) { return v > 0.f ? v : s * v; }
__device__ __forceinline__ int rfl(int v) { return __builtin_amdgcn_readfirstlane(v); }

// ---------------- CSR construction ----------------

__global__ void deg_count_kernel(const int* __restrict__ ei, int* __restrict__ deg, int E) {
    int e = blockIdx.x * blockDim.x + threadIdx.x;
    if (e >= E) return;
    atomicAdd(&deg[ei[E + e]], 1);
}

// phase 1: per-block partial sums of deg
__global__ void scan_p1_kernel(const int* __restrict__ deg, int* __restrict__ partials, int N) {
    __shared__ int red[256];
    int b = blockIdx.x, t = threadIdx.x;
    int chunk = (N + SCAN_BLOCKS - 1) / SCAN_BLOCKS;
    int start = b * chunk;
    int end = start + chunk; if (end > N) end = N;
    int s = 0;
    for (int i = start + t; i < end; i += 256) s += deg[i];
    red[t] = s;
    __syncthreads();
    for (int off = 128; off; off >>= 1) {
        if (t < off) red[t] += red[t + off];
        __syncthreads();
    }
    if (t == 0) partials[b] = red[0];
}

// phase 2: exclusive scan of the 256 partials (one block)
__global__ void scan_p2_kernel(int* __restrict__ partials) {
    __shared__ int s[SCAN_BLOCKS];
    int t = threadIdx.x;
    s[t] = partials[t];
    __syncthreads();
    for (int off = 1; off < SCAN_BLOCKS; off <<= 1) {
        int v = (t >= off) ? s[t - off] : 0;
        __syncthreads();
        s[t] += v;
        __syncthreads();
    }
    partials[t] = (t == 0) ? 0 : s[t - 1];
}

// phase 3: emit row_ptr / cursor / dinv with block offsets
__global__ void scan_p3_kernel(const int* __restrict__ deg, const int* __restrict__ partials,
                               int* __restrict__ row_ptr, int* __restrict__ cursor,
                               float* __restrict__ dinv, int N, int E) {
    __shared__ int red[256];
    int b = blockIdx.x, t = threadIdx.x;
    int chunk = (N + SCAN_BLOCKS - 1) / SCAN_BLOCKS;
    int start = b * chunk;
    int end = start + chunk; if (end > N) end = N;
    int sub = (chunk + 255) / 256;          // elements per thread (1 for N=50000)
    int ts = start + t * sub;
    int te = ts + sub; if (te > end) te = end; if (ts > end) ts = end;
    int s = 0;
    for (int i = ts; i < te; i++) s += deg[i];
    red[t] = s;
    __syncthreads();
    for (int off = 1; off < 256; off <<= 1) {
        int v = (t >= off) ? red[t - off] : 0;
        __syncthreads();
        red[t] += v;
        __syncthreads();
    }
    int run = partials[b] + ((t == 0) ? 0 : red[t - 1]);
    for (int i = ts; i < te; i++) {
        int dg = deg[i];
        row_ptr[i] = run;
        cursor[i] = run;
        dinv[i] = rsqrtf((float)dg + 1.0f);
        run += dg;
    }
    if (b == 0 && t == 0) row_ptr[N] = E;
}

// fill col[] (src per CSR slot)
__global__ void fill_csr_kernel(const int* __restrict__ ei, int* __restrict__ cursor,
                                int* __restrict__ col, int E) {
    int e = blockIdx.x * blockDim.x + threadIdx.x;
    if (e >= E) return;
    int s = ei[e], d = ei[E + e];
    int pos = atomicAdd(&cursor[d], 1);
    col[pos] = s;
}

// ---------------- dense layers ----------------

// h_lin = dinv[n] * (x @ W1)  -> fp16, row stride 160 (pad 156..159 = 0)
// 16 rows/block, block 192
__global__ void lin1_kernel(const float* __restrict__ x, const float* __restrict__ W1,
                            const float* __restrict__ dinv, half_t* __restrict__ h_lin, int N) {
    __shared__ float2 xs[16][39];
    int tid = threadIdx.x;           // 192
    int n0 = blockIdx.x * 16;
    const float2* x2 = (const float2*)x;   // row stride 39 float2
    for (int i = tid; i < 16 * 39; i += 192) {
        int r = i / 39, c = i % 39;
        int n = n0 + r;
        float2 z; z.x = 0.f; z.y = 0.f;
        if (n < N) {
            float dn = dinv[n];
            float2 v = x2[(size_t)n * 39 + c];
            z.x = v.x * dn; z.y = v.y * dn;   // pre-scale by dinv[src]
        }
        xs[r][c] = z;
    }
    __syncthreads();
    if (tid >= 160) return;
    if (tid >= F_MID) {   // zero the pad columns
        for (int r = 0; r < 16; r++) {
            int n = n0 + r;
            if (n < N) h_lin[(size_t)n * 160 + tid] = (half_t)0.f;
        }
        return;
    }
    float acc[16] = {};
    for (int k2 = 0; k2 < 39; k2++) {
        float w0 = W1[(2 * k2) * F_MID + tid];
        float w1 = W1[(2 * k2 + 1) * F_MID + tid];
        #pragma unroll
        for (int r = 0; r < 16; r++) {
            float2 xv = xs[r][k2];
            acc[r] += xv.x * w0 + xv.y * w1;
        }
    }
    #pragma unroll
    for (int r = 0; r < 16; r++) {
        int n = n0 + r;
        if (n < N) h_lin[(size_t)n * 160 + tid] = (half_t)acc[r];
    }
}

// W2 [156][312] fp32 -> w2t [320][160] fp16 transposed, zero-padded
__global__ void w2t_kernel(const float* __restrict__ W2, half_t* __restrict__ w2t) {
    int idx = blockIdx.x * blockDim.x + threadIdx.x;
    if (idx >= 320 * 160) return;
    int coln = idx / 160, k = idx % 160;
    float v = (coln < C2 && k < F_MID) ? W2[k * C2 + coln] : 0.f;
    w2t[idx] = (half_t)v;
}

// g = h16 @ W2 via MFMA f16: [N x 160(pad)] @ [160 x 320(pad)] -> fp16 g stride 312
__global__ void lin2_mfma_kernel(const half_t* __restrict__ h16, const half_t* __restrict__ w2t,
                                 half_t* __restrict__ g, int N) {
    int wid  = (blockIdx.x * blockDim.x + threadIdx.x) >> 6;
    int lane = threadIdx.x & 63;
    int m0 = wid * 32;
    if (m0 >= N) return;
    int rl = lane & 15;          // A row within tile / B col within tile
    int kg = lane >> 4;          // k-group (8 elements each)
    bool has2 = (m0 + 16) < N;

    const half8* hv = (const half8*)h16;   // row stride 20 half8
    const half8* wv = (const half8*)w2t;   // row stride 20 half8 (N-major)
    half8 zz = {(half_t)0.f,(half_t)0.f,(half_t)0.f,(half_t)0.f,
                (half_t)0.f,(half_t)0.f,(half_t)0.f,(half_t)0.f};

    half8 a0[5], a1[5];
    size_t rA = (size_t)(m0 + rl) * 20;
    size_t rB = (size_t)(m0 + 16 + rl) * 20;
    #pragma unroll
    for (int ks = 0; ks < 5; ks++) {
        a0[ks] = hv[rA + ks * 4 + kg];
        a1[ks] = has2 ? hv[rB + ks * 4 + kg] : zz;
    }

    for (int n0 = 0; n0 < 20; n0++) {
        f32x4 c0 = {0.f, 0.f, 0.f, 0.f};
        f32x4 c1 = {0.f, 0.f, 0.f, 0.f};
        size_t wb = (size_t)(n0 * 16 + rl) * 20 + kg;
        #pragma unroll
        for (int ks = 0; ks < 5; ks++) {
            half8 b = wv[wb + ks * 4];
            c0 = __builtin_amdgcn_mfma_f32_16x16x32_f16(a0[ks], b, c0, 0, 0, 0);
            c1 = __builtin_amdgcn_mfma_f32_16x16x32_f16(a1[ks], b, c1, 0, 0, 0);
        }
        int col = n0 * 16 + rl;
        if (col < C2) {
            int r0 = kg * 4;
            #pragma unroll
            for (int j = 0; j < 4; j++) {
                g[(size_t)(m0 + r0 + j) * C2 + col] = (half_t)c0[j];
            }
            if (has2) {
                #pragma unroll
                for (int j = 0; j < 4; j++) {
                    g[(size_t)(m0 + 16 + r0 + j) * C2 + col] = (half_t)c1[j];
                }
            }
        }
    }
}

// ---------------- GCN gather (fp16 rows, pure sum; dinv pre-applied) ----------------
__global__ void gcn_gather_kernel(const half_t* __restrict__ h_lin, const int* __restrict__ row_ptr,
                                  const int* __restrict__ col, const float* __restrict__ dinv,
                                  const float* __restrict__ b1, half_t* __restrict__ h16, int N) {
    int wid  = (blockIdx.x * blockDim.x + threadIdx.x) >> 6;
    int lane = threadIdx.x & 63;
    if (wid >= N) return;
    int d  = wid;
    int jb = row_ptr[d], je = row_ptr[d + 1];
    float dd = dinv[d];
    const half8* h8v = (const half8*)h_lin;  // row stride 20 half8
    bool actv = lane < 20;
    int f0 = lane * 8;
    float acc[8] = {};
    if (actv) {   // self contribution
        half8 v = h8v[(size_t)d * 20 + lane];
        #pragma unroll
        for (int e = 0; e < 8; e++) acc[e] = (float)v[e];
    }
    int j = jb;
    for (; j + 3 < je; j += 4) {
        int s0 = rfl(col[j]);
        int s1 = rfl(col[j + 1]);
        int s2 = rfl(col[j + 2]);
        int s3 = rfl(col[j + 3]);
        if (actv) {
            half8 v0 = h8v[(size_t)s0 * 20 + lane];
            half8 v1 = h8v[(size_t)s1 * 20 + lane];
            half8 v2 = h8v[(size_t)s2 * 20 + lane];
            half8 v3 = h8v[(size_t)s3 * 20 + lane];
            #pragma unroll
            for (int e = 0; e < 8; e++)
                acc[e] += (float)v0[e] + (float)v1[e] + (float)v2[e] + (float)v3[e];
        }
    }
    for (; j < je; j++) {
        int s = rfl(col[j]);
        if (actv) {
            half8 v = h8v[(size_t)s * 20 + lane];
            #pragma unroll
            for (int e = 0; e < 8; e++) acc[e] += (float)v[e];
        }
    }
    if (actv) {
        half8 o;
        #pragma unroll
        for (int e = 0; e < 8; e++) {
            int f = f0 + e;
            float val = 0.f;
            if (f < F_MID) val = leaky(dd * acc[e] + b1[f], 0.01f);
            o[e] = (half_t)val;
        }
        ((half8*)h16)[(size_t)d * 20 + lane] = o;
    }
}

// ---------------- GAT attention coefficients (fp16 g) ----------------
__global__ void att_kernel(const half_t* __restrict__ g, const float* __restrict__ att_src,
                           const float* __restrict__ att_dst, float2* __restrict__ a_src,
                           float2* __restrict__ a_dst, int N) {
    int wid  = (blockIdx.x * blockDim.x + threadIdx.x) >> 6;
    int lane = threadIdx.x & 63;
    if (wid >= N) return;
    const half8* g8 = (const half8*)g;   // row stride 39
    float vs0 = 0.f, vs1 = 0.f, vd0 = 0.f, vd1 = 0.f;
    if (lane < 39) {
        half8 v = g8[(size_t)wid * 39 + lane];
        int f0 = lane * 8;
        #pragma unroll
        for (int e = 0; e < 8; e++) {
            int f = f0 + e;
            float gv = (float)v[e];
            float sw = att_src[f];
            float dw = att_dst[f];
            if (f < F_MID) { vs0 += gv * sw; vd0 += gv * dw; }
            else           { vs1 += gv * sw; vd1 += gv * dw; }
        }
    }
    #pragma unroll
    for (int off = 32; off; off >>= 1) {
        vs0 += __shfl_xor(vs0, off);
        vs1 += __shfl_xor(vs1, off);
        vd0 += __shfl_xor(vd0, off);
        vd1 += __shfl_xor(vd1, off);
    }
    if (lane == 0) {
        float2 s; s.x = vs0; s.y = vs1;
        float2 t; t.x = vd0; t.y = vd1;
        a_src[wid] = s;
        a_dst[wid] = t;
    }
}

// ---------------- GAT: per-dst online max+sum, then per-slot weights ----------------
__global__ void gat_msw_kernel(const float2* __restrict__ a_src, const float2* __restrict__ a_dst,
                               const int* __restrict__ row_ptr, const int* __restrict__ col,
                               float4* __restrict__ minv, float2* __restrict__ wbuf, int N) {
    int wid  = (blockIdx.x * blockDim.x + threadIdx.x) >> 6;
    int lane = threadIdx.x & 63;
    if (wid >= N) return;
    int d  = wid;
    int jb = row_ptr[d], je = row_ptr[d + 1];
    float2 ad = a_dst[d];
    float2 asd = a_src[d];
    float es0 = leaky(asd.x + ad.x, 0.2f);   // self-loop logits
    float es1 = leaky(asd.y + ad.y, 0.2f);

    float m0 = NEG_SENTINEL, s0 = 0.f, m1 = NEG_SENTINEL, s1 = 0.f;
    for (int j = jb + lane; j < je; j += 64) {
        float2 as = a_src[col[j]];
        float e0 = leaky(as.x + ad.x, 0.2f);
        float e1 = leaky(as.y + ad.y, 0.2f);
        float nm0 = fmaxf(m0, e0); s0 = s0 * __expf(m0 - nm0) + __expf(e0 - nm0); m0 = nm0;
        float nm1 = fmaxf(m1, e1); s1 = s1 * __expf(m1 - nm1) + __expf(e1 - nm1); m1 = nm1;
    }
    #pragma unroll
    for (int off = 32; off; off >>= 1) {
        float om0 = __shfl_xor(m0, off), os0 = __shfl_xor(s0, off);
        float om1 = __shfl_xor(m1, off), os1 = __shfl_xor(s1, off);
        float nm0 = fmaxf(m0, om0);
        s0 = s0 * __expf(m0 - nm0) + os0 * __expf(om0 - nm0); m0 = nm0;
        float nm1 = fmaxf(m1, om1);
        s1 = s1 * __expf(m1 - nm1) + os1 * __expf(om1 - nm1); m1 = nm1;
    }
    { // fold self-loop
        float nm0 = fmaxf(m0, es0);
        s0 = s0 * __expf(m0 - nm0) + __expf(es0 - nm0); m0 = nm0;
        float nm1 = fmaxf(m1, es1);
        s1 = s1 * __expf(m1 - nm1) + __expf(es1 - nm1); m1 = nm1;
    }
    float i0 = 1.0f / s0, i1 = 1.0f / s1;
    if (lane == 0) {
        float4 r; r.x = m0; r.y = i0; r.z = m1; r.w = i1;
        minv[d] = r;
    }
    for (int j = jb + lane; j < je; j += 64) {
        float2 as = a_src[col[j]];      // L1-hot from first pass
        float2 w;
        w.x = __expf(leaky(as.x + ad.x, 0.2f) - m0) * i0;
        w.y = __expf(leaky(as.y + ad.y, 0.2f) - m1) * i1;
        wbuf[j] = w;
    }
}

// ---------------- GAT gather (fp16 rows, one load/edge, x4 unroll) ----------------
__global__ void gat_gather_kernel(const half_t* __restrict__ g, const float2* __restrict__ a_src,
                                  const float2* __restrict__ a_dst, const int* __restrict__ row_ptr,
                                  const int* __restrict__ col, const float2* __restrict__ wbuf,
                                  const float4* __restrict__ minv, float* __restrict__ gout, int N) {
    int wid  = (blockIdx.x * blockDim.x + threadIdx.x) >> 6;
    int lane = threadIdx.x & 63;
    if (wid >= N) return;
    int d  = wid;
    int jb = row_ptr[d], je = row_ptr[d + 1];
    const half8* g8 = (const half8*)g;   // row stride 39
    bool actv = lane < 39;
    int f0 = lane * 8;
    bool lo0 = f0 < F_MID;        // head of first 4 feats
    bool hi0 = (f0 + 4) < F_MID;  // head of last 4 feats
    float acc[8] = {};
    { // self contribution
        float2 ad = a_dst[d];
        float2 asd = a_src[d];
        float4 mv = minv[d];
        float w0 = __expf(leaky(asd.x + ad.x, 0.2f) - mv.x) * mv.y;
        float w1 = __expf(leaky(asd.y + ad.y, 0.2f) - mv.z) * mv.w;
        if (actv) {
            half8 v = g8[(size_t)d * 39 + lane];
            float wlo = lo0 ? w0 : w1;
            float whi = hi0 ? w0 : w1;
            #pragma unroll
            for (int e = 0; e < 4; e++) acc[e] = (float)v[e] * wlo;
            #pragma unroll
            for (int e = 4; e < 8; e++) acc[e] = (float)v[e] * whi;
        }
    }
    int j = jb;
    for (; j + 3 < je; j += 4) {
        int s0 = rfl(col[j]);
        int s1 = rfl(col[j + 1]);
        int s2 = rfl(col[j + 2]);
        int s3 = rfl(col[j + 3]);
        float2 W0 = wbuf[j], W1v = wbuf[j + 1], W2v = wbuf[j + 2], W3v = wbuf[j + 3];
        if (actv) {
            half8 v0 = g8[(size_t)s0 * 39 + lane];
            half8 v1 = g8[(size_t)s1 * 39 + lane];
            half8 v2 = g8[(size_t)s2 * 39 + lane];
            half8 v3 = g8[(size_t)s3 * 39 + lane];
            float a0 = lo0 ? W0.x : W0.y,  b0 = hi0 ? W0.x : W0.y;
            float a1 = lo0 ? W1v.x : W1v.y, b1 = hi0 ? W1v.x : W1v.y;
            float a2 = lo0 ? W2v.x : W2v.y, b2 = hi0 ? W2v.x : W2v.y;
            float a3 = lo0 ? W3v.x : W3v.y, b3 = hi0 ? W3v.x : W3v.y;
            #pragma unroll
            for (int e = 0; e < 4; e++)
                acc[e] += (float)v0[e] * a0 + (float)v1[e] * a1 + (float)v2[e] * a2 + (float)v3[e] * a3;
            #pragma unroll
            for (int e = 4; e < 8; e++)
                acc[e] += (float)v0[e] * b0 + (float)v1[e] * b1 + (float)v2[e] * b2 + (float)v3[e] * b3;
        }
    }
    for (; j < je; j++) {
        int s = rfl(col[j]);
        float2 w2 = wbuf[j];
        if (actv) {
            half8 v = g8[(size_t)s * 39 + lane];
            float wlo = lo0 ? w2.x : w2.y;
            float whi = hi0 ? w2.x : w2.y;
            #pragma unroll
            for (int e = 0; e < 4; e++) acc[e] += (float)v[e] * wlo;
            #pragma unroll
            for (int e = 4; e < 8; e++) acc[e] += (float)v[e] * whi;
        }
    }
    if (actv) {
        float* orow = gout + (size_t)d * C2 + f0;
        float4 o0; o0.x = acc[0]; o0.y = acc[1]; o0.z = acc[2]; o0.w = acc[3];
        float4 o1; o1.x = acc[4]; o1.y = acc[5]; o1.z = acc[6]; o1.w = acc[7];
        *(float4*)orow = o0;
        *(float4*)(orow + 4) = o1;
    }
}

// ---------------- pooling + MLP ----------------

__global__ void starts_kernel(const int* __restrict__ batch, int* __restrict__ starts, int N, int B) {
    int b = blockIdx.x * blockDim.x + threadIdx.x;
    if (b > B) return;
    if (b == B) { starts[B] = N; return; }
    int lo = 0, hi = N;
    while (lo < hi) {
        int mid = (lo + hi) >> 1;
        if (batch[mid] < b) lo = mid + 1; else hi = mid;
    }
    starts[b] = lo;
}

// p0[b,:] = leaky(max_n gout[n,:] + b2, 0.01); float4 columns, 4-deep unroll
__global__ void pool_kernel(const float* __restrict__ gout, const float* __restrict__ b2,
                            const int* __restrict__ starts, float* __restrict__ p0) {
    int b = blockIdx.x;
    int t = threadIdx.x;   // block 128; t<78 active
    if (t >= 78) return;
    int s = starts[b], e = starts[b + 1];
    const float4* g4 = (const float4*)gout;
    float4 m0, m1, m2, m3;
    m0.x = m0.y = m0.z = m0.w = -INFINITY;
    m1 = m0; m2 = m0; m3 = m0;
    int n = s;
    for (; n + 3 < e; n += 4) {
        float4 v0 = g4[(size_t)(n + 0) * 78 + t];
        float4 v1 = g4[(size_t)(n + 1) * 78 + t];
        float4 v2 = g4[(size_t)(n + 2) * 78 + t];
        float4 v3 = g4[(size_t)(n + 3) * 78 + t];
        m0.x = fmaxf(m0.x, v0.x); m0.y = fmaxf(m0.y, v0.y); m0.z = fmaxf(m0.z, v0.z); m0.w = fmaxf(m0.w, v0.w);
        m1.x = fmaxf(m1.x, v1.x); m1.y = fmaxf(m1.y, v1.y); m1.z = fmaxf(m1.z, v1.z); m1.w = fmaxf(m1.w, v1.w);
        m2.x = fmaxf(m2.x, v2.x); m2.y = fmaxf(m2.y, v2.y); m2.z = fmaxf(m2.z, v2.z); m2.w = fmaxf(m2.w, v2.w);
        m3.x = fmaxf(m3.x, v3.x); m3.y = fmaxf(m3.y, v3.y); m3.z = fmaxf(m3.z, v3.z); m3.w = fmaxf(m3.w, v3.w);
    }
    for (; n < e; n++) {
        float4 v = g4[(size_t)n * 78 + t];
        m0.x = fmaxf(m0.x, v.x); m0.y = fmaxf(m0.y, v.y); m0.z = fmaxf(m0.z, v.z); m0.w = fmaxf(m0.w, v.w);
    }
    m0.x = fmaxf(fmaxf(m0.x, m1.x), fmaxf(m2.x, m3.x));
    m0.y = fmaxf(fmaxf(m0.y, m1.y), fmaxf(m2.y, m3.y));
    m0.z = fmaxf(fmaxf(m0.z, m1.z), fmaxf(m2.z, m3.z));
    m0.w = fmaxf(fmaxf(m0.w, m1.w), fmaxf(m2.w, m3.w));
    float4 bb = ((const float4*)b2)[t];
    float4 o;
    o.x = leaky(m0.x + bb.x, 0.01f);
    o.y = leaky(m0.y + bb.y, 0.01f);
    o.z = leaky(m0.z + bb.z, 0.01f);
    o.w = leaky(m0.w + bb.w, 0.01f);
    ((float4*)p0)[(size_t)b * 78 + t] = o;
}

// generic dense layer: out[b,c] = act(in[b,:KDIM] . W[:,c] + bias[c])
// ACT: 0 none, 1 leaky 0.01, 2 relu
template <int KDIM, int ACT>
__global__ void fc_kernel(const float* __restrict__ in, const float* __restrict__ W,
                          const float* __restrict__ bias, float* __restrict__ out,
                          int Bn, int OUT) {
    int idx = blockIdx.x * blockDim.x + threadIdx.x;
    if (idx >= Bn * OUT) return;
    int b = idx / OUT, c = idx % OUT;
    const float* irow = in + (size_t)b * KDIM;
    float acc = bias[c];
    #pragma unroll 4
    for (int k = 0; k < KDIM; k++) acc += irow[k] * W[(size_t)k * OUT + c];
    if (ACT == 1) acc = leaky(acc, 0.01f);
    if (ACT == 2) acc = fmaxf(acc, 0.f);
    out[idx] = acc;
}

extern "C" void kernel_launch(void* const* d_in, const int* in_sizes, int n_in,
                              void* d_out, int out_size, void* d_ws, size_t ws_size,
                              hipStream_t stream) {
    const float* x       = (const float*)d_in[0];
    const int*   ei      = (const int*)d_in[1];
    const int*   batch   = (const int*)d_in[2];
    const float* W1      = (const float*)d_in[3];
    const float* b1      = (const float*)d_in[4];
    const float* W2      = (const float*)d_in[5];
    const float* att_src = (const float*)d_in[6];
    const float* att_dst = (const float*)d_in[7];
    const float* b2      = (const float*)d_in[8];
    const float* Wg      = (const float*)d_in[9];
    const float* bg      = (const float*)d_in[10];
    const float* Wf1     = (const float*)d_in[11];
    const float* bf1     = (const float*)d_in[12];
    const float* Wf2     = (const float*)d_in[13];
    const float* bf2     = (const float*)d_in[14];
    const float* Wo      = (const float*)d_in[15];
    const float* bo      = (const float*)d_in[16];
    float* out = (float*)d_out;

    const int N  = in_sizes[0] / F_INP;
    const int E  = in_sizes[1] / 2;
    const int Bn = out_size;          // 128 graphs

    // ---- workspace carving (16B-aligned slices) ----
    char* base = (char*)d_ws;
    size_t off = 0;
    auto take = [&](size_t bytes) -> void* {
        off = (off + 15) & ~(size_t)15;
        void* p = base + off;
        off += bytes;
        return p;
    };
    half_t* g      = (half_t*)take((size_t)C2 * N * 2);      // fp16, stride 312
    char*   AA     = (char*)take((size_t)C2 * N * 4);        // h_lin|h16 early, gout late
    half_t* h_lin  = (half_t*)AA;                            //   N*160 fp16 (16 MB)
    half_t* h16    = (half_t*)(AA + (size_t)160 * N * 2);    //   N*160 fp16 (16 MB)
    float*  gout   = (float*)AA;                             //   N*312 fp32 (62 MB, alias)
    half_t* w2t    = (half_t*)take((size_t)320 * 160 * 2);   // W2^T fp16 padded
    float4* minv   = (float4*)take((size_t)N * 16);
    float2* a_src  = (float2*)take((size_t)N * 8);
    float2* a_dst  = (float2*)take((size_t)N * 8);
    float2* wbuf   = (float2*)take((size_t)E * 8);
    float*  dinv   = (float*)take((size_t)N * 4);
    int*    deg_i  = (int*)take((size_t)N * 4);
    int*    partials = (int*)take((size_t)SCAN_BLOCKS * 4);
    int*    row_ptr= (int*)take((size_t)(N + 1) * 4);
    int*    cursor = (int*)take((size_t)N * 4);
    int*    col    = (int*)take((size_t)E * 4);
    int*    starts = (int*)take((size_t)(Bn + 1) * 4);
    float*  p0     = (float*)take((size_t)Bn * C2 * 4);
    float*  p1     = (float*)take((size_t)Bn * GDIM * 4);
    float*  p2     = (float*)take((size_t)Bn * F1D * 4);
    float*  p3     = (float*)take((size_t)Bn * F2D * 4);

    hipMemsetAsync(deg_i, 0, (size_t)N * sizeof(int), stream);

    // independent prep
    starts_kernel<<<1, 256, 0, stream>>>(batch, starts, N, Bn);
    w2t_kernel<<<(320 * 160 + 255) / 256, 256, 0, stream>>>(W2, w2t);

    // CSR build (parallel 3-phase scan; produces dinv needed by lin1)
    deg_count_kernel<<<(E + 255) / 256, 256, 0, stream>>>(ei, deg_i, E);
    scan_p1_kernel<<<SCAN_BLOCKS, 256, 0, stream>>>(deg_i, partials, N);
    scan_p2_kernel<<<1, SCAN_BLOCKS, 0, stream>>>(partials);
    scan_p3_kernel<<<SCAN_BLOCKS, 256, 0, stream>>>(deg_i, partials, row_ptr, cursor, dinv, N, E);
    fill_csr_kernel<<<(E + 255) / 256, 256, 0, stream>>>(ei, cursor, col, E);

    // GCN
    lin1_kernel<<<(N + 15) / 16, 192, 0, stream>>>(x, W1, dinv, h_lin, N);
    gcn_gather_kernel<<<(N + 3) / 4, 256, 0, stream>>>(h_lin, row_ptr, col, dinv, b1, h16, N);

    // GAT
    {
        int mwaves = (N + 31) / 32;            // one wave per 32 rows
        int blocks = (mwaves + 3) / 4;         // 4 waves per block
        lin2_mfma_kernel<<<blocks, 256, 0, stream>>>(h16, w2t, g, N);
    }
    att_kernel<<<(N + 3) / 4, 256, 0, stream>>>(g, att_src, att_dst, a_src, a_dst, N);
    gat_msw_kernel<<<(N + 3) / 4, 256, 0, stream>>>(a_src, a_dst, row_ptr, col, minv, wbuf, N);
    gat_gather_kernel<<<(N + 3) / 4, 256, 0, stream>>>(g, a_src, a_dst, row_ptr, col, wbuf, minv, gout, N);

    // pool + MLP
    pool_kernel<<<Bn, 128, 0, stream>>>(gout, b2, starts, p0);
    fc_kernel<C2, 1><<<(Bn * GDIM + 255) / 256, 256, 0, stream>>>(p0, Wg, bg, p1, Bn, GDIM);
    fc_kernel<GDIM, 2><<<(Bn * F1D + 255) / 256, 256, 0, stream>>>(p1, Wf1, bf1, p2, Bn, F1D);
    fc_kernel<F1D, 2><<<(Bn * F2D + 255) / 256, 256, 0, stream>>>(p2, Wf2, bf2, p3, Bn, F2D);
    fc_kernel<F2D, 0><<<1, 128, 0, stream>>>(p3, Wo, bo, out, Bn, 1);
}

// Round 13
// 537.764 us; speedup vs baseline: 1.8506x; 1.1517x over previous
//
#include <hip/hip_runtime.h>
#include <cstdint>
#include <cstddef>

// ---- problem constants (from reference) ----
#define F_INP 78
#define F_MID 156
#define C2    312   // HEADS*F_MID
#define GDIM  128
#define F1D   1024
#define F2D   512

#define NEG_SENTINEL -1e30f
#define SCAN_BLOCKS 256

typedef _Float16 half_t;
typedef _Float16 half8 __attribute__((ext_vector_type(8)));
typedef float f32x4 __attribute__((ext_vector_type(4)));

__device__ __forceinline__ float leaky(float v, float s) { return v > 0.f ? v : s * v; }
__device__ __forceinline__ int rfl(int v) { return __builtin_amdgcn_readfirstlane(v); }

// ---------------- CSR construction ----------------

__global__ void deg_count_kernel(const int* __restrict__ ei, int* __restrict__ deg, int E) {
    int e = blockIdx.x * blockDim.x + threadIdx.x;
    if (e >= E) return;
    atomicAdd(&deg[ei[E + e]], 1);
}

// phase 1: per-block partial sums of deg
__global__ void scan_p1_kernel(const int* __restrict__ deg, int* __restrict__ partials, int N) {
    __shared__ int red[256];
    int b = blockIdx.x, t = threadIdx.x;
    int chunk = (N + SCAN_BLOCKS - 1) / SCAN_BLOCKS;
    int start = b * chunk;
    int end = start + chunk; if (end > N) end = N;
    int s = 0;
    for (int i = start + t; i < end; i += 256) s += deg[i];
    red[t] = s;
    __syncthreads();
    for (int off = 128; off; off >>= 1) {
        if (t < off) red[t] += red[t + off];
        __syncthreads();
    }
    if (t == 0) partials[b] = red[0];
}

// phase 2: exclusive scan of the 256 partials (one block)
__global__ void scan_p2_kernel(int* __restrict__ partials) {
    __shared__ int s[SCAN_BLOCKS];
    int t = threadIdx.x;
    s[t] = partials[t];
    __syncthreads();
    for (int off = 1; off < SCAN_BLOCKS; off <<= 1) {
        int v = (t >= off) ? s[t - off] : 0;
        __syncthreads();
        s[t] += v;
        __syncthreads();
    }
    partials[t] = (t == 0) ? 0 : s[t - 1];
}

// phase 3: emit row_ptr / cursor / dinv with block offsets
__global__ void scan_p3_kernel(const int* __restrict__ deg, const int* __restrict__ partials,
                               int* __restrict__ row_ptr, int* __restrict__ cursor,
                               float* __restrict__ dinv, int N, int E) {
    __shared__ int red[256];
    int b = blockIdx.x, t = threadIdx.x;
    int chunk = (N + SCAN_BLOCKS - 1) / SCAN_BLOCKS;
    int start = b * chunk;
    int end = start + chunk; if (end > N) end = N;
    int sub = (chunk + 255) / 256;          // elements per thread (1 for N=50000)
    int ts = start + t * sub;
    int te = ts + sub; if (te > end) te = end; if (ts > end) ts = end;
    int s = 0;
    for (int i = ts; i < te; i++) s += deg[i];
    red[t] = s;
    __syncthreads();
    for (int off = 1; off < 256; off <<= 1) {
        int v = (t >= off) ? red[t - off] : 0;
        __syncthreads();
        red[t] += v;
        __syncthreads();
    }
    int run = partials[b] + ((t == 0) ? 0 : red[t - 1]);
    for (int i = ts; i < te; i++) {
        int dg = deg[i];
        row_ptr[i] = run;
        cursor[i] = run;
        dinv[i] = rsqrtf((float)dg + 1.0f);
        run += dg;
    }
    if (b == 0 && t == 0) row_ptr[N] = E;
}

// fill col[] (src per CSR slot)
__global__ void fill_csr_kernel(const int* __restrict__ ei, int* __restrict__ cursor,
                                int* __restrict__ col, int E) {
    int e = blockIdx.x * blockDim.x + threadIdx.x;
    if (e >= E) return;
    int s = ei[e], d = ei[E + e];
    int pos = atomicAdd(&cursor[d], 1);
    col[pos] = s;
}

// ---------------- dense layers ----------------

// h_lin = dinv[n] * (x @ W1)  -> fp16, row stride 160 (pad 156..159 = 0)
__global__ void lin1_kernel(const float* __restrict__ x, const float* __restrict__ W1,
                            const float* __restrict__ dinv, half_t* __restrict__ h_lin, int N) {
    __shared__ float2 xs[16][39];
    int tid = threadIdx.x;           // 192
    int n0 = blockIdx.x * 16;
    const float2* x2 = (const float2*)x;   // row stride 39 float2
    for (int i = tid; i < 16 * 39; i += 192) {
        int r = i / 39, c = i % 39;
        int n = n0 + r;
        float2 z; z.x = 0.f; z.y = 0.f;
        if (n < N) {
            float dn = dinv[n];
            float2 v = x2[(size_t)n * 39 + c];
            z.x = v.x * dn; z.y = v.y * dn;   // pre-scale by dinv[src]
        }
        xs[r][c] = z;
    }
    __syncthreads();
    if (tid >= 160) return;
    if (tid >= F_MID) {   // zero the pad columns
        for (int r = 0; r < 16; r++) {
            int n = n0 + r;
            if (n < N) h_lin[(size_t)n * 160 + tid] = (half_t)0.f;
        }
        return;
    }
    float acc[16] = {};
    for (int k2 = 0; k2 < 39; k2++) {
        float w0 = W1[(2 * k2) * F_MID + tid];
        float w1 = W1[(2 * k2 + 1) * F_MID + tid];
        #pragma unroll
        for (int r = 0; r < 16; r++) {
            float2 xv = xs[r][k2];
            acc[r] += xv.x * w0 + xv.y * w1;
        }
    }
    #pragma unroll
    for (int r = 0; r < 16; r++) {
        int n = n0 + r;
        if (n < N) h_lin[(size_t)n * 160 + tid] = (half_t)acc[r];
    }
}

// W2 [156][312] fp32 -> w2t [320][160] fp16 transposed, zero-padded
__global__ void w2t_kernel(const float* __restrict__ W2, half_t* __restrict__ w2t) {
    int idx = blockIdx.x * blockDim.x + threadIdx.x;
    if (idx >= 320 * 160) return;
    int coln = idx / 160, k = idx % 160;
    float v = (coln < C2 && k < F_MID) ? W2[k * C2 + coln] : 0.f;
    w2t[idx] = (half_t)v;
}

// transpose MLP weights (one launch): wgT[128][312], wf1T[1024][128], wf2T[512][1024]
__global__ void wT_kernel(const float* __restrict__ Wg, const float* __restrict__ Wf1,
                          const float* __restrict__ Wf2, float* __restrict__ wgT,
                          float* __restrict__ wf1T, float* __restrict__ wf2T) {
    int idx = blockIdx.x * blockDim.x + threadIdx.x;
    if (idx < GDIM * C2) {           // 128 x 312
        int c = idx / C2, k = idx % C2;
        wgT[idx] = Wg[k * GDIM + c];
        return;
    }
    idx -= GDIM * C2;
    if (idx < F1D * GDIM) {          // 1024 x 128
        int c = idx / GDIM, k = idx % GDIM;
        wf1T[idx] = Wf1[k * F1D + c];
        return;
    }
    idx -= F1D * GDIM;
    if (idx < F2D * F1D) {           // 512 x 1024
        int c = idx / F1D, k = idx % F1D;
        wf2T[idx] = Wf2[k * F2D + c];
    }
}

// g = h16 @ W2 via MFMA f16: [N x 160(pad)] @ [160 x 320(pad)] -> fp16 g stride 312
__global__ void lin2_mfma_kernel(const half_t* __restrict__ h16, const half_t* __restrict__ w2t,
                                 half_t* __restrict__ g, int N) {
    int wid  = (blockIdx.x * blockDim.x + threadIdx.x) >> 6;
    int lane = threadIdx.x & 63;
    int m0 = wid * 32;
    if (m0 >= N) return;
    int rl = lane & 15;          // A row within tile / B col within tile
    int kg = lane >> 4;          // k-group (8 elements each)
    bool has2 = (m0 + 16) < N;

    const half8* hv = (const half8*)h16;   // row stride 20 half8
    const half8* wv = (const half8*)w2t;   // row stride 20 half8 (N-major)
    half8 zz = {(half_t)0.f,(half_t)0.f,(half_t)0.f,(half_t)0.f,
                (half_t)0.f,(half_t)0.f,(half_t)0.f,(half_t)0.f};

    half8 a0[5], a1[5];
    size_t rA = (size_t)(m0 + rl) * 20;
    size_t rB = (size_t)(m0 + 16 + rl) * 20;
    #pragma unroll
    for (int ks = 0; ks < 5; ks++) {
        a0[ks] = hv[rA + ks * 4 + kg];
        a1[ks] = has2 ? hv[rB + ks * 4 + kg] : zz;
    }

    for (int n0 = 0; n0 < 20; n0++) {
        f32x4 c0 = {0.f, 0.f, 0.f, 0.f};
        f32x4 c1 = {0.f, 0.f, 0.f, 0.f};
        size_t wb = (size_t)(n0 * 16 + rl) * 20 + kg;
        #pragma unroll
        for (int ks = 0; ks < 5; ks++) {
            half8 b = wv[wb + ks * 4];
            c0 = __builtin_amdgcn_mfma_f32_16x16x32_f16(a0[ks], b, c0, 0, 0, 0);
            c1 = __builtin_amdgcn_mfma_f32_16x16x32_f16(a1[ks], b, c1, 0, 0, 0);
        }
        int col = n0 * 16 + rl;
        if (col < C2) {
            int r0 = kg * 4;
            #pragma unroll
            for (int j = 0; j < 4; j++) {
                g[(size_t)(m0 + r0 + j) * C2 + col] = (half_t)c0[j];
            }
            if (has2) {
                #pragma unroll
                for (int j = 0; j < 4; j++) {
                    g[(size_t)(m0 + 16 + r0 + j) * C2 + col] = (half_t)c1[j];
                }
            }
        }
    }
}

// ---------------- GCN gather (fp16 rows, pure sum; dinv pre-applied) ----------------
__global__ void gcn_gather_kernel(const half_t* __restrict__ h_lin, const int* __restrict__ row_ptr,
                                  const int* __restrict__ col, const float* __restrict__ dinv,
                                  const float* __restrict__ b1, half_t* __restrict__ h16, int N) {
    int wid  = (blockIdx.x * blockDim.x + threadIdx.x) >> 6;
    int lane = threadIdx.x & 63;
    if (wid >= N) return;
    int d  = wid;
    int jb = row_ptr[d], je = row_ptr[d + 1];
    float dd = dinv[d];
    const half8* h8v = (const half8*)h_lin;  // row stride 20 half8
    bool actv = lane < 20;
    int f0 = lane * 8;
    float acc[8] = {};
    if (actv) {   // self contribution
        half8 v = h8v[(size_t)d * 20 + lane];
        #pragma unroll
        for (int e = 0; e < 8; e++) acc[e] = (float)v[e];
    }
    int j = jb;
    for (; j + 3 < je; j += 4) {
        int s0 = rfl(col[j]);
        int s1 = rfl(col[j + 1]);
        int s2 = rfl(col[j + 2]);
        int s3 = rfl(col[j + 3]);
        if (actv) {
            half8 v0 = h8v[(size_t)s0 * 20 + lane];
            half8 v1 = h8v[(size_t)s1 * 20 + lane];
            half8 v2 = h8v[(size_t)s2 * 20 + lane];
            half8 v3 = h8v[(size_t)s3 * 20 + lane];
            #pragma unroll
            for (int e = 0; e < 8; e++)
                acc[e] += (float)v0[e] + (float)v1[e] + (float)v2[e] + (float)v3[e];
        }
    }
    for (; j < je; j++) {
        int s = rfl(col[j]);
        if (actv) {
            half8 v = h8v[(size_t)s * 20 + lane];
            #pragma unroll
            for (int e = 0; e < 8; e++) acc[e] += (float)v[e];
        }
    }
    if (actv) {
        half8 o;
        #pragma unroll
        for (int e = 0; e < 8; e++) {
            int f = f0 + e;
            float val = 0.f;
            if (f < F_MID) val = leaky(dd * acc[e] + b1[f], 0.01f);
            o[e] = (half_t)val;
        }
        ((half8*)h16)[(size_t)d * 20 + lane] = o;
    }
}

// ---------------- GAT attention coefficients (fp16 g) ----------------
__global__ void att_kernel(const half_t* __restrict__ g, const float* __restrict__ att_src,
                           const float* __restrict__ att_dst, float2* __restrict__ a_src,
                           float2* __restrict__ a_dst, int N) {
    int wid  = (blockIdx.x * blockDim.x + threadIdx.x) >> 6;
    int lane = threadIdx.x & 63;
    if (wid >= N) return;
    const half8* g8 = (const half8*)g;   // row stride 39
    float vs0 = 0.f, vs1 = 0.f, vd0 = 0.f, vd1 = 0.f;
    if (lane < 39) {
        half8 v = g8[(size_t)wid * 39 + lane];
        int f0 = lane * 8;
        #pragma unroll
        for (int e = 0; e < 8; e++) {
            int f = f0 + e;
            float gv = (float)v[e];
            float sw = att_src[f];
            float dw = att_dst[f];
            if (f < F_MID) { vs0 += gv * sw; vd0 += gv * dw; }
            else           { vs1 += gv * sw; vd1 += gv * dw; }
        }
    }
    #pragma unroll
    for (int off = 32; off; off >>= 1) {
        vs0 += __shfl_xor(vs0, off);
        vs1 += __shfl_xor(vs1, off);
        vd0 += __shfl_xor(vd0, off);
        vd1 += __shfl_xor(vd1, off);
    }
    if (lane == 0) {
        float2 s; s.x = vs0; s.y = vs1;
        float2 t; t.x = vd0; t.y = vd1;
        a_src[wid] = s;
        a_dst[wid] = t;
    }
}

// ---------------- GAT: per-dst online max+sum, then per-slot weights ----------------
__global__ void gat_msw_kernel(const float2* __restrict__ a_src, const float2* __restrict__ a_dst,
                               const int* __restrict__ row_ptr, const int* __restrict__ col,
                               float4* __restrict__ minv, float2* __restrict__ wbuf, int N) {
    int wid  = (blockIdx.x * blockDim.x + threadIdx.x) >> 6;
    int lane = threadIdx.x & 63;
    if (wid >= N) return;
    int d  = wid;
    int jb = row_ptr[d], je = row_ptr[d + 1];
    float2 ad = a_dst[d];
    float2 asd = a_src[d];
    float es0 = leaky(asd.x + ad.x, 0.2f);   // self-loop logits
    float es1 = leaky(asd.y + ad.y, 0.2f);

    float m0 = NEG_SENTINEL, s0 = 0.f, m1 = NEG_SENTINEL, s1 = 0.f;
    for (int j = jb + lane; j < je; j += 64) {
        float2 as = a_src[col[j]];
        float e0 = leaky(as.x + ad.x, 0.2f);
        float e1 = leaky(as.y + ad.y, 0.2f);
        float nm0 = fmaxf(m0, e0); s0 = s0 * __expf(m0 - nm0) + __expf(e0 - nm0); m0 = nm0;
        float nm1 = fmaxf(m1, e1); s1 = s1 * __expf(m1 - nm1) + __expf(e1 - nm1); m1 = nm1;
    }
    #pragma unroll
    for (int off = 32; off; off >>= 1) {
        float om0 = __shfl_xor(m0, off), os0 = __shfl_xor(s0, off);
        float om1 = __shfl_xor(m1, off), os1 = __shfl_xor(s1, off);
        float nm0 = fmaxf(m0, om0);
        s0 = s0 * __expf(m0 - nm0) + os0 * __expf(om0 - nm0); m0 = nm0;
        float nm1 = fmaxf(m1, om1);
        s1 = s1 * __expf(m1 - nm1) + os1 * __expf(om1 - nm1); m1 = nm1;
    }
    { // fold self-loop
        float nm0 = fmaxf(m0, es0);
        s0 = s0 * __expf(m0 - nm0) + __expf(es0 - nm0); m0 = nm0;
        float nm1 = fmaxf(m1, es1);
        s1 = s1 * __expf(m1 - nm1) + __expf(es1 - nm1); m1 = nm1;
    }
    float i0 = 1.0f / s0, i1 = 1.0f / s1;
    if (lane == 0) {
        float4 r; r.x = m0; r.y = i0; r.z = m1; r.w = i1;
        minv[d] = r;
    }
    for (int j = jb + lane; j < je; j += 64) {
        float2 as = a_src[col[j]];      // L1-hot from first pass
        float2 w;
        w.x = __expf(leaky(as.x + ad.x, 0.2f) - m0) * i0;
        w.y = __expf(leaky(as.y + ad.y, 0.2f) - m1) * i1;
        wbuf[j] = w;
    }
}

// ---------------- GAT gather (fp16 rows, one load/edge, x4 unroll) ----------------
__global__ void gat_gather_kernel(const half_t* __restrict__ g, const float2* __restrict__ a_src,
                                  const float2* __restrict__ a_dst, const int* __restrict__ row_ptr,
                                  const int* __restrict__ col, const float2* __restrict__ wbuf,
                                  const float4* __restrict__ minv, float* __restrict__ gout, int N) {
    int wid  = (blockIdx.x * blockDim.x + threadIdx.x) >> 6;
    int lane = threadIdx.x & 63;
    if (wid >= N) return;
    int d  = wid;
    int jb = row_ptr[d], je = row_ptr[d + 1];
    const half8* g8 = (const half8*)g;   // row stride 39
    bool actv = lane < 39;
    int f0 = lane * 8;
    bool lo0 = f0 < F_MID;        // head of first 4 feats
    bool hi0 = (f0 + 4) < F_MID;  // head of last 4 feats
    float acc[8] = {};
    { // self contribution
        float2 ad = a_dst[d];
        float2 asd = a_src[d];
        float4 mv = minv[d];
        float w0 = __expf(leaky(asd.x + ad.x, 0.2f) - mv.x) * mv.y;
        float w1 = __expf(leaky(asd.y + ad.y, 0.2f) - mv.z) * mv.w;
        if (actv) {
            half8 v = g8[(size_t)d * 39 + lane];
            float wlo = lo0 ? w0 : w1;
            float whi = hi0 ? w0 : w1;
            #pragma unroll
            for (int e = 0; e < 4; e++) acc[e] = (float)v[e] * wlo;
            #pragma unroll
            for (int e = 4; e < 8; e++) acc[e] = (float)v[e] * whi;
        }
    }
    int j = jb;
    for (; j + 3 < je; j += 4) {
        int s0 = rfl(col[j]);
        int s1 = rfl(col[j + 1]);
        int s2 = rfl(col[j + 2]);
        int s3 = rfl(col[j + 3]);
        float2 W0 = wbuf[j], W1v = wbuf[j + 1], W2v = wbuf[j + 2], W3v = wbuf[j + 3];
        if (actv) {
            half8 v0 = g8[(size_t)s0 * 39 + lane];
            half8 v1 = g8[(size_t)s1 * 39 + lane];
            half8 v2 = g8[(size_t)s2 * 39 + lane];
            half8 v3 = g8[(size_t)s3 * 39 + lane];
            float a0 = lo0 ? W0.x : W0.y,  b0 = hi0 ? W0.x : W0.y;
            float a1 = lo0 ? W1v.x : W1v.y, b1 = hi0 ? W1v.x : W1v.y;
            float a2 = lo0 ? W2v.x : W2v.y, b2 = hi0 ? W2v.x : W2v.y;
            float a3 = lo0 ? W3v.x : W3v.y, b3 = hi0 ? W3v.x : W3v.y;
            #pragma unroll
            for (int e = 0; e < 4; e++)
                acc[e] += (float)v0[e] * a0 + (float)v1[e] * a1 + (float)v2[e] * a2 + (float)v3[e] * a3;
            #pragma unroll
            for (int e = 4; e < 8; e++)
                acc[e] += (float)v0[e] * b0 + (float)v1[e] * b1 + (float)v2[e] * b2 + (float)v3[e] * b3;
        }
    }
    for (; j < je; j++) {
        int s = rfl(col[j]);
        float2 w2 = wbuf[j];
        if (actv) {
            half8 v = g8[(size_t)s * 39 + lane];
            float wlo = lo0 ? w2.x : w2.y;
            float whi = hi0 ? w2.x : w2.y;
            #pragma unroll
            for (int e = 0; e < 4; e++) acc[e] += (float)v[e] * wlo;
            #pragma unroll
            for (int e = 4; e < 8; e++) acc[e] += (float)v[e] * whi;
        }
    }
    if (actv) {
        float* orow = gout + (size_t)d * C2 + f0;
        float4 o0; o0.x = acc[0]; o0.y = acc[1]; o0.z = acc[2]; o0.w = acc[3];
        float4 o1; o1.x = acc[4]; o1.y = acc[5]; o1.z = acc[6]; o1.w = acc[7];
        *(float4*)orow = o0;
        *(float4*)(orow + 4) = o1;
    }
}

// ---------------- pooling + MLP ----------------

__global__ void starts_kernel(const int* __restrict__ batch, int* __restrict__ starts, int N, int B) {
    int b = blockIdx.x * blockDim.x + threadIdx.x;
    if (b > B) return;
    if (b == B) { starts[B] = N; return; }
    int lo = 0, hi = N;
    while (lo < hi) {
        int mid = (lo + hi) >> 1;
        if (batch[mid] < b) lo = mid + 1; else hi = mid;
    }
    starts[b] = lo;
}

// p0[b,:] = leaky(max_n gout[n,:] + b2, 0.01); float4 columns, 4-deep unroll
__global__ void pool_kernel(const float* __restrict__ gout, const float* __restrict__ b2,
                            const int* __restrict__ starts, float* __restrict__ p0) {
    int b = blockIdx.x;
    int t = threadIdx.x;   // block 128; t<78 active
    if (t >= 78) return;
    int s = starts[b], e = starts[b + 1];
    const float4* g4 = (const float4*)gout;
    float4 m0, m1, m2, m3;
    m0.x = m0.y = m0.z = m0.w = -INFINITY;
    m1 = m0; m2 = m0; m3 = m0;
    int n = s;
    for (; n + 3 < e; n += 4) {
        float4 v0 = g4[(size_t)(n + 0) * 78 + t];
        float4 v1 = g4[(size_t)(n + 1) * 78 + t];
        float4 v2 = g4[(size_t)(n + 2) * 78 + t];
        float4 v3 = g4[(size_t)(n + 3) * 78 + t];
        m0.x = fmaxf(m0.x, v0.x); m0.y = fmaxf(m0.y, v0.y); m0.z = fmaxf(m0.z, v0.z); m0.w = fmaxf(m0.w, v0.w);
        m1.x = fmaxf(m1.x, v1.x); m1.y = fmaxf(m1.y, v1.y); m1.z = fmaxf(m1.z, v1.z); m1.w = fmaxf(m1.w, v1.w);
        m2.x = fmaxf(m2.x, v2.x); m2.y = fmaxf(m2.y, v2.y); m2.z = fmaxf(m2.z, v2.z); m2.w = fmaxf(m2.w, v2.w);
        m3.x = fmaxf(m3.x, v3.x); m3.y = fmaxf(m3.y, v3.y); m3.z = fmaxf(m3.z, v3.z); m3.w = fmaxf(m3.w, v3.w);
    }
    for (; n < e; n++) {
        float4 v = g4[(size_t)n * 78 + t];
        m0.x = fmaxf(m0.x, v.x); m0.y = fmaxf(m0.y, v.y); m0.z = fmaxf(m0.z, v.z); m0.w = fmaxf(m0.w, v.w);
    }
    m0.x = fmaxf(fmaxf(m0.x, m1.x), fmaxf(m2.x, m3.x));
    m0.y = fmaxf(fmaxf(m0.y, m1.y), fmaxf(m2.y, m3.y));
    m0.z = fmaxf(fmaxf(m0.z, m1.z), fmaxf(m2.z, m3.z));
    m0.w = fmaxf(fmaxf(m0.w, m1.w), fmaxf(m2.w, m3.w));
    float4 bb = ((const float4*)b2)[t];
    float4 o;
    o.x = leaky(m0.x + bb.x, 0.01f);
    o.y = leaky(m0.y + bb.y, 0.01f);
    o.z = leaky(m0.z + bb.z, 0.01f);
    o.w = leaky(m0.w + bb.w, 0.01f);
    ((float4*)p0)[(size_t)b * 78 + t] = o;
}

// dense layer, wave per output scalar: out[b,c] = act(dot(in[b,:], Wt[c,:]) + bias[c])
// Wt is [OUT][KDIM] (transposed weights) -> lanes read contiguous K.
// ACT: 0 none, 1 leaky 0.01, 2 relu
template <int KDIM, int ACT>
__global__ void fcT_kernel(const float* __restrict__ in, const float* __restrict__ Wt,
                           const float* __restrict__ bias, float* __restrict__ out,
                           int Bn, int OUT) {
    int wid  = (blockIdx.x * blockDim.x + threadIdx.x) >> 6;
    int lane = threadIdx.x & 63;
    if (wid >= Bn * OUT) return;
    int b = wid / OUT, c = wid % OUT;
    const float* irow = in + (size_t)b * KDIM;
    const float* wrow = Wt + (size_t)c * KDIM;
    float acc = 0.f;
    #pragma unroll 4
    for (int k = lane; k < KDIM; k += 64)
        acc += irow[k] * wrow[k];
    #pragma unroll
    for (int off = 32; off; off >>= 1) acc += __shfl_xor(acc, off);
    if (lane == 0) {
        acc += bias[c];
        if (ACT == 1) acc = leaky(acc, 0.01f);
        if (ACT == 2) acc = fmaxf(acc, 0.f);
        out[wid] = acc;
    }
}

extern "C" void kernel_launch(void* const* d_in, const int* in_sizes, int n_in,
                              void* d_out, int out_size, void* d_ws, size_t ws_size,
                              hipStream_t stream) {
    const float* x       = (const float*)d_in[0];
    const int*   ei      = (const int*)d_in[1];
    const int*   batch   = (const int*)d_in[2];
    const float* W1      = (const float*)d_in[3];
    const float* b1      = (const float*)d_in[4];
    const float* W2      = (const float*)d_in[5];
    const float* att_src = (const float*)d_in[6];
    const float* att_dst = (const float*)d_in[7];
    const float* b2      = (const float*)d_in[8];
    const float* Wg      = (const float*)d_in[9];
    const float* bg      = (const float*)d_in[10];
    const float* Wf1     = (const float*)d_in[11];
    const float* bf1     = (const float*)d_in[12];
    const float* Wf2     = (const float*)d_in[13];
    const float* bf2     = (const float*)d_in[14];
    const float* Wo      = (const float*)d_in[15];
    const float* bo      = (const float*)d_in[16];
    float* out = (float*)d_out;

    const int N  = in_sizes[0] / F_INP;
    const int E  = in_sizes[1] / 2;
    const int Bn = out_size;          // 128 graphs

    // ---- workspace carving (16B-aligned slices) ----
    char* base = (char*)d_ws;
    size_t off = 0;
    auto take = [&](size_t bytes) -> void* {
        off = (off + 15) & ~(size_t)15;
        void* p = base + off;
        off += bytes;
        return p;
    };
    half_t* g      = (half_t*)take((size_t)C2 * N * 2);      // fp16, stride 312
    char*   AA     = (char*)take((size_t)C2 * N * 4);        // h_lin|h16 early, gout late
    half_t* h_lin  = (half_t*)AA;                            //   N*160 fp16 (16 MB)
    half_t* h16    = (half_t*)(AA + (size_t)160 * N * 2);    //   N*160 fp16 (16 MB)
    float*  gout   = (float*)AA;                             //   N*312 fp32 (62 MB, alias)
    half_t* w2t    = (half_t*)take((size_t)320 * 160 * 2);   // W2^T fp16 padded
    float*  wgT    = (float*)take((size_t)GDIM * C2 * 4);    // 128x312
    float*  wf1T   = (float*)take((size_t)F1D * GDIM * 4);   // 1024x128
    float*  wf2T   = (float*)take((size_t)F2D * F1D * 4);    // 512x1024
    float4* minv   = (float4*)take((size_t)N * 16);
    float2* a_src  = (float2*)take((size_t)N * 8);
    float2* a_dst  = (float2*)take((size_t)N * 8);
    float2* wbuf   = (float2*)take((size_t)E * 8);
    float*  dinv   = (float*)take((size_t)N * 4);
    int*    deg_i  = (int*)take((size_t)N * 4);
    int*    partials = (int*)take((size_t)SCAN_BLOCKS * 4);
    int*    row_ptr= (int*)take((size_t)(N + 1) * 4);
    int*    cursor = (int*)take((size_t)N * 4);
    int*    col    = (int*)take((size_t)E * 4);
    int*    starts = (int*)take((size_t)(Bn + 1) * 4);
    float*  p0     = (float*)take((size_t)Bn * C2 * 4);
    float*  p1     = (float*)take((size_t)Bn * GDIM * 4);
    float*  p2     = (float*)take((size_t)Bn * F1D * 4);
    float*  p3     = (float*)take((size_t)Bn * F2D * 4);

    hipMemsetAsync(deg_i, 0, (size_t)N * sizeof(int), stream);

    // independent prep
    starts_kernel<<<1, 256, 0, stream>>>(batch, starts, N, Bn);
    w2t_kernel<<<(320 * 160 + 255) / 256, 256, 0, stream>>>(W2, w2t);
    {
        int tot = GDIM * C2 + F1D * GDIM + F2D * F1D;
        wT_kernel<<<(tot + 255) / 256, 256, 0, stream>>>(Wg, Wf1, Wf2, wgT, wf1T, wf2T);
    }

    // CSR build (parallel 3-phase scan; produces dinv needed by lin1)
    deg_count_kernel<<<(E + 255) / 256, 256, 0, stream>>>(ei, deg_i, E);
    scan_p1_kernel<<<SCAN_BLOCKS, 256, 0, stream>>>(deg_i, partials, N);
    scan_p2_kernel<<<1, SCAN_BLOCKS, 0, stream>>>(partials);
    scan_p3_kernel<<<SCAN_BLOCKS, 256, 0, stream>>>(deg_i, partials, row_ptr, cursor, dinv, N, E);
    fill_csr_kernel<<<(E + 255) / 256, 256, 0, stream>>>(ei, cursor, col, E);

    // GCN
    lin1_kernel<<<(N + 15) / 16, 192, 0, stream>>>(x, W1, dinv, h_lin, N);
    gcn_gather_kernel<<<(N + 3) / 4, 256, 0, stream>>>(h_lin, row_ptr, col, dinv, b1, h16, N);

    // GAT
    {
        int mwaves = (N + 31) / 32;            // one wave per 32 rows
        int blocks = (mwaves + 3) / 4;         // 4 waves per block
        lin2_mfma_kernel<<<blocks, 256, 0, stream>>>(h16, w2t, g, N);
    }
    att_kernel<<<(N + 3) / 4, 256, 0, stream>>>(g, att_src, att_dst, a_src, a_dst, N);
    gat_msw_kernel<<<(N + 3) / 4, 256, 0, stream>>>(a_src, a_dst, row_ptr, col, minv, wbuf, N);
    gat_gather_kernel<<<(N + 3) / 4, 256, 0, stream>>>(g, a_src, a_dst, row_ptr, col, wbuf, minv, gout, N);

    // pool + MLP (wave-per-output, transposed weights)
    pool_kernel<<<Bn, 128, 0, stream>>>(gout, b2, starts, p0);
    {
        auto blocks_for = [](int waves) { return (waves + 3) / 4; };   // 4 waves / 256-thr block
        fcT_kernel<C2, 1><<<blocks_for(Bn * GDIM), 256, 0, stream>>>(p0, wgT, bg, p1, Bn, GDIM);
        fcT_kernel<GDIM, 2><<<blocks_for(Bn * F1D), 256, 0, stream>>>(p1, wf1T, bf1, p2, Bn, F1D);
        fcT_kernel<F1D, 2><<<blocks_for(Bn * F2D), 256, 0, stream>>>(p2, wf2T, bf2, p3, Bn, F2D);
        fcT_kernel<F2D, 0><<<blocks_for(Bn), 256, 0, stream>>>(p3, Wo, bo, out, Bn, 1);
    }
}

// Round 14
// 508.233 us; speedup vs baseline: 1.9581x; 1.0581x over previous
//
#include <hip/hip_runtime.h>
#include <cstdint>
#include <cstddef>

// ---- problem constants (from reference) ----
#define F_INP 78
#define F_MID 156
#define C2    312   // HEADS*F_MID
#define GDIM  128
#define F1D   1024
#define F2D   512

#define NEG_SENTINEL -1e30f
#define SCAN_BLOCKS 256

typedef _Float16 half_t;
typedef _Float16 half8 __attribute__((ext_vector_type(8)));
typedef float f32x4 __attribute__((ext_vector_type(4)));

__device__ __forceinline__ float leaky(float v, float s) { return v > 0.f ? v : s * v; }
__device__ __forceinline__ int rfl(int v) { return __builtin_amdgcn_readfirstlane(v); }

// ---------------- CSR construction ----------------

__global__ void deg_count_kernel(const int* __restrict__ ei, int* __restrict__ deg, int E) {
    int e = blockIdx.x * blockDim.x + threadIdx.x;
    if (e >= E) return;
    atomicAdd(&deg[ei[E + e]], 1);
}

// phase 1: per-block partial sums of deg
__global__ void scan_p1_kernel(const int* __restrict__ deg, int* __restrict__ partials, int N) {
    __shared__ int red[256];
    int b = blockIdx.x, t = threadIdx.x;
    int chunk = (N + SCAN_BLOCKS - 1) / SCAN_BLOCKS;
    int start = b * chunk;
    int end = start + chunk; if (end > N) end = N;
    int s = 0;
    for (int i = start + t; i < end; i += 256) s += deg[i];
    red[t] = s;
    __syncthreads();
    for (int off = 128; off; off >>= 1) {
        if (t < off) red[t] += red[t + off];
        __syncthreads();
    }
    if (t == 0) partials[b] = red[0];
}

// phase 2: exclusive scan of the 256 partials (one block)
__global__ void scan_p2_kernel(int* __restrict__ partials) {
    __shared__ int s[SCAN_BLOCKS];
    int t = threadIdx.x;
    s[t] = partials[t];
    __syncthreads();
    for (int off = 1; off < SCAN_BLOCKS; off <<= 1) {
        int v = (t >= off) ? s[t - off] : 0;
        __syncthreads();
        s[t] += v;
        __syncthreads();
    }
    partials[t] = (t == 0) ? 0 : s[t - 1];
}

// phase 3: emit row_ptr / cursor / dinv with block offsets
__global__ void scan_p3_kernel(const int* __restrict__ deg, const int* __restrict__ partials,
                               int* __restrict__ row_ptr, int* __restrict__ cursor,
                               float* __restrict__ dinv, int N, int E) {
    __shared__ int red[256];
    int b = blockIdx.x, t = threadIdx.x;
    int chunk = (N + SCAN_BLOCKS - 1) / SCAN_BLOCKS;
    int start = b * chunk;
    int end = start + chunk; if (end > N) end = N;
    int sub = (chunk + 255) / 256;          // elements per thread (1 for N=50000)
    int ts = start + t * sub;
    int te = ts + sub; if (te > end) te = end; if (ts > end) ts = end;
    int s = 0;
    for (int i = ts; i < te; i++) s += deg[i];
    red[t] = s;
    __syncthreads();
    for (int off = 1; off < 256; off <<= 1) {
        int v = (t >= off) ? red[t - off] : 0;
        __syncthreads();
        red[t] += v;
        __syncthreads();
    }
    int run = partials[b] + ((t == 0) ? 0 : red[t - 1]);
    for (int i = ts; i < te; i++) {
        int dg = deg[i];
        row_ptr[i] = run;
        cursor[i] = run;
        dinv[i] = rsqrtf((float)dg + 1.0f);
        run += dg;
    }
    if (b == 0 && t == 0) row_ptr[N] = E;
}

// fill col[] (src per CSR slot)
__global__ void fill_csr_kernel(const int* __restrict__ ei, int* __restrict__ cursor,
                                int* __restrict__ col, int E) {
    int e = blockIdx.x * blockDim.x + threadIdx.x;
    if (e >= E) return;
    int s = ei[e], d = ei[E + e];
    int pos = atomicAdd(&cursor[d], 1);
    col[pos] = s;
}

// ---------------- dense layers ----------------

// hx[n][96] fp16 = x[n][k]*dinv[n] (k<78, pad 0); one half8 chunk per thread
__global__ void x16_kernel(const float* __restrict__ x, const float* __restrict__ dinv,
                           half_t* __restrict__ hx, int N) {
    int idx = blockIdx.x * blockDim.x + threadIdx.x;
    if (idx >= N * 12) return;
    int n = idx / 12, c = idx % 12;
    float dn = dinv[n];
    half8 o;
    int k0 = c * 8;
    #pragma unroll
    for (int e = 0; e < 8; e++) {
        int k = k0 + e;
        float v = (k < F_INP) ? x[(size_t)n * F_INP + k] * dn : 0.f;
        o[e] = (half_t)v;
    }
    ((half8*)hx)[idx] = o;
}

// W1 [78][156] fp32 -> w1t [160][96] fp16 transposed, zero-padded
__global__ void w1t_kernel(const float* __restrict__ W1, half_t* __restrict__ w1t) {
    int idx = blockIdx.x * blockDim.x + threadIdx.x;
    if (idx >= 160 * 96) return;
    int c = idx / 96, k = idx % 96;
    float v = (c < F_MID && k < F_INP) ? W1[k * F_MID + c] : 0.f;
    w1t[idx] = (half_t)v;
}

// h_lin = hx @ W1 via MFMA f16: [N x 96] @ [96 x 160] -> fp16, stride 160
// (pad cols 156..159 are zero columns of w1t -> output pad = 0 automatically)
__global__ void lin1_mfma_kernel(const half_t* __restrict__ hx, const half_t* __restrict__ w1t,
                                 half_t* __restrict__ h_lin, int N) {
    int wid  = (blockIdx.x * blockDim.x + threadIdx.x) >> 6;
    int lane = threadIdx.x & 63;
    int m0 = wid * 32;
    if (m0 >= N) return;
    int rl = lane & 15;
    int kg = lane >> 4;
    bool has2 = (m0 + 16) < N;

    const half8* hv = (const half8*)hx;    // row stride 12 half8
    const half8* wv = (const half8*)w1t;   // row stride 12 half8
    half8 zz = {(half_t)0.f,(half_t)0.f,(half_t)0.f,(half_t)0.f,
                (half_t)0.f,(half_t)0.f,(half_t)0.f,(half_t)0.f};

    half8 a0[3], a1[3];
    size_t rA = (size_t)(m0 + rl) * 12;
    size_t rB = (size_t)(m0 + 16 + rl) * 12;
    #pragma unroll
    for (int ks = 0; ks < 3; ks++) {
        a0[ks] = hv[rA + ks * 4 + kg];
        a1[ks] = has2 ? hv[rB + ks * 4 + kg] : zz;
    }

    for (int n0 = 0; n0 < 10; n0++) {
        f32x4 c0 = {0.f, 0.f, 0.f, 0.f};
        f32x4 c1 = {0.f, 0.f, 0.f, 0.f};
        size_t wb = (size_t)(n0 * 16 + rl) * 12 + kg;
        #pragma unroll
        for (int ks = 0; ks < 3; ks++) {
            half8 b = wv[wb + ks * 4];
            c0 = __builtin_amdgcn_mfma_f32_16x16x32_f16(a0[ks], b, c0, 0, 0, 0);
            c1 = __builtin_amdgcn_mfma_f32_16x16x32_f16(a1[ks], b, c1, 0, 0, 0);
        }
        int col = n0 * 16 + rl;
        int r0 = kg * 4;
        #pragma unroll
        for (int j = 0; j < 4; j++)
            h_lin[(size_t)(m0 + r0 + j) * 160 + col] = (half_t)c0[j];
        if (has2) {
            #pragma unroll
            for (int j = 0; j < 4; j++)
                h_lin[(size_t)(m0 + 16 + r0 + j) * 160 + col] = (half_t)c1[j];
        }
    }
}

// W2 [156][312] fp32 -> w2t [320][160] fp16 transposed, zero-padded
__global__ void w2t_kernel(const float* __restrict__ W2, half_t* __restrict__ w2t) {
    int idx = blockIdx.x * blockDim.x + threadIdx.x;
    if (idx >= 320 * 160) return;
    int coln = idx / 160, k = idx % 160;
    float v = (coln < C2 && k < F_MID) ? W2[k * C2 + coln] : 0.f;
    w2t[idx] = (half_t)v;
}

// transpose MLP weights (one launch): wgT[128][312], wf1T[1024][128], wf2T[512][1024]
__global__ void wT_kernel(const float* __restrict__ Wg, const float* __restrict__ Wf1,
                          const float* __restrict__ Wf2, float* __restrict__ wgT,
                          float* __restrict__ wf1T, float* __restrict__ wf2T) {
    int idx = blockIdx.x * blockDim.x + threadIdx.x;
    if (idx < GDIM * C2) {           // 128 x 312
        int c = idx / C2, k = idx % C2;
        wgT[idx] = Wg[k * GDIM + c];
        return;
    }
    idx -= GDIM * C2;
    if (idx < F1D * GDIM) {          // 1024 x 128
        int c = idx / GDIM, k = idx % GDIM;
        wf1T[idx] = Wf1[k * F1D + c];
        return;
    }
    idx -= F1D * GDIM;
    if (idx < F2D * F1D) {           // 512 x 1024
        int c = idx / F1D, k = idx % F1D;
        wf2T[idx] = Wf2[k * F2D + c];
    }
}

// g = h16 @ W2 via MFMA f16: [N x 160(pad)] @ [160 x 320(pad)] -> fp16 g stride 312
__global__ void lin2_mfma_kernel(const half_t* __restrict__ h16, const half_t* __restrict__ w2t,
                                 half_t* __restrict__ g, int N) {
    int wid  = (blockIdx.x * blockDim.x + threadIdx.x) >> 6;
    int lane = threadIdx.x & 63;
    int m0 = wid * 32;
    if (m0 >= N) return;
    int rl = lane & 15;          // A row within tile / B col within tile
    int kg = lane >> 4;          // k-group (8 elements each)
    bool has2 = (m0 + 16) < N;

    const half8* hv = (const half8*)h16;   // row stride 20 half8
    const half8* wv = (const half8*)w2t;   // row stride 20 half8 (N-major)
    half8 zz = {(half_t)0.f,(half_t)0.f,(half_t)0.f,(half_t)0.f,
                (half_t)0.f,(half_t)0.f,(half_t)0.f,(half_t)0.f};

    half8 a0[5], a1[5];
    size_t rA = (size_t)(m0 + rl) * 20;
    size_t rB = (size_t)(m0 + 16 + rl) * 20;
    #pragma unroll
    for (int ks = 0; ks < 5; ks++) {
        a0[ks] = hv[rA + ks * 4 + kg];
        a1[ks] = has2 ? hv[rB + ks * 4 + kg] : zz;
    }

    for (int n0 = 0; n0 < 20; n0++) {
        f32x4 c0 = {0.f, 0.f, 0.f, 0.f};
        f32x4 c1 = {0.f, 0.f, 0.f, 0.f};
        size_t wb = (size_t)(n0 * 16 + rl) * 20 + kg;
        #pragma unroll
        for (int ks = 0; ks < 5; ks++) {
            half8 b = wv[wb + ks * 4];
            c0 = __builtin_amdgcn_mfma_f32_16x16x32_f16(a0[ks], b, c0, 0, 0, 0);
            c1 = __builtin_amdgcn_mfma_f32_16x16x32_f16(a1[ks], b, c1, 0, 0, 0);
        }
        int col = n0 * 16 + rl;
        if (col < C2) {
            int r0 = kg * 4;
            #pragma unroll
            for (int j = 0; j < 4; j++) {
                g[(size_t)(m0 + r0 + j) * C2 + col] = (half_t)c0[j];
            }
            if (has2) {
                #pragma unroll
                for (int j = 0; j < 4; j++) {
                    g[(size_t)(m0 + 16 + r0 + j) * C2 + col] = (half_t)c1[j];
                }
            }
        }
    }
}

// ---------------- GCN gather (fp16 rows, pure sum; dinv pre-applied) ----------------
__global__ void gcn_gather_kernel(const half_t* __restrict__ h_lin, const int* __restrict__ row_ptr,
                                  const int* __restrict__ col, const float* __restrict__ dinv,
                                  const float* __restrict__ b1, half_t* __restrict__ h16, int N) {
    int wid  = (blockIdx.x * blockDim.x + threadIdx.x) >> 6;
    int lane = threadIdx.x & 63;
    if (wid >= N) return;
    int d  = wid;
    int jb = row_ptr[d], je = row_ptr[d + 1];
    float dd = dinv[d];
    const half8* h8v = (const half8*)h_lin;  // row stride 20 half8
    bool actv = lane < 20;
    int f0 = lane * 8;
    float acc[8] = {};
    if (actv) {   // self contribution
        half8 v = h8v[(size_t)d * 20 + lane];
        #pragma unroll
        for (int e = 0; e < 8; e++) acc[e] = (float)v[e];
    }
    int j = jb;
    for (; j + 3 < je; j += 4) {
        int s0 = rfl(col[j]);
        int s1 = rfl(col[j + 1]);
        int s2 = rfl(col[j + 2]);
        int s3 = rfl(col[j + 3]);
        if (actv) {
            half8 v0 = h8v[(size_t)s0 * 20 + lane];
            half8 v1 = h8v[(size_t)s1 * 20 + lane];
            half8 v2 = h8v[(size_t)s2 * 20 + lane];
            half8 v3 = h8v[(size_t)s3 * 20 + lane];
            #pragma unroll
            for (int e = 0; e < 8; e++)
                acc[e] += (float)v0[e] + (float)v1[e] + (float)v2[e] + (float)v3[e];
        }
    }
    for (; j < je; j++) {
        int s = rfl(col[j]);
        if (actv) {
            half8 v = h8v[(size_t)s * 20 + lane];
            #pragma unroll
            for (int e = 0; e < 8; e++) acc[e] += (float)v[e];
        }
    }
    if (actv) {
        half8 o;
        #pragma unroll
        for (int e = 0; e < 8; e++) {
            int f = f0 + e;
            float val = 0.f;
            if (f < F_MID) val = leaky(dd * acc[e] + b1[f], 0.01f);
            o[e] = (half_t)val;
        }
        ((half8*)h16)[(size_t)d * 20 + lane] = o;
    }
}

// ---------------- GAT attention coefficients (fp16 g) ----------------
__global__ void att_kernel(const half_t* __restrict__ g, const float* __restrict__ att_src,
                           const float* __restrict__ att_dst, float2* __restrict__ a_src,
                           float2* __restrict__ a_dst, int N) {
    int wid  = (blockIdx.x * blockDim.x + threadIdx.x) >> 6;
    int lane = threadIdx.x & 63;
    if (wid >= N) return;
    const half8* g8 = (const half8*)g;   // row stride 39
    float vs0 = 0.f, vs1 = 0.f, vd0 = 0.f, vd1 = 0.f;
    if (lane < 39) {
        half8 v = g8[(size_t)wid * 39 + lane];
        int f0 = lane * 8;
        #pragma unroll
        for (int e = 0; e < 8; e++) {
            int f = f0 + e;
            float gv = (float)v[e];
            float sw = att_src[f];
            float dw = att_dst[f];
            if (f < F_MID) { vs0 += gv * sw; vd0 += gv * dw; }
            else           { vs1 += gv * sw; vd1 += gv * dw; }
        }
    }
    #pragma unroll
    for (int off = 32; off; off >>= 1) {
        vs0 += __shfl_xor(vs0, off);
        vs1 += __shfl_xor(vs1, off);
        vd0 += __shfl_xor(vd0, off);
        vd1 += __shfl_xor(vd1, off);
    }
    if (lane == 0) {
        float2 s; s.x = vs0; s.y = vs1;
        float2 t; t.x = vd0; t.y = vd1;
        a_src[wid] = s;
        a_dst[wid] = t;
    }
}

// ---------------- GAT: per-dst online max+sum, then per-slot weights ----------------
__global__ void gat_msw_kernel(const float2* __restrict__ a_src, const float2* __restrict__ a_dst,
                               const int* __restrict__ row_ptr, const int* __restrict__ col,
                               float4* __restrict__ minv, float2* __restrict__ wbuf, int N) {
    int wid  = (blockIdx.x * blockDim.x + threadIdx.x) >> 6;
    int lane = threadIdx.x & 63;
    if (wid >= N) return;
    int d  = wid;
    int jb = row_ptr[d], je = row_ptr[d + 1];
    float2 ad = a_dst[d];
    float2 asd = a_src[d];
    float es0 = leaky(asd.x + ad.x, 0.2f);   // self-loop logits
    float es1 = leaky(asd.y + ad.y, 0.2f);

    float m0 = NEG_SENTINEL, s0 = 0.f, m1 = NEG_SENTINEL, s1 = 0.f;
    for (int j = jb + lane; j < je; j += 64) {
        float2 as = a_src[col[j]];
        float e0 = leaky(as.x + ad.x, 0.2f);
        float e1 = leaky(as.y + ad.y, 0.2f);
        float nm0 = fmaxf(m0, e0); s0 = s0 * __expf(m0 - nm0) + __expf(e0 - nm0); m0 = nm0;
        float nm1 = fmaxf(m1, e1); s1 = s1 * __expf(m1 - nm1) + __expf(e1 - nm1); m1 = nm1;
    }
    #pragma unroll
    for (int off = 32; off; off >>= 1) {
        float om0 = __shfl_xor(m0, off), os0 = __shfl_xor(s0, off);
        float om1 = __shfl_xor(m1, off), os1 = __shfl_xor(s1, off);
        float nm0 = fmaxf(m0, om0);
        s0 = s0 * __expf(m0 - nm0) + os0 * __expf(om0 - nm0); m0 = nm0;
        float nm1 = fmaxf(m1, om1);
        s1 = s1 * __expf(m1 - nm1) + os1 * __expf(om1 - nm1); m1 = nm1;
    }
    { // fold self-loop
        float nm0 = fmaxf(m0, es0);
        s0 = s0 * __expf(m0 - nm0) + __expf(es0 - nm0); m0 = nm0;
        float nm1 = fmaxf(m1, es1);
        s1 = s1 * __expf(m1 - nm1) + __expf(es1 - nm1); m1 = nm1;
    }
    float i0 = 1.0f / s0, i1 = 1.0f / s1;
    if (lane == 0) {
        float4 r; r.x = m0; r.y = i0; r.z = m1; r.w = i1;
        minv[d] = r;
    }
    for (int j = jb + lane; j < je; j += 64) {
        float2 as = a_src[col[j]];      // L1-hot from first pass
        float2 w;
        w.x = __expf(leaky(as.x + ad.x, 0.2f) - m0) * i0;
        w.y = __expf(leaky(as.y + ad.y, 0.2f) - m1) * i1;
        wbuf[j] = w;
    }
}

// ---------------- GAT gather (fp16 rows, one load/edge, x4 unroll; fp16 out) ----------------
__global__ void gat_gather_kernel(const half_t* __restrict__ g, const float2* __restrict__ a_src,
                                  const float2* __restrict__ a_dst, const int* __restrict__ row_ptr,
                                  const int* __restrict__ col, const float2* __restrict__ wbuf,
                                  const float4* __restrict__ minv, half_t* __restrict__ gout, int N) {
    int wid  = (blockIdx.x * blockDim.x + threadIdx.x) >> 6;
    int lane = threadIdx.x & 63;
    if (wid >= N) return;
    int d  = wid;
    int jb = row_ptr[d], je = row_ptr[d + 1];
    const half8* g8 = (const half8*)g;   // row stride 39
    bool actv = lane < 39;
    int f0 = lane * 8;
    bool lo0 = f0 < F_MID;        // head of first 4 feats
    bool hi0 = (f0 + 4) < F_MID;  // head of last 4 feats
    float acc[8] = {};
    { // self contribution
        float2 ad = a_dst[d];
        float2 asd = a_src[d];
        float4 mv = minv[d];
        float w0 = __expf(leaky(asd.x + ad.x, 0.2f) - mv.x) * mv.y;
        float w1 = __expf(leaky(asd.y + ad.y, 0.2f) - mv.z) * mv.w;
        if (actv) {
            half8 v = g8[(size_t)d * 39 + lane];
            float wlo = lo0 ? w0 : w1;
            float whi = hi0 ? w0 : w1;
            #pragma unroll
            for (int e = 0; e < 4; e++) acc[e] = (float)v[e] * wlo;
            #pragma unroll
            for (int e = 4; e < 8; e++) acc[e] = (float)v[e] * whi;
        }
    }
    int j = jb;
    for (; j + 3 < je; j += 4) {
        int s0 = rfl(col[j]);
        int s1 = rfl(col[j + 1]);
        int s2 = rfl(col[j + 2]);
        int s3 = rfl(col[j + 3]);
        float2 W0 = wbuf[j], W1v = wbuf[j + 1], W2v = wbuf[j + 2], W3v = wbuf[j + 3];
        if (actv) {
            half8 v0 = g8[(size_t)s0 * 39 + lane];
            half8 v1 = g8[(size_t)s1 * 39 + lane];
            half8 v2 = g8[(size_t)s2 * 39 + lane];
            half8 v3 = g8[(size_t)s3 * 39 + lane];
            float a0 = lo0 ? W0.x : W0.y,  b0 = hi0 ? W0.x : W0.y;
            float a1 = lo0 ? W1v.x : W1v.y, b1 = hi0 ? W1v.x : W1v.y;
            float a2 = lo0 ? W2v.x : W2v.y, b2 = hi0 ? W2v.x : W2v.y;
            float a3 = lo0 ? W3v.x : W3v.y, b3 = hi0 ? W3v.x : W3v.y;
            #pragma unroll
            for (int e = 0; e < 4; e++)
                acc[e] += (float)v0[e] * a0 + (float)v1[e] * a1 + (float)v2[e] * a2 + (float)v3[e] * a3;
            #pragma unroll
            for (int e = 4; e < 8; e++)
                acc[e] += (float)v0[e] * b0 + (float)v1[e] * b1 + (float)v2[e] * b2 + (float)v3[e] * b3;
        }
    }
    for (; j < je; j++) {
        int s = rfl(col[j]);
        float2 w2 = wbuf[j];
        if (actv) {
            half8 v = g8[(size_t)s * 39 + lane];
            float wlo = lo0 ? w2.x : w2.y;
            float whi = hi0 ? w2.x : w2.y;
            #pragma unroll
            for (int e = 0; e < 4; e++) acc[e] += (float)v[e] * wlo;
            #pragma unroll
            for (int e = 4; e < 8; e++) acc[e] += (float)v[e] * whi;
        }
    }
    if (actv) {
        half8 o;
        #pragma unroll
        for (int e = 0; e < 8; e++) o[e] = (half_t)acc[e];
        ((half8*)gout)[(size_t)d * 39 + lane] = o;
    }
}

// ---------------- pooling + MLP ----------------

__global__ void starts_kernel(const int* __restrict__ batch, int* __restrict__ starts, int N, int B) {
    int b = blockIdx.x * blockDim.x + threadIdx.x;
    if (b > B) return;
    if (b == B) { starts[B] = N; return; }
    int lo = 0, hi = N;
    while (lo < hi) {
        int mid = (lo + hi) >> 1;
        if (batch[mid] < b) lo = mid + 1; else hi = mid;
    }
    starts[b] = lo;
}

// p0[b,:] = leaky(max_n gout16[n,:] + b2, 0.01); half8 columns, 4-deep node unroll
__global__ void pool_kernel(const half_t* __restrict__ gout, const float* __restrict__ b2,
                            const int* __restrict__ starts, float* __restrict__ p0) {
    int b = blockIdx.x;
    int t = threadIdx.x;   // block 64; t<39 active
    if (t >= 39) return;
    int s = starts[b], e = starts[b + 1];
    const half8* g8 = (const half8*)gout;   // row stride 39
    float m[8];
    #pragma unroll
    for (int i = 0; i < 8; i++) m[i] = -INFINITY;
    int n = s;
    for (; n + 3 < e; n += 4) {
        half8 v0 = g8[(size_t)(n + 0) * 39 + t];
        half8 v1 = g8[(size_t)(n + 1) * 39 + t];
        half8 v2 = g8[(size_t)(n + 2) * 39 + t];
        half8 v3 = g8[(size_t)(n + 3) * 39 + t];
        #pragma unroll
        for (int i = 0; i < 8; i++) {
            float a = fmaxf((float)v0[i], (float)v1[i]);
            float c = fmaxf((float)v2[i], (float)v3[i]);
            m[i] = fmaxf(m[i], fmaxf(a, c));
        }
    }
    for (; n < e; n++) {
        half8 v = g8[(size_t)n * 39 + t];
        #pragma unroll
        for (int i = 0; i < 8; i++) m[i] = fmaxf(m[i], (float)v[i]);
    }
    int f0 = t * 8;
    float* orow = p0 + (size_t)b * C2 + f0;
    #pragma unroll
    for (int i = 0; i < 8; i++)
        orow[i] = leaky(m[i] + b2[f0 + i], 0.01f);
}

// dense layer, wave per output scalar: out[b,c] = act(dot(in[b,:], Wt[c,:]) + bias[c])
// ACT: 0 none, 1 leaky 0.01, 2 relu
template <int KDIM, int ACT>
__global__ void fcT_kernel(const float* __restrict__ in, const float* __restrict__ Wt,
                           const float* __restrict__ bias, float* __restrict__ out,
                           int Bn, int OUT) {
    int wid  = (blockIdx.x * blockDim.x + threadIdx.x) >> 6;
    int lane = threadIdx.x & 63;
    if (wid >= Bn * OUT) return;
    int b = wid / OUT, c = wid % OUT;
    const float* irow = in + (size_t)b * KDIM;
    const float* wrow = Wt + (size_t)c * KDIM;
    float acc = 0.f;
    #pragma unroll 4
    for (int k = lane; k < KDIM; k += 64)
        acc += irow[k] * wrow[k];
    #pragma unroll
    for (int off = 32; off; off >>= 1) acc += __shfl_xor(acc, off);
    if (lane == 0) {
        acc += bias[c];
        if (ACT == 1) acc = leaky(acc, 0.01f);
        if (ACT == 2) acc = fmaxf(acc, 0.f);
        out[wid] = acc;
    }
}

extern "C" void kernel_launch(void* const* d_in, const int* in_sizes, int n_in,
                              void* d_out, int out_size, void* d_ws, size_t ws_size,
                              hipStream_t stream) {
    const float* x       = (const float*)d_in[0];
    const int*   ei      = (const int*)d_in[1];
    const int*   batch   = (const int*)d_in[2];
    const float* W1      = (const float*)d_in[3];
    const float* b1      = (const float*)d_in[4];
    const float* W2      = (const float*)d_in[5];
    const float* att_src = (const float*)d_in[6];
    const float* att_dst = (const float*)d_in[7];
    const float* b2      = (const float*)d_in[8];
    const float* Wg      = (const float*)d_in[9];
    const float* bg      = (const float*)d_in[10];
    const float* Wf1     = (const float*)d_in[11];
    const float* bf1     = (const float*)d_in[12];
    const float* Wf2     = (const float*)d_in[13];
    const float* bf2     = (const float*)d_in[14];
    const float* Wo      = (const float*)d_in[15];
    const float* bo      = (const float*)d_in[16];
    float* out = (float*)d_out;

    const int N  = in_sizes[0] / F_INP;
    const int E  = in_sizes[1] / 2;
    const int Bn = out_size;          // 128 graphs

    // ---- workspace carving (16B-aligned slices) ----
    char* base = (char*)d_ws;
    size_t off = 0;
    auto take = [&](size_t bytes) -> void* {
        off = (off + 15) & ~(size_t)15;
        void* p = base + off;
        off += bytes;
        return p;
    };
    half_t* g      = (half_t*)take((size_t)C2 * N * 2);      // fp16, stride 312
    char*   AA     = (char*)take((size_t)C2 * N * 4);        // h_lin|h16 early, gout16 late
    half_t* h_lin  = (half_t*)AA;                            //   N*160 fp16 (16 MB)
    half_t* h16    = (half_t*)(AA + (size_t)160 * N * 2);    //   N*160 fp16 (16 MB)
    half_t* gout   = (half_t*)AA;                            //   N*312 fp16 (31 MB, alias)
    half_t* hx     = (half_t*)take((size_t)96 * N * 2);      // x*dinv fp16 [N][96]
    half_t* w1t    = (half_t*)take((size_t)160 * 96 * 2);    // W1^T fp16 padded
    half_t* w2t    = (half_t*)take((size_t)320 * 160 * 2);   // W2^T fp16 padded
    float*  wgT    = (float*)take((size_t)GDIM * C2 * 4);    // 128x312
    float*  wf1T   = (float*)take((size_t)F1D * GDIM * 4);   // 1024x128
    float*  wf2T   = (float*)take((size_t)F2D * F1D * 4);    // 512x1024
    float4* minv   = (float4*)take((size_t)N * 16);
    float2* a_src  = (float2*)take((size_t)N * 8);
    float2* a_dst  = (float2*)take((size_t)N * 8);
    float2* wbuf   = (float2*)take((size_t)E * 8);
    float*  dinv   = (float*)take((size_t)N * 4);
    int*    deg_i  = (int*)take((size_t)N * 4);
    int*    partials = (int*)take((size_t)SCAN_BLOCKS * 4);
    int*    row_ptr= (int*)take((size_t)(N + 1) * 4);
    int*    cursor = (int*)take((size_t)N * 4);
    int*    col    = (int*)take((size_t)E * 4);
    int*    starts = (int*)take((size_t)(Bn + 1) * 4);
    float*  p0     = (float*)take((size_t)Bn * C2 * 4);
    float*  p1     = (float*)take((size_t)Bn * GDIM * 4);
    float*  p2     = (float*)take((size_t)Bn * F1D * 4);
    float*  p3     = (float*)take((size_t)Bn * F2D * 4);

    hipMemsetAsync(deg_i, 0, (size_t)N * sizeof(int), stream);

    // independent prep
    starts_kernel<<<1, 256, 0, stream>>>(batch, starts, N, Bn);
    w1t_kernel<<<(160 * 96 + 255) / 256, 256, 0, stream>>>(W1, w1t);
    w2t_kernel<<<(320 * 160 + 255) / 256, 256, 0, stream>>>(W2, w2t);
    {
        int tot = GDIM * C2 + F1D * GDIM + F2D * F1D;
        wT_kernel<<<(tot + 255) / 256, 256, 0, stream>>>(Wg, Wf1, Wf2, wgT, wf1T, wf2T);
    }

    // CSR build (parallel 3-phase scan; produces dinv needed by x16)
    deg_count_kernel<<<(E + 255) / 256, 256, 0, stream>>>(ei, deg_i, E);
    scan_p1_kernel<<<SCAN_BLOCKS, 256, 0, stream>>>(deg_i, partials, N);
    scan_p2_kernel<<<1, SCAN_BLOCKS, 0, stream>>>(partials);
    scan_p3_kernel<<<SCAN_BLOCKS, 256, 0, stream>>>(deg_i, partials, row_ptr, cursor, dinv, N, E);
    fill_csr_kernel<<<(E + 255) / 256, 256, 0, stream>>>(ei, cursor, col, E);

    // GCN (lin1 via MFMA)
    x16_kernel<<<(N * 12 + 255) / 256, 256, 0, stream>>>(x, dinv, hx, N);
    {
        int mwaves = (N + 31) / 32;
        lin1_mfma_kernel<<<(mwaves + 3) / 4, 256, 0, stream>>>(hx, w1t, h_lin, N);
    }
    gcn_gather_kernel<<<(N + 3) / 4, 256, 0, stream>>>(h_lin, row_ptr, col, dinv, b1, h16, N);

    // GAT
    {
        int mwaves = (N + 31) / 32;            // one wave per 32 rows
        lin2_mfma_kernel<<<(mwaves + 3) / 4, 256, 0, stream>>>(h16, w2t, g, N);
    }
    att_kernel<<<(N + 3) / 4, 256, 0, stream>>>(g, att_src, att_dst, a_src, a_dst, N);
    gat_msw_kernel<<<(N + 3) / 4, 256, 0, stream>>>(a_src, a_dst, row_ptr, col, minv, wbuf, N);
    gat_gather_kernel<<<(N + 3) / 4, 256, 0, stream>>>(g, a_src, a_dst, row_ptr, col, wbuf, minv, gout, N);

    // pool + MLP (wave-per-output, transposed weights)
    pool_kernel<<<Bn, 64, 0, stream>>>(gout, b2, starts, p0);
    {
        auto blocks_for = [](int waves) { return (waves + 3) / 4; };   // 4 waves / 256-thr block
        fcT_kernel<C2, 1><<<blocks_for(Bn * GDIM), 256, 0, stream>>>(p0, wgT, bg, p1, Bn, GDIM);
        fcT_kernel<GDIM, 2><<<blocks_for(Bn * F1D), 256, 0, stream>>>(p1, wf1T, bf1, p2, Bn, F1D);
        fcT_kernel<F1D, 2><<<blocks_for(Bn * F2D), 256, 0, stream>>>(p2, wf2T, bf2, p3, Bn, F2D);
        fcT_kernel<F2D, 0><<<blocks_for(Bn), 256, 0, stream>>>(p3, Wo, bo, out, Bn, 1);
    }
}